// Round 1
// baseline (3999.330 us; speedup 1.0000x reference)
//
#include <hip/hip_runtime.h>
#include <hip/hip_bf16.h>
#include <math.h>

#define Bc 2
#define Tc 1024
#define DMc 2048
#define NQc 16
#define NKVc 4
#define DHc 128
#define BLKc 32
#define STRIDEc 16
#define TOPNc 16
#define WINc 512
#define NREPc 4
#define NBc 63
#define SCALEc 0.08838834764831843f

__device__ __forceinline__ float geluf(float x) {
  return 0.5f * x * (1.0f + erff(x * 0.7071067811865476f));
}

// C[m,n] = act( sum_k A[m,k] * W[n,k] + bias[n] ),  A: MxK, W: NxK (row-major)
// act: 0=none, 1=sigmoid, 2=gelu(exact)
__global__ __launch_bounds__(256) void gemm_xwt(
    const float* __restrict__ A, const float* __restrict__ W,
    const float* __restrict__ bias, float* __restrict__ C,
    int M, int N, int K, int act)
{
  __shared__ float As[16][68];  // pad 68: staging writes 2-way, float4 reads aligned
  __shared__ float Ws[16][68];
  const int bm = blockIdx.y * 64, bn = blockIdx.x * 64;
  const int tid = threadIdx.x;
  const int tx = tid & 15, ty = tid >> 4;
  float acc[4][4] = {{0.f}};
  for (int k0 = 0; k0 < K; k0 += 16) {
    #pragma unroll
    for (int i0 = 0; i0 < 4; ++i0) {
      int i = tid + i0 * 256;
      int m = i >> 4, kk = i & 15;
      int gm = bm + m;
      As[kk][m] = (gm < M) ? A[(size_t)gm * K + (k0 + kk)] : 0.f;
      int gn = bn + m;
      Ws[kk][m] = (gn < N) ? W[(size_t)gn * K + (k0 + kk)] : 0.f;
    }
    __syncthreads();
    #pragma unroll
    for (int kk = 0; kk < 16; ++kk) {
      float4 a4 = *reinterpret_cast<const float4*>(&As[kk][ty * 4]);
      float4 w4 = *reinterpret_cast<const float4*>(&Ws[kk][tx * 4]);
      float av[4] = {a4.x, a4.y, a4.z, a4.w};
      float wv[4] = {w4.x, w4.y, w4.z, w4.w};
      #pragma unroll
      for (int i = 0; i < 4; ++i)
        #pragma unroll
        for (int j = 0; j < 4; ++j)
          acc[i][j] = fmaf(av[i], wv[j], acc[i][j]);
    }
    __syncthreads();
  }
  #pragma unroll
  for (int i = 0; i < 4; ++i) {
    int m = bm + ty * 4 + i;
    if (m >= M) continue;
    #pragma unroll
    for (int j = 0; j < 4; ++j) {
      int n = bn + tx * 4 + j;
      if (n >= N) continue;
      float v = acc[i][j] + (bias ? bias[n] : 0.f);
      if (act == 1) v = 1.f / (1.f + __expf(-v));
      else if (act == 2) v = geluf(v);
      C[(size_t)m * N + n] = v;
    }
  }
}

// in-place RoPE on k: layout (B,T,KV,DH); rotate pairs (d, d+64); angle = t / 10000^(d/64)
__global__ void rope_kernel(float* __restrict__ k) {
  int blk = blockIdx.x;                // (b*T + t)*KV + kv
  int kv = blk & 3;
  int t = (blk >> 2) & (Tc - 1);
  int b = blk >> 12;
  float* p = k + ((((size_t)b * Tc + t) * NKVc) + kv) * DHc;
  int d = threadIdx.x;                 // 0..63
  float inv = powf(10000.f, -(float)d * (1.f / 64.f));
  float ang = (float)t * inv;
  float s, c;
  sincosf(ang, &s, &c);
  float x1 = p[d], x2 = p[d + 64];
  p[d] = x1 * c - x2 * s;
  p[d + 64] = x1 * s + x2 * c;
}

// kbf[(b,n,kv)][j*DH+d] = k_cmp[b, 16n+j, kv, d] + block_pos[j,d]; same for v
__global__ void gather_blocks(const float* __restrict__ k_cmp,
                              const float* __restrict__ v_cmp,
                              const float* __restrict__ block_pos,
                              float* __restrict__ kbf, float* __restrict__ vbf) {
  size_t idx = (size_t)blockIdx.x * 256 + threadIdx.x;
  size_t total = (size_t)Bc * NBc * NKVc * BLKc * DHc;
  if (idx >= total) return;
  int d = (int)(idx & 127);
  size_t r = idx >> 7;
  int j = (int)(r & 31); r >>= 5;
  int kv = (int)(r & 3); r >>= 2;
  int n = (int)(r % NBc);
  int b = (int)(r / NBc);
  int tt = n * STRIDEc + j;
  float bp = block_pos[j * DHc + d];
  size_t src = (((size_t)b * Tc + tt) * NKVc + kv) * DHc + d;
  kbf[idx] = k_cmp[src] + bp;
  vbf[idx] = v_cmp[src] + bp;
}

// Per (b,kv,t): compressed attention for the 4 query heads sharing this kv,
// top-16 block selection bitmask, and out = gate0 * o_cmp.
__global__ __launch_bounds__(256) void cmp_attn(
    const float* __restrict__ q, const float* __restrict__ k_sum,
    const float* __restrict__ v_sum, const float* __restrict__ gates,
    float* __restrict__ out, unsigned long long* __restrict__ sel)
{
  __shared__ float q_s[NREPc][DHc];
  __shared__ float ks[NBc][DHc + 1];   // +1 pad: 2-way max on both access patterns
  __shared__ float p_s[NREPc][64];

  int wg = blockIdx.x;                 // (b*KV + kv)*T + t
  int t = wg & (Tc - 1);
  int kv = (wg >> 10) & 3;
  int b = wg >> 12;
  int tid = threadIdx.x;
  int lane = tid & 63;
  int g = tid >> 6;                    // wave = head-group index

  for (int i = tid; i < NREPc * DHc; i += 256) {
    int gg = i >> 7, d = i & 127;
    int h = gg * NKVc + kv;
    q_s[gg][d] = q[(((size_t)b * NQc + h) * Tc + t) * DHc + d];
  }
  for (int i = tid; i < NBc * DHc; i += 256) {
    int n = i >> 7, d = i & 127;
    ks[n][d] = k_sum[(((size_t)b * NBc + n) * NKVc + kv) * DHc + d];
  }
  __syncthreads();

  int nvalid = min(t / STRIDEc + 1, NBc);

  // scores: lane = block index n
  float acc = 0.f;
  if (lane < NBc) {
    for (int d = 0; d < DHc; ++d) acc = fmaf(q_s[g][d], ks[lane][d], acc);
  }
  bool valid = (lane < nvalid);
  float sval = valid ? acc * SCALEc : -INFINITY;
  float m = sval;
  for (int off = 32; off; off >>= 1) m = fmaxf(m, __shfl_xor(m, off));
  float e = valid ? __expf(sval - m) : 0.f;
  float l = e;
  for (int off = 32; off; off >>= 1) l += __shfl_xor(l, off);
  p_s[g][lane] = e / fmaxf(l, 1e-9f);
  __syncthreads();

  // wave 0: p_grp + iterative top-16 (lowest-index tie-break == stable top_k)
  if (g == 0) {
    float v = p_s[0][lane] + p_s[1][lane] + p_s[2][lane] + p_s[3][lane];
    if (lane >= NBc) v = -1.f;
    unsigned long long mask = 0ull;
    for (int it = 0; it < TOPNc; ++it) {
      float mx = v;
      for (int off = 32; off; off >>= 1) mx = fmaxf(mx, __shfl_xor(mx, off));
      unsigned long long ball = __ballot(v == mx);
      int sl = __ffsll((unsigned long long)ball) - 1;
      mask |= (1ull << sl);
      if (lane == sl) v = -1.f;
    }
    if (lane == 0) sel[wg] = mask;
  }
  __syncthreads();
  // overwrite ks with v_sum
  for (int i = tid; i < NBc * DHc; i += 256) {
    int n = i >> 7, d = i & 127;
    ks[n][d] = v_sum[(((size_t)b * NBc + n) * NKVc + kv) * DHc + d];
  }
  __syncthreads();

  int h = g * NKVc + kv;
  float g0 = gates[((size_t)b * Tc + t) * (3 * NQc) + h * 3 + 0];
  size_t obase = (((size_t)b * NQc + h) * Tc + t) * DHc;
  #pragma unroll
  for (int half = 0; half < 2; ++half) {
    int d = lane + half * 64;
    float o = 0.f;
    for (int n = 0; n < nvalid; ++n) o = fmaf(p_s[g][n], ks[n][d], o);
    out[obase + d] = g0 * o;
  }
}

// MODE 0: selected-block attention (uses sel bitmask, gate ch1, accumulates into out)
// MODE 1: sliding-window attention (gate ch2)
template <int MODE>
__global__ __launch_bounds__(256) void sparse_attn(
    const float* __restrict__ q, const float* __restrict__ kArr,
    const float* __restrict__ vArr, const float* __restrict__ gates,
    const unsigned long long* __restrict__ sel, float* __restrict__ out)
{
  __shared__ float q_s[NREPc][DHc];
  __shared__ float ch[64][DHc + 1];
  __shared__ float p_s[NREPc][64];

  int wg = blockIdx.x;
  int t = wg & (Tc - 1);
  int kv = (wg >> 10) & 3;
  int b = wg >> 12;
  int tid = threadIdx.x;
  int lane = tid & 63;
  int g = tid >> 6;

  for (int i = tid; i < NREPc * DHc; i += 256) {
    int gg = i >> 7, d = i & 127;
    int h = gg * NKVc + kv;
    q_s[gg][d] = q[(((size_t)b * NQc + h) * Tc + t) * DHc + d];
  }
  __syncthreads();

  unsigned long long bmask = 0ull;
  int c0 = 0;
  int c1 = t >> 6;
  if (MODE == 0) bmask = sel[wg];
  else c0 = (t - (WINc - 1) > 0 ? t - (WINc - 1) : 0) >> 6;

  float run_m = -INFINITY, run_l = 0.f;
  float o0 = 0.f, o1 = 0.f;

  for (int c = c0; c <= c1; ++c) {
    int s = c * 64 + lane;
    bool att;
    if (MODE == 0) {
      int n1 = s >> 4;
      bool hit = (n1 < NBc) && ((bmask >> n1) & 1ull);
      if (!hit && n1 >= 1) hit = (bmask >> (n1 - 1)) & 1ull;
      att = (s <= t) && hit;
    } else {
      att = (s <= t) && (t - s < WINc);
    }
    if (__ballot(att) == 0ull) continue;   // uniform across block (mask is head-indep)

    __syncthreads();  // previous chunk's PV reads done before overwriting ch
    for (int i = tid; i < 64 * DHc; i += 256) {
      int j = i >> 7, d = i & 127;
      int ss = c * 64 + j;
      ch[j][d] = (ss < Tc) ? kArr[(((size_t)b * Tc + ss) * NKVc + kv) * DHc + d] : 0.f;
    }
    __syncthreads();

    // scores: lane = token within chunk
    float acc = 0.f;
    for (int d = 0; d < DHc; ++d) acc = fmaf(q_s[g][d], ch[lane][d], acc);
    float sv = att ? acc * SCALEc : -INFINITY;
    float cm = sv;
    for (int off = 32; off; off >>= 1) cm = fmaxf(cm, __shfl_xor(cm, off));
    float nm = fmaxf(run_m, cm);
    float resc = (run_m == -INFINITY) ? 0.f : __expf(run_m - nm);
    float e = att ? __expf(sv - nm) : 0.f;
    float cl = e;
    for (int off = 32; off; off >>= 1) cl += __shfl_xor(cl, off);
    run_l = run_l * resc + cl;
    run_m = nm;
    p_s[g][lane] = e;
    o0 *= resc;
    o1 *= resc;
    __syncthreads();  // all waves done with K before overwriting with V
    for (int i = tid; i < 64 * DHc; i += 256) {
      int j = i >> 7, d = i & 127;
      int ss = c * 64 + j;
      ch[j][d] = (ss < Tc) ? vArr[(((size_t)b * Tc + ss) * NKVc + kv) * DHc + d] : 0.f;
    }
    __syncthreads();

    // PV: lane = dim d (two halves)
    int jmax = min(64, t - c * 64 + 1);
    for (int j = 0; j < jmax; ++j) {
      float pj = p_s[g][j];
      o0 = fmaf(pj, ch[j][lane], o0);
      o1 = fmaf(pj, ch[j][lane + 64], o1);
    }
  }

  float inv_l = 1.f / fmaxf(run_l, 1e-9f);
  int h = g * NKVc + kv;
  float gg = gates[((size_t)b * Tc + t) * (3 * NQc) + h * 3 + (MODE == 0 ? 1 : 2)];
  size_t obase = (((size_t)b * NQc + h) * Tc + t) * DHc;
  out[obase + lane] += gg * o0 * inv_l;
  out[obase + lane + 64] += gg * o1 * inv_l;
}

extern "C" void kernel_launch(void* const* d_in, const int* in_sizes, int n_in,
                              void* d_out, int out_size, void* d_ws, size_t ws_size,
                              hipStream_t stream) {
  const float* x = (const float*)d_in[0];
  const float* q = (const float*)d_in[1];
  const float* gate_w = (const float*)d_in[2];
  const float* gate_b = (const float*)d_in[3];
  const float* wk_cmp = (const float*)d_in[4];
  const float* wv_cmp = (const float*)d_in[5];
  const float* wk_slc = (const float*)d_in[6];
  const float* wv_slc = (const float*)d_in[7];
  const float* wk_win = (const float*)d_in[8];
  const float* wv_win = (const float*)d_in[9];
  const float* block_pos = (const float*)d_in[10];
  const float* ck1_w = (const float*)d_in[11];
  const float* ck1_b = (const float*)d_in[12];
  const float* ck2_w = (const float*)d_in[13];
  const float* ck2_b = (const float*)d_in[14];
  const float* cv1_w = (const float*)d_in[15];
  const float* cv1_b = (const float*)d_in[16];
  const float* cv2_w = (const float*)d_in[17];
  const float* cv2_b = (const float*)d_in[18];
  float* out = (float*)d_out;

  char* wsp = (char*)d_ws;
  size_t off = 0;
  auto alloc = [&](size_t bytes) -> void* {
    void* p = wsp + off;
    off += (bytes + 255) & ~(size_t)255;
    return p;
  };
  float* gatesB = (float*)alloc((size_t)Bc * Tc * 48 * 4);
  float* k_cmp  = (float*)alloc((size_t)Bc * Tc * NKVc * DHc * 4);
  float* v_cmp  = (float*)alloc((size_t)Bc * Tc * NKVc * DHc * 4);
  float* k_slc  = (float*)alloc((size_t)Bc * Tc * NKVc * DHc * 4);
  float* v_slc  = (float*)alloc((size_t)Bc * Tc * NKVc * DHc * 4);
  float* k_win  = (float*)alloc((size_t)Bc * Tc * NKVc * DHc * 4);
  float* v_win  = (float*)alloc((size_t)Bc * Tc * NKVc * DHc * 4);
  float* kbf    = (float*)alloc((size_t)Bc * NBc * NKVc * BLKc * DHc * 4);
  float* vbf    = (float*)alloc((size_t)Bc * NBc * NKVc * BLKc * DHc * 4);
  float* hk     = (float*)alloc((size_t)Bc * NBc * NKVc * DHc * 4);
  float* hv     = (float*)alloc((size_t)Bc * NBc * NKVc * DHc * 4);
  float* k_sum  = (float*)alloc((size_t)Bc * NBc * NKVc * DHc * 4);
  float* v_sum  = (float*)alloc((size_t)Bc * NBc * NKVc * DHc * 4);
  unsigned long long* selB = (unsigned long long*)alloc((size_t)Bc * NKVc * Tc * 8);

  dim3 blk256(256);
  const int M = Bc * Tc;  // 2048

  gemm_xwt<<<dim3(8, 32), blk256, 0, stream>>>(x, wk_cmp, nullptr, k_cmp, M, 512, DMc, 0);
  gemm_xwt<<<dim3(8, 32), blk256, 0, stream>>>(x, wv_cmp, nullptr, v_cmp, M, 512, DMc, 0);
  gemm_xwt<<<dim3(8, 32), blk256, 0, stream>>>(x, wk_slc, nullptr, k_slc, M, 512, DMc, 0);
  gemm_xwt<<<dim3(8, 32), blk256, 0, stream>>>(x, wv_slc, nullptr, v_slc, M, 512, DMc, 0);
  gemm_xwt<<<dim3(8, 32), blk256, 0, stream>>>(x, wk_win, nullptr, k_win, M, 512, DMc, 0);
  gemm_xwt<<<dim3(8, 32), blk256, 0, stream>>>(x, wv_win, nullptr, v_win, M, 512, DMc, 0);
  gemm_xwt<<<dim3(1, 32), blk256, 0, stream>>>(x, gate_w, gate_b, gatesB, M, 48, DMc, 1);

  rope_kernel<<<Bc * Tc * NKVc, 64, 0, stream>>>(k_cmp);
  rope_kernel<<<Bc * Tc * NKVc, 64, 0, stream>>>(k_slc);
  rope_kernel<<<Bc * Tc * NKVc, 64, 0, stream>>>(k_win);

  {
    size_t total = (size_t)Bc * NBc * NKVc * BLKc * DHc;
    gather_blocks<<<(int)((total + 255) / 256), blk256, 0, stream>>>(
        k_cmp, v_cmp, block_pos, kbf, vbf);
  }

  const int MC = Bc * NBc * NKVc;  // 504
  gemm_xwt<<<dim3(2, 8), blk256, 0, stream>>>(kbf, ck1_w, ck1_b, hk, MC, DHc, BLKc * DHc, 2);
  gemm_xwt<<<dim3(2, 8), blk256, 0, stream>>>(hk, ck2_w, ck2_b, k_sum, MC, DHc, DHc, 0);
  gemm_xwt<<<dim3(2, 8), blk256, 0, stream>>>(vbf, cv1_w, cv1_b, hv, MC, DHc, BLKc * DHc, 2);
  gemm_xwt<<<dim3(2, 8), blk256, 0, stream>>>(hv, cv2_w, cv2_b, v_sum, MC, DHc, DHc, 0);

  cmp_attn<<<Bc * NKVc * Tc, blk256, 0, stream>>>(q, k_sum, v_sum, gatesB, out, selB);
  sparse_attn<0><<<Bc * NKVc * Tc, blk256, 0, stream>>>(q, k_slc, v_slc, gatesB, selB, out);
  sparse_attn<1><<<Bc * NKVc * Tc, blk256, 0, stream>>>(q, k_win, v_win, gatesB, selB, out);
}

// Round 3
// 1487.229 us; speedup vs baseline: 2.6891x; 2.6891x over previous
//
#include <hip/hip_runtime.h>
#include <hip/hip_bf16.h>
#include <math.h>

#define Bc 2
#define Tc 1024
#define DMc 2048
#define NQc 16
#define NKVc 4
#define DHc 128
#define BLKc 32
#define STRIDEc 16
#define TOPNc 16
#define WINc 512
#define NREPc 4
#define NBc 63
#define SCALEc 0.08838834764831843f

typedef unsigned short bf16_t;
typedef short s16x8 __attribute__((ext_vector_type(8)));
typedef float f32x4 __attribute__((ext_vector_type(4)));

__device__ __forceinline__ unsigned short f2bf(float f) {
  unsigned int u = __float_as_uint(f);
  u += 0x7fffu + ((u >> 16) & 1u);
  return (unsigned short)(u >> 16);
}
__device__ __forceinline__ float geluf(float x) {
  return 0.5f * x * (1.0f + erff(x * 0.7071067811865476f));
}
__device__ __forceinline__ void load_lds16(const void* g, void* l) {
  __builtin_amdgcn_global_load_lds(
      (const __attribute__((address_space(1))) void*)g,
      (__attribute__((address_space(3))) void*)l, 16, 0, 0);
}

// ---------- x -> bf16 (for MFMA path) ----------
__global__ void conv_x(const float* __restrict__ x, bf16_t* __restrict__ xbf) {
  size_t i = (size_t)blockIdx.x * 256 + threadIdx.x;  // grid exact: 2048*2048/256
  xbf[i] = f2bf(x[i]);
}

// ---------- concat weights rows 512..3199 into bf16 Wcat (rows 0..2687) ----------
__global__ void build_wcat(
    const float* __restrict__ wv_cmp, const float* __restrict__ wk_slc,
    const float* __restrict__ wv_slc, const float* __restrict__ wk_win,
    const float* __restrict__ wv_win, const float* __restrict__ gate_w,
    const float* __restrict__ gate_b, bf16_t* __restrict__ Wcat,
    float* __restrict__ bias_cat) {
  size_t i = (size_t)blockIdx.x * 256 + threadIdx.x;  // grid exact: 2688*2048/256
  int rr = (int)(i >> 11), c = (int)(i & 2047);
  int r = rr + 512;
  float v = 0.f;
  if (r < 3072) {
    int blk = r >> 9;  // 1..5
    size_t o = (size_t)(r & 511) * 2048 + c;
    if (blk == 1) v = wv_cmp[o];
    else if (blk == 2) v = wk_slc[o];
    else if (blk == 3) v = wv_slc[o];
    else if (blk == 4) v = wk_win[o];
    else v = wv_win[o];
  } else if (r < 3120) {
    v = gate_w[(size_t)(r - 3072) * 2048 + c];
  }
  Wcat[i] = f2bf(v);
  if (c == 0) bias_cat[r] = (r >= 3072 && r < 3120) ? gate_b[r - 3072] : 0.f;
}

// ---------- bf16 MFMA GEMM: C[m, colbase+n] = A[m,:].Wcat[n,:] (+bias; sigmoid cols>=3072)
// 128x128 tile, BK=32, 4 waves (2x2), 16x16x32 mfma, global_load_lds w/ source swizzle (G21)
__global__ __launch_bounds__(256) void gemm_mfma(
    const bf16_t* __restrict__ A, int lda,
    const bf16_t* __restrict__ Bw, int ldb,
    float* __restrict__ C, int ldc, const float* __restrict__ bias,
    int K, int colbase) {
  __shared__ bf16_t As[128 * 32];
  __shared__ bf16_t Bs[128 * 32];
  const int bm = blockIdx.y * 128, bnw = blockIdx.x * 128, bn = colbase + bnw;
  const int tid = threadIdx.x, lane = tid & 63, w = tid >> 6;
  const int wr = (w >> 1) * 64, wc = (w & 1) * 64;

  f32x4 acc[4][4];
#pragma unroll
  for (int i = 0; i < 4; ++i)
#pragma unroll
    for (int j = 0; j < 4; ++j) acc[i][j] = 0.f;

  const int srow = lane >> 2;  // 0..15
  const int sslot = lane & 3;  // 16B slot within 64B row

  for (int k0 = 0; k0 < K; k0 += 32) {
    __syncthreads();
#pragma unroll
    for (int j = 0; j < 2; ++j) {
      int rb = w * 32 + j * 16;
      int row = rb + srow;
      int slot = sslot ^ ((row >> 1) & 3);  // pre-swizzled global source
      load_lds16(A + (size_t)(bm + row) * lda + k0 + slot * 8, &As[rb * 32]);
      load_lds16(Bw + (size_t)(bnw + row) * ldb + k0 + slot * 8, &Bs[rb * 32]);
    }
    __syncthreads();  // vmcnt(0) drained by compiler before barrier

    s16x8 af[4], bfr[4];
#pragma unroll
    for (int i = 0; i < 4; ++i) {
      int ar = wr + i * 16 + (lane & 15);
      int as = ((lane >> 4) ^ ((ar >> 1) & 3)) * 8;
      af[i] = *(const s16x8*)&As[ar * 32 + as];
      int br = wc + i * 16 + (lane & 15);
      int bs = ((lane >> 4) ^ ((br >> 1) & 3)) * 8;
      bfr[i] = *(const s16x8*)&Bs[br * 32 + bs];
    }
#pragma unroll
    for (int i = 0; i < 4; ++i)
#pragma unroll
      for (int j = 0; j < 4; ++j)
        acc[i][j] = __builtin_amdgcn_mfma_f32_16x16x32_bf16(af[i], bfr[j], acc[i][j], 0, 0, 0);
  }

#pragma unroll
  for (int i = 0; i < 4; ++i) {
    int row = bm + wr + i * 16 + ((lane >> 4) << 2);
#pragma unroll
    for (int j = 0; j < 4; ++j) {
      int col = bn + wc + j * 16 + (lane & 15);
      float bv = bias[col];
#pragma unroll
      for (int r = 0; r < 4; ++r) {
        float v = acc[i][j][r] + bv;
        if (col >= 3072) v = 1.f / (1.f + __expf(-v));  // gate sigmoid
        C[(size_t)(row + r) * ldc + col] = v;
      }
    }
  }
}

// ---------- f32 VALU GEMM: C[m,n] = A[m,:].W[n,:] (+bias), split-K via blockIdx.z ----------
__global__ __launch_bounds__(256) void gemm_xwt(
    const float* __restrict__ A, int lda, const float* __restrict__ W, int ldw,
    const float* __restrict__ bias, float* __restrict__ C, int ldc,
    int M, int N, int K) {
  __shared__ float As[16][68];
  __shared__ float Ws[16][68];
  const int z = blockIdx.z;
  A += (size_t)z * K;
  W += (size_t)z * K;
  C += (size_t)z * (size_t)M * ldc;
  const int bm = blockIdx.y * 64, bn = blockIdx.x * 64;
  const int tid = threadIdx.x;
  const int tx = tid & 15, ty = tid >> 4;
  float acc[4][4] = {{0.f}};
  for (int k0 = 0; k0 < K; k0 += 16) {
#pragma unroll
    for (int i0 = 0; i0 < 4; ++i0) {
      int i = tid + i0 * 256;
      int m = i >> 4, kk = i & 15;
      int gm = bm + m;
      As[kk][m] = (gm < M) ? A[(size_t)gm * lda + (k0 + kk)] : 0.f;
      int gn = bn + m;
      Ws[kk][m] = (gn < N) ? W[(size_t)gn * ldw + (k0 + kk)] : 0.f;
    }
    __syncthreads();
#pragma unroll
    for (int kk = 0; kk < 16; ++kk) {
      float4 a4 = *reinterpret_cast<const float4*>(&As[kk][ty * 4]);
      float4 w4 = *reinterpret_cast<const float4*>(&Ws[kk][tx * 4]);
      float av[4] = {a4.x, a4.y, a4.z, a4.w};
      float wv[4] = {w4.x, w4.y, w4.z, w4.w};
#pragma unroll
      for (int i = 0; i < 4; ++i)
#pragma unroll
        for (int j = 0; j < 4; ++j) acc[i][j] = fmaf(av[i], wv[j], acc[i][j]);
    }
    __syncthreads();
  }
#pragma unroll
  for (int i = 0; i < 4; ++i) {
    int m = bm + ty * 4 + i;
    if (m >= M) continue;
#pragma unroll
    for (int j = 0; j < 4; ++j) {
      int n = bn + tx * 4 + j;
      if (n >= N) continue;
      C[(size_t)m * ldc + n] = acc[i][j] + (bias ? bias[n] : 0.f);
    }
  }
}

// ---------- compress layer1: gathered-A GEMM (fused block gather), split-K x4 ----------
// Cpart[z][m][o] = sum_{f in z-chunk} kvproj[(b*1024+16n+j)*3200+coloff+kv*128+d] * W[o][f]
__global__ __launch_bounds__(256) void gemm_cmp1(
    const float* __restrict__ kvproj, int coloff,
    const float* __restrict__ W, float* __restrict__ Cpart) {
  __shared__ float As[16][68];
  __shared__ float Ws[16][68];
  const int z = blockIdx.z;
  const int bm = blockIdx.y * 64, bn = blockIdx.x * 64;
  const int tid = threadIdx.x;
  const int tx = tid & 15, ty = tid >> 4;
  float acc[4][4] = {{0.f}};
  for (int k0 = z * 1024; k0 < z * 1024 + 1024; k0 += 16) {
#pragma unroll
    for (int i0 = 0; i0 < 4; ++i0) {
      int i = tid + i0 * 256;
      int m = i >> 4, kk = i & 15;
      int gm = bm + m;
      float av = 0.f;
      if (gm < 504) {
        int b = gm / 252, rem = gm % 252;
        int n = rem >> 2, kv = rem & 3;
        int f = k0 + kk;
        int j = f >> 7, d = f & 127;
        av = kvproj[(size_t)(b * 1024 + n * 16 + j) * 3200 + coloff + kv * 128 + d];
      }
      As[kk][m] = av;
      Ws[kk][m] = W[(size_t)(bn + m) * 4096 + (k0 + kk)];  // bn+m < 128 always
    }
    __syncthreads();
#pragma unroll
    for (int kk = 0; kk < 16; ++kk) {
      float4 a4 = *reinterpret_cast<const float4*>(&As[kk][ty * 4]);
      float4 w4 = *reinterpret_cast<const float4*>(&Ws[kk][tx * 4]);
      float av[4] = {a4.x, a4.y, a4.z, a4.w};
      float wv[4] = {w4.x, w4.y, w4.z, w4.w};
#pragma unroll
      for (int i = 0; i < 4; ++i)
#pragma unroll
        for (int j = 0; j < 4; ++j) acc[i][j] = fmaf(av[i], wv[j], acc[i][j]);
    }
    __syncthreads();
  }
#pragma unroll
  for (int i = 0; i < 4; ++i) {
    int m = bm + ty * 4 + i;
    if (m >= 504) continue;
#pragma unroll
    for (int j = 0; j < 4; ++j) {
      int n = bn + tx * 4 + j;
      Cpart[(size_t)z * 64512 + (size_t)m * 128 + n] = acc[i][j];
    }
  }
}

// ---------- bias_adj[o] = b1[o] + sum_f block_pos_flat[f] * w1[o][f] ----------
__global__ void bias_adj_kernel(const float* __restrict__ bp,
                                const float* __restrict__ w1k,
                                const float* __restrict__ b1k,
                                const float* __restrict__ w1v,
                                const float* __restrict__ b1v,
                                float* __restrict__ outk,
                                float* __restrict__ outv) {
  __shared__ float red[4];
  const int o = blockIdx.x;  // 0..127
  const float* w1 = blockIdx.y ? w1v : w1k;
  float s = 0.f;
  for (int i = threadIdx.x; i < 4096; i += 256)
    s += bp[i] * w1[(size_t)o * 4096 + i];
#pragma unroll
  for (int off = 32; off; off >>= 1) s += __shfl_xor(s, off);
  if ((threadIdx.x & 63) == 0) red[threadIdx.x >> 6] = s;
  __syncthreads();
  if (threadIdx.x == 0) {
    float t = red[0] + red[1] + red[2] + red[3];
    if (blockIdx.y) outv[o] = t + b1v[o];
    else outk[o] = t + b1k[o];
  }
}

__global__ void reduce_gelu(const float* __restrict__ parts,
                            const float* __restrict__ bias_adj,
                            float* __restrict__ outp) {
  int i = blockIdx.x * 256 + threadIdx.x;  // grid exact: 504*128/256
  float s = parts[i] + parts[64512 + i] + parts[2 * 64512 + i] +
            parts[3 * 64512 + i] + bias_adj[i & 127];
  outp[i] = geluf(s);
}

// ---------- RoPE in place on kvproj k-slices (coloff = blockIdx.y<<10: 0,1024,2048) ----------
__global__ void rope_kernel(float* __restrict__ kvproj) {
  int blk = blockIdx.x;  // (b*T+t)*KV+kv
  int coloff = blockIdx.y << 10;
  int kv = blk & 3;
  int t = (blk >> 2) & (Tc - 1);
  int b = blk >> 12;
  float* p = kvproj + (size_t)(b * Tc + t) * 3200 + coloff + kv * 128;
  int d = threadIdx.x;  // 0..63
  float inv = powf(10000.f, -(float)d * (1.f / 64.f));
  float ang = (float)t * inv;
  float s, c;
  sincosf(ang, &s, &c);
  float x1 = p[d], x2 = p[d + 64];
  p[d] = x1 * c - x2 * s;
  p[d + 64] = x1 * s + x2 * c;
}

// ---------- compressed attention + top-k selection ----------
__global__ __launch_bounds__(256) void cmp_attn(
    const float* __restrict__ q, const float* __restrict__ k_sum,
    const float* __restrict__ v_sum, const float* __restrict__ kvproj,
    float* __restrict__ out, unsigned long long* __restrict__ sel) {
  __shared__ __align__(16) float q_s[NREPc * 128];
  __shared__ __align__(16) float ks[NBc * 128];
  __shared__ float p_s[NREPc][64];

  const int wg = blockIdx.x;  // (b*KV+kv)*T+t
  const int t = wg & (Tc - 1);
  const int kv = (wg >> 10) & 3;
  const int b = wg >> 12;
  const int tid = threadIdx.x;
  const int lane = tid & 63;
  const int g = tid >> 6;

  for (int i = tid; i < NREPc * 128; i += 256) {
    int gg = i >> 7, d = i & 127;
    q_s[i] = q[(((size_t)b * NQc + gg * NKVc + kv) * Tc + t) * 128 + d];
  }
  {
    const float* kbase = k_sum + (size_t)(b * 252 + kv) * 128;
    for (int i = tid; i < NBc * 32; i += 256) {
      int n = i >> 5, s = i & 31;
      f32x4 v4 = *(const f32x4*)(kbase + (size_t)n * 512 + s * 4);
      *(f32x4*)&ks[n * 128 + ((s ^ (n & 7)) << 2)] = v4;  // G4 XOR swizzle
    }
  }
  __syncthreads();

  const int nvalid = min(t / STRIDEc + 1, NBc);

  float acc = 0.f;
  {
    const int lrow = (lane < 63) ? lane : 62;  // avoid OOB row read
    const int lx = lrow & 7;
#pragma unroll
    for (int s = 0; s < 32; ++s) {
      f32x4 k4 = *(const f32x4*)&ks[lrow * 128 + ((s ^ lx) << 2)];
      f32x4 q4 = *(const f32x4*)&q_s[g * 128 + s * 4];
      acc = fmaf(q4[0], k4[0], acc);
      acc = fmaf(q4[1], k4[1], acc);
      acc = fmaf(q4[2], k4[2], acc);
      acc = fmaf(q4[3], k4[3], acc);
    }
  }
  const bool valid = (lane < nvalid);
  float sval = valid ? acc * SCALEc : -INFINITY;
  float m = sval;
#pragma unroll
  for (int off = 32; off; off >>= 1) m = fmaxf(m, __shfl_xor(m, off));
  float e = valid ? __expf(sval - m) : 0.f;
  float l = e;
#pragma unroll
  for (int off = 32; off; off >>= 1) l += __shfl_xor(l, off);
  p_s[g][lane] = e / fmaxf(l, 1e-9f);
  __syncthreads();

  if (g == 0) {  // p_grp + iterative top-16, lowest-index tie-break (== lax.top_k)
    float v = p_s[0][lane] + p_s[1][lane] + p_s[2][lane] + p_s[3][lane];
    if (lane >= NBc) v = -1.f;
    unsigned long long mask = 0ull;
    for (int it = 0; it < TOPNc; ++it) {
      float mx = v;
#pragma unroll
      for (int off = 32; off; off >>= 1) mx = fmaxf(mx, __shfl_xor(mx, off));
      unsigned long long ball = __ballot(v == mx);
      int sl = __ffsll(ball) - 1;
      mask |= 1ull << sl;
      if (lane == sl) v = -1.f;
    }
    if (lane == 0) sel[wg] = mask;
  }
  __syncthreads();

  {
    const float* vbase = v_sum + (size_t)(b * 252 + kv) * 128;
    for (int i = tid; i < NBc * 32; i += 256) {
      int n = i >> 5, s = i & 31;
      f32x4 v4 = *(const f32x4*)(vbase + (size_t)n * 512 + s * 4);
      *(f32x4*)&ks[n * 128 + ((s ^ (n & 7)) << 2)] = v4;
    }
  }
  __syncthreads();

  const int h = g * NKVc + kv;
  const float g0 = kvproj[(size_t)(b * Tc + t) * 3200 + 3072 + h * 3];
  float ox = 0.f, oy = 0.f;
  const int slotd = lane >> 1, wi = (lane & 1) * 2;
  for (int n = 0; n < nvalid; ++n) {
    float pn = p_s[g][n];
    const float* vp = &ks[n * 128 + (((slotd ^ (n & 7)) << 2) | wi)];
    ox = fmaf(pn, vp[0], ox);
    oy = fmaf(pn, vp[1], oy);
  }
  size_t obase = ((size_t)(b * NQc + h) * Tc + t) * 128 + lane * 2;
  *(float2*)&out[obase] = make_float2(g0 * ox, g0 * oy);
}

// ---------- selected (MODE 0) / windowed (MODE 1) attention ----------
template <int MODE>
__global__ __launch_bounds__(256) void sparse_attn(
    const float* __restrict__ q, const float* __restrict__ kvproj, int colbase,
    const unsigned long long* __restrict__ sel, float* __restrict__ out) {
  __shared__ __align__(16) float q_s[NREPc * 128];
  __shared__ __align__(16) float ch[64 * 128];
  __shared__ float p_s[NREPc][64];

  const int wg = blockIdx.x;
  const int t = wg & (Tc - 1);
  const int kv = (wg >> 10) & 3;
  const int b = wg >> 12;
  const int tid = threadIdx.x;
  const int lane = tid & 63;
  const int g = tid >> 6;

  for (int i = tid; i < NREPc * 128; i += 256) {
    int gg = i >> 7, d = i & 127;
    q_s[i] = q[(((size_t)b * NQc + gg * NKVc + kv) * Tc + t) * 128 + d];
  }

  unsigned long long bmask = 0ull;
  int c0 = 0;
  const int c1 = t >> 6;
  if (MODE == 0) {
    bmask = sel[wg];
    c0 = (__ffsll(bmask) - 1) >> 2;
  } else {
    int lo = t - (WINc - 1);
    c0 = (lo > 0 ? lo : 0) >> 6;
  }

  const float* kbase = kvproj + colbase + kv * 128;
  const float* vbase = kbase + 512;
  const size_t brow = (size_t)b * Tc;

  float run_m = -INFINITY, run_l = 0.f;
  float ox = 0.f, oy = 0.f;
  const int lx = lane & 7;
  const int slotd = lane >> 1, wi = (lane & 1) * 2;

  for (int c = c0; c <= c1; ++c) {
    const int s0 = c * 64;
    const int s = s0 + lane;
    bool att;
    if (MODE == 0) {
      int n1 = s >> 4;
      bool hit = (n1 < NBc) && ((bmask >> n1) & 1ull);
      if (!hit && n1 >= 1) hit = (bmask >> (n1 - 1)) & 1ull;
      att = (s <= t) && hit;
    } else {
      att = (s <= t) && (t - s < WINc);
    }
    if (__ballot(att) == 0ull) continue;  // uniform across all waves

    __syncthreads();  // prior chunk's PV/p_s reads done
    for (int i = tid; i < 2048; i += 256) {
      int j = i >> 5, sl = i & 31;
      f32x4 v4 = *(const f32x4*)(kbase + (brow + s0 + j) * 3200 + sl * 4);
      *(f32x4*)&ch[j * 128 + ((sl ^ (j & 7)) << 2)] = v4;
    }
    __syncthreads();

    float acc = 0.f;
#pragma unroll
    for (int sl = 0; sl < 32; ++sl) {
      f32x4 k4 = *(const f32x4*)&ch[lane * 128 + ((sl ^ lx) << 2)];
      f32x4 q4 = *(const f32x4*)&q_s[g * 128 + sl * 4];
      acc = fmaf(q4[0], k4[0], acc);
      acc = fmaf(q4[1], k4[1], acc);
      acc = fmaf(q4[2], k4[2], acc);
      acc = fmaf(q4[3], k4[3], acc);
    }
    float sv = att ? acc * SCALEc : -INFINITY;
    float cm = sv;
#pragma unroll
    for (int off = 32; off; off >>= 1) cm = fmaxf(cm, __shfl_xor(cm, off));
    float nm = fmaxf(run_m, cm);
    float resc = (run_m == -INFINITY) ? 0.f : __expf(run_m - nm);
    float e = att ? __expf(sv - nm) : 0.f;
    float cl = e;
#pragma unroll
    for (int off = 32; off; off >>= 1) cl += __shfl_xor(cl, off);
    run_l = run_l * resc + cl;
    run_m = nm;
    p_s[g][lane] = e;
    ox *= resc;
    oy *= resc;
    __syncthreads();  // QK reads done before V overwrite
    for (int i = tid; i < 2048; i += 256) {
      int j = i >> 5, sl = i & 31;
      f32x4 v4 = *(const f32x4*)(vbase + (brow + s0 + j) * 3200 + sl * 4);
      *(f32x4*)&ch[j * 128 + ((sl ^ (j & 7)) << 2)] = v4;
    }
    __syncthreads();

    const int jmax = min(64, t - s0 + 1);
    for (int j = 0; j < jmax; ++j) {
      float pj = p_s[g][j];
      const float* vp = &ch[j * 128 + (((slotd ^ (j & 7)) << 2) | wi)];
      ox = fmaf(pj, vp[0], ox);
      oy = fmaf(pj, vp[1], oy);
    }
  }

  const float inv_l = 1.f / fmaxf(run_l, 1e-9f);
  const int h = g * NKVc + kv;
  const float gg = kvproj[(size_t)(b * Tc + t) * 3200 + 3072 + h * 3 + (MODE == 0 ? 1 : 2)];
  const size_t obase = ((size_t)(b * NQc + h) * Tc + t) * 128 + lane * 2;
  float2 o2 = *(float2*)&out[obase];
  o2.x += gg * ox * inv_l;
  o2.y += gg * oy * inv_l;
  *(float2*)&out[obase] = o2;
}

extern "C" void kernel_launch(void* const* d_in, const int* in_sizes, int n_in,
                              void* d_out, int out_size, void* d_ws, size_t ws_size,
                              hipStream_t stream) {
  const float* x = (const float*)d_in[0];
  const float* q = (const float*)d_in[1];
  const float* gate_w = (const float*)d_in[2];
  const float* gate_b = (const float*)d_in[3];
  const float* wk_cmp = (const float*)d_in[4];
  const float* wv_cmp = (const float*)d_in[5];
  const float* wk_slc = (const float*)d_in[6];
  const float* wv_slc = (const float*)d_in[7];
  const float* wk_win = (const float*)d_in[8];
  const float* wv_win = (const float*)d_in[9];
  const float* block_pos = (const float*)d_in[10];
  const float* ck1_w = (const float*)d_in[11];
  const float* ck1_b = (const float*)d_in[12];
  const float* ck2_w = (const float*)d_in[13];
  const float* ck2_b = (const float*)d_in[14];
  const float* cv1_w = (const float*)d_in[15];
  const float* cv1_b = (const float*)d_in[16];
  const float* cv2_w = (const float*)d_in[17];
  const float* cv2_b = (const float*)d_in[18];
  float* out = (float*)d_out;

  char* wsp = (char*)d_ws;
  // [0, 26214400)               kvproj f32 (2048 x 3200)
  // [26214400, 34603008)        region A: xbf (8.4MB) -> later compress buffers
  // [34603008, 45625856)        region B: Wcat (11.0MB) + bias_cat (12.8KB)
  // [45625856, 45691392)        selB
  float* kvproj = (float*)wsp;
  char* pA = wsp + 26214400;
  char* pB = wsp + 34603008;

  bf16_t* xbf = (bf16_t*)pA;
  float* hk_part = (float*)pA;                 // 4*504*128*4 = 1032192
  float* hv_part = (float*)(pA + 1032192);
  float* hk      = (float*)(pA + 2064384);     // 258048
  float* hv      = (float*)(pA + 2322432);
  float* k_sum   = (float*)(pA + 2580480);
  float* v_sum   = (float*)(pA + 2838528);
  float* bias_k  = (float*)(pA + 3096576);     // 512
  float* bias_v  = (float*)(pA + 3097088);

  bf16_t* Wcat = (bf16_t*)pB;                  // 2688*2048*2 = 11010048
  float* bias_cat = (float*)(pB + 11010048);   // 3200*4
  unsigned long long* selB = (unsigned long long*)(wsp + 45625856);

  dim3 blk256(256);

  conv_x<<<16384, blk256, 0, stream>>>(x, xbf);
  build_wcat<<<21504, blk256, 0, stream>>>(wv_cmp, wk_slc, wv_slc, wk_win,
                                           wv_win, gate_w, gate_b, Wcat, bias_cat);

  // k_cmp cols 0..511: f32 VALU GEMM (selection-critical path, exact f32)
  gemm_xwt<<<dim3(8, 32, 1), blk256, 0, stream>>>(x, 2048, wk_cmp, 2048, nullptr,
                                                  kvproj, 3200, 2048, 512, 2048);
  // cols 512..3199 (v_cmp, slc, win, gates): bf16 MFMA
  gemm_mfma<<<dim3(21, 16), blk256, 0, stream>>>(xbf, 2048, Wcat, 2048, kvproj,
                                                 3200, bias_cat, 2048, 512);

  rope_kernel<<<dim3(Bc * Tc * NKVc, 3), 64, 0, stream>>>(kvproj);

  // compress: adjusted bias (folds block_pos), fused-gather layer1 split-K x4, gelu, layer2
  bias_adj_kernel<<<dim3(128, 2), blk256, 0, stream>>>(block_pos, ck1_w, ck1_b,
                                                       cv1_w, cv1_b, bias_k, bias_v);
  gemm_cmp1<<<dim3(2, 8, 4), blk256, 0, stream>>>(kvproj, 0, ck1_w, hk_part);
  gemm_cmp1<<<dim3(2, 8, 4), blk256, 0, stream>>>(kvproj, 512, cv1_w, hv_part);
  reduce_gelu<<<252, blk256, 0, stream>>>(hk_part, bias_k, hk);
  reduce_gelu<<<252, blk256, 0, stream>>>(hv_part, bias_v, hv);
  gemm_xwt<<<dim3(2, 8, 1), blk256, 0, stream>>>(hk, 128, ck2_w, 128, ck2_b,
                                                 k_sum, 128, 504, 128, 128);
  gemm_xwt<<<dim3(2, 8, 1), blk256, 0, stream>>>(hv, 128, cv2_w, 128, cv2_b,
                                                 v_sum, 128, 504, 128, 128);

  cmp_attn<<<Bc * NKVc * Tc, blk256, 0, stream>>>(q, k_sum, v_sum, kvproj, out, selB);
  sparse_attn<0><<<Bc * NKVc * Tc, blk256, 0, stream>>>(q, kvproj, 1024, selB, out);
  sparse_attn<1><<<Bc * NKVc * Tc, blk256, 0, stream>>>(q, kvproj, 2048, selB, out);
}

// Round 4
// 827.952 us; speedup vs baseline: 4.8304x; 1.7963x over previous
//
#include <hip/hip_runtime.h>
#include <hip/hip_bf16.h>
#include <math.h>

#define Bc 2
#define Tc 1024
#define DMc 2048
#define NQc 16
#define NKVc 4
#define DHc 128
#define BLKc 32
#define STRIDEc 16
#define TOPNc 16
#define WINc 512
#define NREPc 4
#define NBc 63
#define SCALEc 0.08838834764831843f

typedef unsigned short bf16_t;
typedef short s16x8 __attribute__((ext_vector_type(8)));
typedef float f32x4 __attribute__((ext_vector_type(4)));

__device__ __forceinline__ unsigned short f2bf(float f) {
  unsigned int u = __float_as_uint(f);
  u += 0x7fffu + ((u >> 16) & 1u);
  return (unsigned short)(u >> 16);
}
__device__ __forceinline__ float geluf(float x) {
  return 0.5f * x * (1.0f + erff(x * 0.7071067811865476f));
}
__device__ __forceinline__ void load_lds16(const void* g, void* l) {
  __builtin_amdgcn_global_load_lds(
      (const __attribute__((address_space(1))) void*)g,
      (__attribute__((address_space(3))) void*)l, 16, 0, 0);
}

// ---------- x -> bf16 (for MFMA path) ----------
__global__ void conv_x(const float* __restrict__ x, bf16_t* __restrict__ xbf) {
  size_t i = (size_t)blockIdx.x * 256 + threadIdx.x;  // grid exact: 2048*2048/256
  xbf[i] = f2bf(x[i]);
}

// ---------- concat weights rows 512..3199 into bf16 Wcat (rows 0..2687) ----------
__global__ void build_wcat(
    const float* __restrict__ wv_cmp, const float* __restrict__ wk_slc,
    const float* __restrict__ wv_slc, const float* __restrict__ wk_win,
    const float* __restrict__ wv_win, const float* __restrict__ gate_w,
    const float* __restrict__ gate_b, bf16_t* __restrict__ Wcat,
    float* __restrict__ bias_cat) {
  size_t i = (size_t)blockIdx.x * 256 + threadIdx.x;  // grid exact: 2688*2048/256
  int rr = (int)(i >> 11), c = (int)(i & 2047);
  int r = rr + 512;
  float v = 0.f;
  if (r < 3072) {
    int blk = r >> 9;  // 1..5
    size_t o = (size_t)(r & 511) * 2048 + c;
    if (blk == 1) v = wv_cmp[o];
    else if (blk == 2) v = wk_slc[o];
    else if (blk == 3) v = wv_slc[o];
    else if (blk == 4) v = wk_win[o];
    else v = wv_win[o];
  } else if (r < 3120) {
    v = gate_w[(size_t)(r - 3072) * 2048 + c];
  }
  Wcat[i] = f2bf(v);
  if (c == 0) bias_cat[r] = (r >= 3072 && r < 3120) ? gate_b[r - 3072] : 0.f;
}

// ---------- bf16 MFMA GEMM: C[m, colbase+n] = A[m,:].Wcat[n,:] (+bias; sigmoid cols>=3072)
__global__ __launch_bounds__(256) void gemm_mfma(
    const bf16_t* __restrict__ A, int lda,
    const bf16_t* __restrict__ Bw, int ldb,
    float* __restrict__ C, int ldc, const float* __restrict__ bias,
    int K, int colbase) {
  __shared__ bf16_t As[128 * 32];
  __shared__ bf16_t Bs[128 * 32];
  const int bm = blockIdx.y * 128, bnw = blockIdx.x * 128, bn = colbase + bnw;
  const int tid = threadIdx.x, lane = tid & 63, w = tid >> 6;
  const int wr = (w >> 1) * 64, wc = (w & 1) * 64;

  f32x4 acc[4][4];
#pragma unroll
  for (int i = 0; i < 4; ++i)
#pragma unroll
    for (int j = 0; j < 4; ++j) acc[i][j] = 0.f;

  const int srow = lane >> 2;
  const int sslot = lane & 3;

  for (int k0 = 0; k0 < K; k0 += 32) {
    __syncthreads();
#pragma unroll
    for (int j = 0; j < 2; ++j) {
      int rb = w * 32 + j * 16;
      int row = rb + srow;
      int slot = sslot ^ ((row >> 1) & 3);
      load_lds16(A + (size_t)(bm + row) * lda + k0 + slot * 8, &As[rb * 32]);
      load_lds16(Bw + (size_t)(bnw + row) * ldb + k0 + slot * 8, &Bs[rb * 32]);
    }
    __syncthreads();

    s16x8 af[4], bfr[4];
#pragma unroll
    for (int i = 0; i < 4; ++i) {
      int ar = wr + i * 16 + (lane & 15);
      int as = ((lane >> 4) ^ ((ar >> 1) & 3)) * 8;
      af[i] = *(const s16x8*)&As[ar * 32 + as];
      int br = wc + i * 16 + (lane & 15);
      int bs = ((lane >> 4) ^ ((br >> 1) & 3)) * 8;
      bfr[i] = *(const s16x8*)&Bs[br * 32 + bs];
    }
#pragma unroll
    for (int i = 0; i < 4; ++i)
#pragma unroll
      for (int j = 0; j < 4; ++j)
        acc[i][j] = __builtin_amdgcn_mfma_f32_16x16x32_bf16(af[i], bfr[j], acc[i][j], 0, 0, 0);
  }

#pragma unroll
  for (int i = 0; i < 4; ++i) {
    int row = bm + wr + i * 16 + ((lane >> 4) << 2);
#pragma unroll
    for (int j = 0; j < 4; ++j) {
      int col = bn + wc + j * 16 + (lane & 15);
      float bv = bias[col];
#pragma unroll
      for (int r = 0; r < 4; ++r) {
        float v = acc[i][j][r] + bv;
        if (col >= 3072) v = 1.f / (1.f + __expf(-v));
        C[(size_t)(row + r) * ldc + col] = v;
      }
    }
  }
}

// ---------- f32 VALU GEMM (split-K via blockIdx.z) ----------
__global__ __launch_bounds__(256) void gemm_xwt(
    const float* __restrict__ A, int lda, const float* __restrict__ W, int ldw,
    const float* __restrict__ bias, float* __restrict__ C, int ldc,
    int M, int N, int K) {
  __shared__ float As[16][68];
  __shared__ float Ws[16][68];
  const int z = blockIdx.z;
  A += (size_t)z * K;
  W += (size_t)z * K;
  C += (size_t)z * (size_t)M * ldc;
  const int bm = blockIdx.y * 64, bn = blockIdx.x * 64;
  const int tid = threadIdx.x;
  const int tx = tid & 15, ty = tid >> 4;
  float acc[4][4] = {{0.f}};
  for (int k0 = 0; k0 < K; k0 += 16) {
#pragma unroll
    for (int i0 = 0; i0 < 4; ++i0) {
      int i = tid + i0 * 256;
      int m = i >> 4, kk = i & 15;
      int gm = bm + m;
      As[kk][m] = (gm < M) ? A[(size_t)gm * lda + (k0 + kk)] : 0.f;
      int gn = bn + m;
      Ws[kk][m] = (gn < N) ? W[(size_t)gn * ldw + (k0 + kk)] : 0.f;
    }
    __syncthreads();
#pragma unroll
    for (int kk = 0; kk < 16; ++kk) {
      float4 a4 = *reinterpret_cast<const float4*>(&As[kk][ty * 4]);
      float4 w4 = *reinterpret_cast<const float4*>(&Ws[kk][tx * 4]);
      float av[4] = {a4.x, a4.y, a4.z, a4.w};
      float wv[4] = {w4.x, w4.y, w4.z, w4.w};
#pragma unroll
      for (int i = 0; i < 4; ++i)
#pragma unroll
        for (int j = 0; j < 4; ++j) acc[i][j] = fmaf(av[i], wv[j], acc[i][j]);
    }
    __syncthreads();
  }
#pragma unroll
  for (int i = 0; i < 4; ++i) {
    int m = bm + ty * 4 + i;
    if (m >= M) continue;
#pragma unroll
    for (int j = 0; j < 4; ++j) {
      int n = bn + tx * 4 + j;
      if (n >= N) continue;
      C[(size_t)m * ldc + n] = acc[i][j] + (bias ? bias[n] : 0.f);
    }
  }
}

// ---------- compress layer1: gathered-A GEMM, split-K x4 ----------
__global__ __launch_bounds__(256) void gemm_cmp1(
    const float* __restrict__ kvproj, int coloff,
    const float* __restrict__ W, float* __restrict__ Cpart) {
  __shared__ float As[16][68];
  __shared__ float Ws[16][68];
  const int z = blockIdx.z;
  const int bm = blockIdx.y * 64, bn = blockIdx.x * 64;
  const int tid = threadIdx.x;
  const int tx = tid & 15, ty = tid >> 4;
  float acc[4][4] = {{0.f}};
  for (int k0 = z * 1024; k0 < z * 1024 + 1024; k0 += 16) {
#pragma unroll
    for (int i0 = 0; i0 < 4; ++i0) {
      int i = tid + i0 * 256;
      int m = i >> 4, kk = i & 15;
      int gm = bm + m;
      float av = 0.f;
      if (gm < 504) {
        int b = gm / 252, rem = gm % 252;
        int n = rem >> 2, kv = rem & 3;
        int f = k0 + kk;
        int j = f >> 7, d = f & 127;
        av = kvproj[(size_t)(b * 1024 + n * 16 + j) * 3200 + coloff + kv * 128 + d];
      }
      As[kk][m] = av;
      Ws[kk][m] = W[(size_t)(bn + m) * 4096 + (k0 + kk)];
    }
    __syncthreads();
#pragma unroll
    for (int kk = 0; kk < 16; ++kk) {
      float4 a4 = *reinterpret_cast<const float4*>(&As[kk][ty * 4]);
      float4 w4 = *reinterpret_cast<const float4*>(&Ws[kk][tx * 4]);
      float av[4] = {a4.x, a4.y, a4.z, a4.w};
      float wv[4] = {w4.x, w4.y, w4.z, w4.w};
#pragma unroll
      for (int i = 0; i < 4; ++i)
#pragma unroll
        for (int j = 0; j < 4; ++j) acc[i][j] = fmaf(av[i], wv[j], acc[i][j]);
    }
    __syncthreads();
  }
#pragma unroll
  for (int i = 0; i < 4; ++i) {
    int m = bm + ty * 4 + i;
    if (m >= 504) continue;
#pragma unroll
    for (int j = 0; j < 4; ++j) {
      int n = bn + tx * 4 + j;
      Cpart[(size_t)z * 64512 + (size_t)m * 128 + n] = acc[i][j];
    }
  }
}

// ---------- bias_adj[o] = b1[o] + block_pos_flat . w1[o,:] ----------
__global__ void bias_adj_kernel(const float* __restrict__ bp,
                                const float* __restrict__ w1k,
                                const float* __restrict__ b1k,
                                const float* __restrict__ w1v,
                                const float* __restrict__ b1v,
                                float* __restrict__ outk,
                                float* __restrict__ outv) {
  __shared__ float red[4];
  const int o = blockIdx.x;
  const float* w1 = blockIdx.y ? w1v : w1k;
  float s = 0.f;
  for (int i = threadIdx.x; i < 4096; i += 256)
    s += bp[i] * w1[(size_t)o * 4096 + i];
#pragma unroll
  for (int off = 32; off; off >>= 1) s += __shfl_xor(s, off);
  if ((threadIdx.x & 63) == 0) red[threadIdx.x >> 6] = s;
  __syncthreads();
  if (threadIdx.x == 0) {
    float t = red[0] + red[1] + red[2] + red[3];
    if (blockIdx.y) outv[o] = t + b1v[o];
    else outk[o] = t + b1k[o];
  }
}

__global__ void reduce_gelu(const float* __restrict__ parts,
                            const float* __restrict__ bias_adj,
                            float* __restrict__ outp) {
  int i = blockIdx.x * 256 + threadIdx.x;
  float s = parts[i] + parts[64512 + i] + parts[2 * 64512 + i] +
            parts[3 * 64512 + i] + bias_adj[i & 127];
  outp[i] = geluf(s);
}

// ---------- RoPE in place on kvproj k-slices ----------
__global__ void rope_kernel(float* __restrict__ kvproj) {
  int blk = blockIdx.x;
  int coloff = blockIdx.y << 10;
  int kv = blk & 3;
  int t = (blk >> 2) & (Tc - 1);
  int b = blk >> 12;
  float* p = kvproj + (size_t)(b * Tc + t) * 3200 + coloff + kv * 128;
  int d = threadIdx.x;
  float inv = powf(10000.f, -(float)d * (1.f / 64.f));
  float ang = (float)t * inv;
  float s, c;
  sincosf(ang, &s, &c);
  float x1 = p[d], x2 = p[d + 64];
  p[d] = x1 * c - x2 * s;
  p[d + 64] = x1 * s + x2 * c;
}

// ---------- compressed attention + top-k selection (unchanged) ----------
__global__ __launch_bounds__(256) void cmp_attn(
    const float* __restrict__ q, const float* __restrict__ k_sum,
    const float* __restrict__ v_sum, const float* __restrict__ kvproj,
    float* __restrict__ out, unsigned long long* __restrict__ sel) {
  __shared__ __align__(16) float q_s[NREPc * 128];
  __shared__ __align__(16) float ks[NBc * 128];
  __shared__ float p_s[NREPc][64];

  const int wg = blockIdx.x;
  const int t = wg & (Tc - 1);
  const int kv = (wg >> 10) & 3;
  const int b = wg >> 12;
  const int tid = threadIdx.x;
  const int lane = tid & 63;
  const int g = tid >> 6;

  for (int i = tid; i < NREPc * 128; i += 256) {
    int gg = i >> 7, d = i & 127;
    q_s[i] = q[(((size_t)b * NQc + gg * NKVc + kv) * Tc + t) * 128 + d];
  }
  {
    const float* kbase = k_sum + (size_t)(b * 252 + kv) * 128;
    for (int i = tid; i < NBc * 32; i += 256) {
      int n = i >> 5, s = i & 31;
      f32x4 v4 = *(const f32x4*)(kbase + (size_t)n * 512 + s * 4);
      *(f32x4*)&ks[n * 128 + ((s ^ (n & 7)) << 2)] = v4;
    }
  }
  __syncthreads();

  const int nvalid = min(t / STRIDEc + 1, NBc);

  float acc = 0.f;
  {
    const int lrow = (lane < 63) ? lane : 62;
    const int lx = lrow & 7;
#pragma unroll
    for (int s = 0; s < 32; ++s) {
      f32x4 k4 = *(const f32x4*)&ks[lrow * 128 + ((s ^ lx) << 2)];
      f32x4 q4 = *(const f32x4*)&q_s[g * 128 + s * 4];
      acc = fmaf(q4[0], k4[0], acc);
      acc = fmaf(q4[1], k4[1], acc);
      acc = fmaf(q4[2], k4[2], acc);
      acc = fmaf(q4[3], k4[3], acc);
    }
  }
  const bool valid = (lane < nvalid);
  float sval = valid ? acc * SCALEc : -INFINITY;
  float m = sval;
#pragma unroll
  for (int off = 32; off; off >>= 1) m = fmaxf(m, __shfl_xor(m, off));
  float e = valid ? __expf(sval - m) : 0.f;
  float l = e;
#pragma unroll
  for (int off = 32; off; off >>= 1) l += __shfl_xor(l, off);
  p_s[g][lane] = e / fmaxf(l, 1e-9f);
  __syncthreads();

  if (g == 0) {
    float v = p_s[0][lane] + p_s[1][lane] + p_s[2][lane] + p_s[3][lane];
    if (lane >= NBc) v = -1.f;
    unsigned long long mask = 0ull;
    for (int it = 0; it < TOPNc; ++it) {
      float mx = v;
#pragma unroll
      for (int off = 32; off; off >>= 1) mx = fmaxf(mx, __shfl_xor(mx, off));
      unsigned long long ball = __ballot(v == mx);
      int sl = __ffsll(ball) - 1;
      mask |= 1ull << sl;
      if (lane == sl) v = -1.f;
    }
    if (lane == 0) sel[wg] = mask;
  }
  __syncthreads();

  {
    const float* vbase = v_sum + (size_t)(b * 252 + kv) * 128;
    for (int i = tid; i < NBc * 32; i += 256) {
      int n = i >> 5, s = i & 31;
      f32x4 v4 = *(const f32x4*)(vbase + (size_t)n * 512 + s * 4);
      *(f32x4*)&ks[n * 128 + ((s ^ (n & 7)) << 2)] = v4;
    }
  }
  __syncthreads();

  const int h = g * NKVc + kv;
  const float g0 = kvproj[(size_t)(b * Tc + t) * 3200 + 3072 + h * 3];
  float ox = 0.f, oy = 0.f;
  const int slotd = lane >> 1, wi = (lane & 1) * 2;
  for (int n = 0; n < nvalid; ++n) {
    float pn = p_s[g][n];
    const float* vp = &ks[n * 128 + (((slotd ^ (n & 7)) << 2) | wi)];
    ox = fmaf(pn, vp[0], ox);
    oy = fmaf(pn, vp[1], oy);
  }
  size_t obase = ((size_t)(b * NQc + h) * Tc + t) * 128 + lane * 2;
  *(float2*)&out[obase] = make_float2(g0 * ox, g0 * oy);
}

// ---------- MFMA flash-tile selected (MODE 0) / windowed (MODE 1) attention ----------
// wg = (b*4+kv)*64 + tt : 16 consecutive t, 4 waves = 4 heads.
template <int MODE>
__global__ __launch_bounds__(256) void sparse_attn_mfma(
    const float* __restrict__ q, const float* __restrict__ kvproj, int colbase,
    const unsigned long long* __restrict__ sel, float* __restrict__ out) {
  __shared__ bf16_t Ks[64 * 128];    // [s][d] bf16, 256B rows, swz ^((s&7)<<4)
  __shared__ bf16_t Vt[128 * 64];    // [d][s] bf16, 128B rows, swz ^((d&7)<<4)
  __shared__ bf16_t Ps[4][16 * 64];  // per-wave P [t][s], 128B rows, swz ^((t&7)<<4)

  const int wg = blockIdx.x;
  const int tt = wg & 63;
  const int kv = (wg >> 6) & 3;
  const int b = wg >> 8;
  const int t0 = tt * 16;
  const int tid = threadIdx.x, lane = tid & 63, g = tid >> 6;
  const int h = g * NKVc + kv;
  const int lr = lane >> 4;  // 0..3
  const int lc = lane & 15;  // 0..15

  // Q fragments: aq[ks] holds Q[t=t0+lc][k=ks*32+lr*8 .. +7] as bf16
  s16x8 aq[4];
  {
    const float* qrow = q + (((size_t)(b * NQc + h) * Tc) + t0 + lc) * 128;
#pragma unroll
    for (int ks = 0; ks < 4; ++ks) {
      f32x4 lo = *(const f32x4*)(qrow + ks * 32 + lr * 8);
      f32x4 hi = *(const f32x4*)(qrow + ks * 32 + lr * 8 + 4);
      s16x8 v;
#pragma unroll
      for (int e = 0; e < 4; ++e) {
        v[e] = (short)f2bf(lo[e]);
        v[e + 4] = (short)f2bf(hi[e]);
      }
      aq[ks] = v;
    }
  }

  unsigned long long hm[4];
  unsigned long long um = 0ull;
  int c0;
  const int c1 = (t0 + 15) >> 6;
  if (MODE == 0) {
    const unsigned long long* sb = sel + ((size_t)(b * NKVc + kv) << 10);
#pragma unroll
    for (int r = 0; r < 4; ++r) {
      unsigned long long bm = sb[t0 + lr * 4 + r];
      hm[r] = bm | (bm << 1);  // token s attended iff hm bit (s>>4)
      um |= hm[r];
    }
    um |= __shfl_xor(um, 16);
    um |= __shfl_xor(um, 32);
    c0 = (__ffsll(um) - 1) >> 2;
  } else {
    int lo = t0 - (WINc - 1);
    c0 = (lo > 0 ? lo : 0) >> 6;
  }

  float run_m[4], run_l[4];
  f32x4 acc_o[8];
#pragma unroll
  for (int r = 0; r < 4; ++r) {
    run_m[r] = -INFINITY;
    run_l[r] = 0.f;
  }
#pragma unroll
  for (int j = 0; j < 8; ++j) acc_o[j] = 0.f;

  const float* kg = kvproj + colbase + kv * 128;
  const float* vg = kg + 512;
  const size_t rbase = (size_t)b * Tc;

  for (int c = c0; c <= c1; ++c) {
    if (MODE == 0 && ((um >> (4 * c)) & 0xFull) == 0ull) continue;
    const int s0 = c * 64;

    __syncthreads();  // prior chunk's LDS reads done
    // stage K: s=idx>>5 (token), c4=idx&31 (4-dim group)
    for (int idx = tid; idx < 2048; idx += 256) {
      int s = idx >> 5, c4 = idx & 31;
      f32x4 v4 = *(const f32x4*)(kg + (rbase + s0 + s) * 3200 + c4 * 4);
      ushort4 wv;
      wv.x = f2bf(v4[0]);
      wv.y = f2bf(v4[1]);
      wv.z = f2bf(v4[2]);
      wv.w = f2bf(v4[3]);
      *(ushort4*)((char*)Ks + ((s * 256 + c4 * 8) ^ ((s & 7) << 4))) = wv;
    }
    // stage V transposed: d=idx&127 (lane-consecutive -> coalesced), sg=idx>>7
    for (int idx = tid; idx < 1024; idx += 256) {
      int sg = idx >> 7, d = idx & 127;
      unsigned short wv[8];
#pragma unroll
      for (int e = 0; e < 8; ++e)
        wv[e] = f2bf(vg[(rbase + s0 + sg * 8 + e) * 3200 + d]);
      *(s16x8*)((char*)Vt + ((d * 128 + sg * 16) ^ ((d & 7) << 4))) = *(s16x8*)wv;
    }
    __syncthreads();

    // QK^T: S[16 t][64 s] per wave
    f32x4 accs[4];
#pragma unroll
    for (int j = 0; j < 4; ++j) accs[j] = 0.f;
#pragma unroll
    for (int ks = 0; ks < 4; ++ks) {
      s16x8 bk[4];
#pragma unroll
      for (int j = 0; j < 4; ++j) {
        int sB = j * 16 + lc;
        bk[j] = *(const s16x8*)((const char*)Ks +
                                ((sB * 256 + (ks * 4 + lr) * 16) ^ ((sB & 7) << 4)));
      }
#pragma unroll
      for (int j = 0; j < 4; ++j)
        accs[j] = __builtin_amdgcn_mfma_f32_16x16x32_bf16(aq[ks], bk[j], accs[j], 0, 0, 0);
    }

    // mask + online softmax per row; write P (unnormalized e) to per-wave LDS
#pragma unroll
    for (int r = 0; r < 4; ++r) {
      const int t = t0 + lr * 4 + r;
      float ev[4];
      float mx = -INFINITY;
#pragma unroll
      for (int j = 0; j < 4; ++j) {
        int s = s0 + j * 16 + lc;
        bool att;
        if (MODE == 0) att = (s <= t) && ((hm[r] >> (s >> 4)) & 1ull);
        else att = (s <= t) && (t - s < WINc);
        float sv = att ? accs[j][r] * SCALEc : -INFINITY;
        ev[j] = sv;
        mx = fmaxf(mx, sv);
      }
      mx = fmaxf(mx, __shfl_xor(mx, 1));
      mx = fmaxf(mx, __shfl_xor(mx, 2));
      mx = fmaxf(mx, __shfl_xor(mx, 4));
      mx = fmaxf(mx, __shfl_xor(mx, 8));
      const float nm = fmaxf(run_m[r], mx);
      const float resc = (run_m[r] == -INFINITY) ? 0.f : __expf(run_m[r] - nm);
      float cl = 0.f;
#pragma unroll
      for (int j = 0; j < 4; ++j) {
        float e = (ev[j] == -INFINITY) ? 0.f : __expf(ev[j] - nm);
        ev[j] = e;
        cl += e;
      }
      cl += __shfl_xor(cl, 1);
      cl += __shfl_xor(cl, 2);
      cl += __shfl_xor(cl, 4);
      cl += __shfl_xor(cl, 8);
      run_l[r] = run_l[r] * resc + cl;
      run_m[r] = nm;
#pragma unroll
      for (int jo = 0; jo < 8; ++jo) acc_o[jo][r] *= resc;
      const int row = lr * 4 + r;
#pragma unroll
      for (int j = 0; j < 4; ++j) {
        int col = j * 16 + lc;
        *(bf16_t*)((char*)Ps[g] + ((row * 128 + col * 2) ^ ((row & 7) << 4))) =
            f2bf(ev[j]);
      }
    }

    // PV: O[16 t][128 d] += P . V   (P writes are same-wave; LDS pipe in-order,
    // belt-and-braces wait below)
    asm volatile("s_waitcnt lgkmcnt(0)" ::: "memory");
    __builtin_amdgcn_sched_barrier(0);
    s16x8 ap[2];
#pragma unroll
    for (int k2 = 0; k2 < 2; ++k2)
      ap[k2] = *(const s16x8*)((const char*)Ps[g] +
                               ((lc * 128 + k2 * 64 + lr * 16) ^ ((lc & 7) << 4)));
#pragma unroll
    for (int k2 = 0; k2 < 2; ++k2) {
#pragma unroll
      for (int jo = 0; jo < 8; ++jo) {
        int d = jo * 16 + lc;
        s16x8 bv = *(const s16x8*)((const char*)Vt +
                                   ((d * 128 + k2 * 64 + lr * 16) ^ ((d & 7) << 4)));
        acc_o[jo] = __builtin_amdgcn_mfma_f32_16x16x32_bf16(ap[k2], bv, acc_o[jo], 0, 0, 0);
      }
    }
  }

  // epilogue: accumulate gated, normalized O into out
#pragma unroll
  for (int r = 0; r < 4; ++r) {
    const int t = t0 + lr * 4 + r;
    const float gg =
        kvproj[(rbase + t) * 3200 + 3072 + h * 3 + (MODE == 0 ? 1 : 2)];
    const float sc = gg / fmaxf(run_l[r], 1e-9f);
    const size_t ob = ((size_t)(b * NQc + h) * Tc + t) * 128;
#pragma unroll
    for (int jo = 0; jo < 8; ++jo) {
      size_t oi = ob + jo * 16 + lc;
      out[oi] += acc_o[jo][r] * sc;
    }
  }
}

extern "C" void kernel_launch(void* const* d_in, const int* in_sizes, int n_in,
                              void* d_out, int out_size, void* d_ws, size_t ws_size,
                              hipStream_t stream) {
  const float* x = (const float*)d_in[0];
  const float* q = (const float*)d_in[1];
  const float* gate_w = (const float*)d_in[2];
  const float* gate_b = (const float*)d_in[3];
  const float* wk_cmp = (const float*)d_in[4];
  const float* wv_cmp = (const float*)d_in[5];
  const float* wk_slc = (const float*)d_in[6];
  const float* wv_slc = (const float*)d_in[7];
  const float* wk_win = (const float*)d_in[8];
  const float* wv_win = (const float*)d_in[9];
  const float* block_pos = (const float*)d_in[10];
  const float* ck1_w = (const float*)d_in[11];
  const float* ck1_b = (const float*)d_in[12];
  const float* ck2_w = (const float*)d_in[13];
  const float* ck2_b = (const float*)d_in[14];
  const float* cv1_w = (const float*)d_in[15];
  const float* cv1_b = (const float*)d_in[16];
  const float* cv2_w = (const float*)d_in[17];
  const float* cv2_b = (const float*)d_in[18];
  float* out = (float*)d_out;

  char* wsp = (char*)d_ws;
  float* kvproj = (float*)wsp;                 // 2048*3200*4 = 26,214,400
  char* pA = wsp + 26214400;
  char* pB = wsp + 34603008;

  bf16_t* xbf = (bf16_t*)pA;
  float* hk_part = (float*)pA;
  float* hv_part = (float*)(pA + 1032192);
  float* hk = (float*)(pA + 2064384);
  float* hv = (float*)(pA + 2322432);
  float* k_sum = (float*)(pA + 2580480);
  float* v_sum = (float*)(pA + 2838528);
  float* bias_k = (float*)(pA + 3096576);
  float* bias_v = (float*)(pA + 3097088);

  bf16_t* Wcat = (bf16_t*)pB;                  // 2688*2048*2
  float* bias_cat = (float*)(pB + 11010048);
  unsigned long long* selB = (unsigned long long*)(wsp + 45625856);

  dim3 blk256(256);

  conv_x<<<16384, blk256, 0, stream>>>(x, xbf);
  build_wcat<<<21504, blk256, 0, stream>>>(wv_cmp, wk_slc, wv_slc, wk_win,
                                           wv_win, gate_w, gate_b, Wcat, bias_cat);

  gemm_xwt<<<dim3(8, 32, 1), blk256, 0, stream>>>(x, 2048, wk_cmp, 2048, nullptr,
                                                  kvproj, 3200, 2048, 512, 2048);
  gemm_mfma<<<dim3(21, 16), blk256, 0, stream>>>(xbf, 2048, Wcat, 2048, kvproj,
                                                 3200, bias_cat, 2048, 512);

  rope_kernel<<<dim3(Bc * Tc * NKVc, 3), 64, 0, stream>>>(kvproj);

  bias_adj_kernel<<<dim3(128, 2), blk256, 0, stream>>>(block_pos, ck1_w, ck1_b,
                                                       cv1_w, cv1_b, bias_k, bias_v);
  gemm_cmp1<<<dim3(2, 8, 4), blk256, 0, stream>>>(kvproj, 0, ck1_w, hk_part);
  gemm_cmp1<<<dim3(2, 8, 4), blk256, 0, stream>>>(kvproj, 512, cv1_w, hv_part);
  reduce_gelu<<<252, blk256, 0, stream>>>(hk_part, bias_k, hk);
  reduce_gelu<<<252, blk256, 0, stream>>>(hv_part, bias_v, hv);
  gemm_xwt<<<dim3(2, 8, 1), blk256, 0, stream>>>(hk, 128, ck2_w, 128, ck2_b,
                                                 k_sum, 128, 504, 128, 128);
  gemm_xwt<<<dim3(2, 8, 1), blk256, 0, stream>>>(hv, 128, cv2_w, 128, cv2_b,
                                                 v_sum, 128, 504, 128, 128);

  cmp_attn<<<Bc * NKVc * Tc, blk256, 0, stream>>>(q, k_sum, v_sum, kvproj, out, selB);
  sparse_attn_mfma<0><<<512, blk256, 0, stream>>>(q, kvproj, 1024, selB, out);
  sparse_attn_mfma<1><<<512, blk256, 0, stream>>>(q, kvproj, 2048, selB, out);
}

// Round 5
// 460.293 us; speedup vs baseline: 8.6887x; 1.7987x over previous
//
#include <hip/hip_runtime.h>
#include <hip/hip_bf16.h>
#include <math.h>

#define Bc 2
#define Tc 1024
#define DMc 2048
#define NQc 16
#define NKVc 4
#define DHc 128
#define BLKc 32
#define STRIDEc 16
#define TOPNc 16
#define WINc 512
#define NREPc 4
#define NBc 63
#define SCALEc 0.08838834764831843f

typedef unsigned short bf16_t;
typedef short s16x8 __attribute__((ext_vector_type(8)));
typedef float f32x4 __attribute__((ext_vector_type(4)));

__device__ __forceinline__ unsigned short f2bf(float f) {
  unsigned int u = __float_as_uint(f);
  u += 0x7fffu + ((u >> 16) & 1u);
  return (unsigned short)(u >> 16);
}
__device__ __forceinline__ float geluf(float x) {
  return 0.5f * x * (1.0f + erff(x * 0.7071067811865476f));
}
__device__ __forceinline__ void load_lds16(const void* g, void* l) {
  __builtin_amdgcn_global_load_lds(
      (const __attribute__((address_space(1))) void*)g,
      (__attribute__((address_space(3))) void*)l, 16, 0, 0);
}

// ---------- x -> bf16 ----------
__global__ void conv_x(const float* __restrict__ x, bf16_t* __restrict__ xbf) {
  size_t i = (size_t)blockIdx.x * 256 + threadIdx.x;  // exact: 2048*2048/256
  xbf[i] = f2bf(x[i]);
}

// ---------- concat weights rows 512..3199 into bf16 Wcat ----------
__global__ void build_wcat(
    const float* __restrict__ wv_cmp, const float* __restrict__ wk_slc,
    const float* __restrict__ wv_slc, const float* __restrict__ wk_win,
    const float* __restrict__ wv_win, const float* __restrict__ gate_w,
    const float* __restrict__ gate_b, bf16_t* __restrict__ Wcat,
    float* __restrict__ bias_cat) {
  size_t i = (size_t)blockIdx.x * 256 + threadIdx.x;  // exact: 2688*2048/256
  int rr = (int)(i >> 11), c = (int)(i & 2047);
  int r = rr + 512;
  float v = 0.f;
  if (r < 3072) {
    int blk = r >> 9;  // 1..5
    size_t o = (size_t)(r & 511) * 2048 + c;
    if (blk == 1) v = wv_cmp[o];
    else if (blk == 2) v = wk_slc[o];
    else if (blk == 3) v = wv_slc[o];
    else if (blk == 4) v = wk_win[o];
    else v = wv_win[o];
  } else if (r < 3120) {
    v = gate_w[(size_t)(r - 3072) * 2048 + c];
  }
  Wcat[i] = f2bf(v);
  if (c == 0) bias_cat[r] = (r >= 3072 && r < 3120) ? gate_b[r - 3072] : 0.f;
}

// ---------- bf16 MFMA GEMM (cols 512..3199 of kvproj) ----------
__global__ __launch_bounds__(256) void gemm_mfma(
    const bf16_t* __restrict__ A, int lda,
    const bf16_t* __restrict__ Bw, int ldb,
    float* __restrict__ C, int ldc, const float* __restrict__ bias,
    int K, int colbase) {
  __shared__ bf16_t As[128 * 32];
  __shared__ bf16_t Bs[128 * 32];
  const int bm = blockIdx.y * 128, bnw = blockIdx.x * 128, bn = colbase + bnw;
  const int tid = threadIdx.x, lane = tid & 63, w = tid >> 6;
  const int wr = (w >> 1) * 64, wc = (w & 1) * 64;

  f32x4 acc[4][4];
#pragma unroll
  for (int i = 0; i < 4; ++i)
#pragma unroll
    for (int j = 0; j < 4; ++j) acc[i][j] = 0.f;

  const int srow = lane >> 2;
  const int sslot = lane & 3;

  for (int k0 = 0; k0 < K; k0 += 32) {
    __syncthreads();
#pragma unroll
    for (int j = 0; j < 2; ++j) {
      int rb = w * 32 + j * 16;
      int row = rb + srow;
      int slot = sslot ^ ((row >> 1) & 3);
      load_lds16(A + (size_t)(bm + row) * lda + k0 + slot * 8, &As[rb * 32]);
      load_lds16(Bw + (size_t)(bnw + row) * ldb + k0 + slot * 8, &Bs[rb * 32]);
    }
    __syncthreads();

    s16x8 af[4], bfr[4];
#pragma unroll
    for (int i = 0; i < 4; ++i) {
      int ar = wr + i * 16 + (lane & 15);
      int as = ((lane >> 4) ^ ((ar >> 1) & 3)) * 8;
      af[i] = *(const s16x8*)&As[ar * 32 + as];
      int br = wc + i * 16 + (lane & 15);
      int bs = ((lane >> 4) ^ ((br >> 1) & 3)) * 8;
      bfr[i] = *(const s16x8*)&Bs[br * 32 + bs];
    }
#pragma unroll
    for (int i = 0; i < 4; ++i)
#pragma unroll
      for (int j = 0; j < 4; ++j)
        acc[i][j] = __builtin_amdgcn_mfma_f32_16x16x32_bf16(af[i], bfr[j], acc[i][j], 0, 0, 0);
  }

#pragma unroll
  for (int i = 0; i < 4; ++i) {
    int row = bm + wr + i * 16 + ((lane >> 4) << 2);
#pragma unroll
    for (int j = 0; j < 4; ++j) {
      int col = bn + wc + j * 16 + (lane & 15);
      float bv = bias[col];
#pragma unroll
      for (int r = 0; r < 4; ++r) {
        float v = acc[i][j][r] + bv;
        if (col >= 3072) v = 1.f / (1.f + __expf(-v));
        C[(size_t)(row + r) * ldc + col] = v;
      }
    }
  }
}

// ---------- f32 VALU GEMM (split-K partials via blockIdx.z) ----------
__global__ __launch_bounds__(256) void gemm_xwt(
    const float* __restrict__ A, int lda, const float* __restrict__ W, int ldw,
    const float* __restrict__ bias, float* __restrict__ C, int ldc,
    int M, int N, int K) {
  __shared__ float As[16][68];
  __shared__ float Ws[16][68];
  const int z = blockIdx.z;
  A += (size_t)z * K;
  W += (size_t)z * K;
  C += (size_t)z * (size_t)M * ldc;
  const int bm = blockIdx.y * 64, bn = blockIdx.x * 64;
  const int tid = threadIdx.x;
  const int tx = tid & 15, ty = tid >> 4;
  float acc[4][4] = {{0.f}};
  for (int k0 = 0; k0 < K; k0 += 16) {
#pragma unroll
    for (int i0 = 0; i0 < 4; ++i0) {
      int i = tid + i0 * 256;
      int m = i >> 4, kk = i & 15;
      int gm = bm + m;
      As[kk][m] = (gm < M) ? A[(size_t)gm * lda + (k0 + kk)] : 0.f;
      int gn = bn + m;
      Ws[kk][m] = (gn < N) ? W[(size_t)gn * ldw + (k0 + kk)] : 0.f;
    }
    __syncthreads();
#pragma unroll
    for (int kk = 0; kk < 16; ++kk) {
      float4 a4 = *reinterpret_cast<const float4*>(&As[kk][ty * 4]);
      float4 w4 = *reinterpret_cast<const float4*>(&Ws[kk][tx * 4]);
      float av[4] = {a4.x, a4.y, a4.z, a4.w};
      float wv[4] = {w4.x, w4.y, w4.z, w4.w};
#pragma unroll
      for (int i = 0; i < 4; ++i)
#pragma unroll
        for (int j = 0; j < 4; ++j) acc[i][j] = fmaf(av[i], wv[j], acc[i][j]);
    }
    __syncthreads();
  }
#pragma unroll
  for (int i = 0; i < 4; ++i) {
    int m = bm + ty * 4 + i;
    if (m >= M) continue;
#pragma unroll
    for (int j = 0; j < 4; ++j) {
      int n = bn + tx * 4 + j;
      if (n >= N) continue;
      C[(size_t)m * ldc + n] = acc[i][j] + (bias ? bias[n] : 0.f);
    }
  }
}

// ---------- reduce 4 k_cmp partials -> kvproj cols 0..511 ----------
__global__ void reduce_k(const float* __restrict__ part, float* __restrict__ kvproj) {
  int i = blockIdx.x * 256 + threadIdx.x;  // exact: 2048*512/256
  int m = i >> 9, n = i & 511;
  kvproj[(size_t)m * 3200 + n] =
      part[i] + part[1048576 + i] + part[2097152 + i] + part[3145728 + i];
}

// ---------- compress layer1: gathered-A GEMM, split-K x16, k&v merged ----------
__global__ __launch_bounds__(256) void gemm_cmp1(
    const float* __restrict__ kvproj,
    const float* __restrict__ ck1_w, const float* __restrict__ cv1_w,
    float* __restrict__ hk_part, float* __restrict__ hv_part) {
  __shared__ float As[16][68];
  __shared__ float Ws[16][68];
  const int zz = blockIdx.z;
  const bool isv = zz >= 16;
  const int z = zz & 15;
  const int coloff = isv ? 512 : 0;
  const float* W = isv ? cv1_w : ck1_w;
  float* Cpart = isv ? hv_part : hk_part;
  const int bm = blockIdx.y * 64, bn = blockIdx.x * 64;
  const int tid = threadIdx.x;
  const int tx = tid & 15, ty = tid >> 4;
  float acc[4][4] = {{0.f}};
  for (int k0 = z * 256; k0 < z * 256 + 256; k0 += 16) {
#pragma unroll
    for (int i0 = 0; i0 < 4; ++i0) {
      int i = tid + i0 * 256;
      int m = i >> 4, kk = i & 15;
      int gm = bm + m;
      float av = 0.f;
      if (gm < 504) {
        int b = gm / 252, rem = gm % 252;
        int n = rem >> 2, kv = rem & 3;
        int f = k0 + kk;
        int j = f >> 7, d = f & 127;
        av = kvproj[(size_t)(b * 1024 + n * 16 + j) * 3200 + coloff + kv * 128 + d];
      }
      As[kk][m] = av;
      Ws[kk][m] = W[(size_t)(bn + m) * 4096 + (k0 + kk)];
    }
    __syncthreads();
#pragma unroll
    for (int kk = 0; kk < 16; ++kk) {
      float4 a4 = *reinterpret_cast<const float4*>(&As[kk][ty * 4]);
      float4 w4 = *reinterpret_cast<const float4*>(&Ws[kk][tx * 4]);
      float av[4] = {a4.x, a4.y, a4.z, a4.w};
      float wv[4] = {w4.x, w4.y, w4.z, w4.w};
#pragma unroll
      for (int i = 0; i < 4; ++i)
#pragma unroll
        for (int j = 0; j < 4; ++j) acc[i][j] = fmaf(av[i], wv[j], acc[i][j]);
    }
    __syncthreads();
  }
#pragma unroll
  for (int i = 0; i < 4; ++i) {
    int m = bm + ty * 4 + i;
    if (m >= 504) continue;
#pragma unroll
    for (int j = 0; j < 4; ++j) {
      int n = bn + tx * 4 + j;
      Cpart[(size_t)z * 64512 + (size_t)m * 128 + n] = acc[i][j];
    }
  }
}

// ---------- bias_adj[o] = b1[o] + block_pos_flat . w1[o,:] ----------
__global__ void bias_adj_kernel(const float* __restrict__ bp,
                                const float* __restrict__ w1k,
                                const float* __restrict__ b1k,
                                const float* __restrict__ w1v,
                                const float* __restrict__ b1v,
                                float* __restrict__ outk,
                                float* __restrict__ outv) {
  __shared__ float red[4];
  const int o = blockIdx.x;
  const float* w1 = blockIdx.y ? w1v : w1k;
  float s = 0.f;
  for (int i = threadIdx.x; i < 4096; i += 256)
    s += bp[i] * w1[(size_t)o * 4096 + i];
#pragma unroll
  for (int off = 32; off; off >>= 1) s += __shfl_xor(s, off);
  if ((threadIdx.x & 63) == 0) red[threadIdx.x >> 6] = s;
  __syncthreads();
  if (threadIdx.x == 0) {
    float t = red[0] + red[1] + red[2] + red[3];
    if (blockIdx.y) outv[o] = t + b1v[o];
    else outk[o] = t + b1k[o];
  }
}

// ---------- reduce 16 partials + bias + gelu, k&v merged ----------
__global__ void reduce_gelu(const float* __restrict__ hk_part,
                            const float* __restrict__ hv_part,
                            const float* __restrict__ bias_k,
                            const float* __restrict__ bias_v,
                            float* __restrict__ hk, float* __restrict__ hv) {
  int gi = blockIdx.x * 256 + threadIdx.x;  // exact: 2*64512/256
  const bool isv = gi >= 64512;
  int i = isv ? gi - 64512 : gi;
  const float* parts = isv ? hv_part : hk_part;
  float s = (isv ? bias_v : bias_k)[i & 127];
#pragma unroll
  for (int z = 0; z < 16; ++z) s += parts[z * 64512 + i];
  (isv ? hv : hk)[i] = geluf(s);
}

// ---------- compress layer2, k&v merged: 64x64 tiles, M=504,N=128,K=128 ----------
__global__ __launch_bounds__(256) void gemm_l2(
    const float* __restrict__ hk, const float* __restrict__ w2k,
    const float* __restrict__ b2k, const float* __restrict__ hv,
    const float* __restrict__ w2v, const float* __restrict__ b2v,
    float* __restrict__ k_sum, float* __restrict__ v_sum) {
  __shared__ float As[16][68];
  __shared__ float Ws[16][68];
  const bool isv = blockIdx.z != 0;
  const float* A = isv ? hv : hk;
  const float* W = isv ? w2v : w2k;
  const float* bias = isv ? b2v : b2k;
  float* C = isv ? v_sum : k_sum;
  const int bm = blockIdx.y * 64, bn = blockIdx.x * 64;
  const int tid = threadIdx.x;
  const int tx = tid & 15, ty = tid >> 4;
  float acc[4][4] = {{0.f}};
  for (int k0 = 0; k0 < 128; k0 += 16) {
#pragma unroll
    for (int i0 = 0; i0 < 4; ++i0) {
      int i = tid + i0 * 256;
      int m = i >> 4, kk = i & 15;
      int gm = bm + m;
      As[kk][m] = (gm < 504) ? A[(size_t)gm * 128 + (k0 + kk)] : 0.f;
      Ws[kk][m] = W[(size_t)(bn + m) * 128 + (k0 + kk)];
    }
    __syncthreads();
#pragma unroll
    for (int kk = 0; kk < 16; ++kk) {
      float4 a4 = *reinterpret_cast<const float4*>(&As[kk][ty * 4]);
      float4 w4 = *reinterpret_cast<const float4*>(&Ws[kk][tx * 4]);
      float av[4] = {a4.x, a4.y, a4.z, a4.w};
      float wv[4] = {w4.x, w4.y, w4.z, w4.w};
#pragma unroll
      for (int i = 0; i < 4; ++i)
#pragma unroll
        for (int j = 0; j < 4; ++j) acc[i][j] = fmaf(av[i], wv[j], acc[i][j]);
    }
    __syncthreads();
  }
#pragma unroll
  for (int i = 0; i < 4; ++i) {
    int m = bm + ty * 4 + i;
    if (m >= 504) continue;
#pragma unroll
    for (int j = 0; j < 4; ++j) {
      int n = bn + tx * 4 + j;
      C[(size_t)m * 128 + n] = acc[i][j] + bias[n];
    }
  }
}

// ---------- RoPE in place on kvproj k-slices ----------
__global__ void rope_kernel(float* __restrict__ kvproj) {
  int blk = blockIdx.x;
  int coloff = blockIdx.y << 10;
  int kv = blk & 3;
  int t = (blk >> 2) & (Tc - 1);
  int b = blk >> 12;
  float* p = kvproj + (size_t)(b * Tc + t) * 3200 + coloff + kv * 128;
  int d = threadIdx.x;
  float inv = powf(10000.f, -(float)d * (1.f / 64.f));
  float ang = (float)t * inv;
  float s, c;
  sincosf(ang, &s, &c);
  float x1 = p[d], x2 = p[d + 64];
  p[d] = x1 * c - x2 * s;
  p[d + 64] = x1 * s + x2 * c;
}

// ---------- compressed attention + top-k: 4 query tokens per wg ----------
__global__ __launch_bounds__(256) void cmp_attn(
    const float* __restrict__ q, const float* __restrict__ k_sum,
    const float* __restrict__ v_sum, const float* __restrict__ kvproj,
    float* __restrict__ out, unsigned long long* __restrict__ sel) {
  __shared__ __align__(16) float q_s[4][4][128];  // [g][r][d]
  __shared__ __align__(16) float ks[NBc * 128];
  __shared__ float p_s[4][4][64];                 // [g][r][n]

  const int wg = blockIdx.x;  // (b*4+kv)*256 + tq
  const int tq = wg & 255;
  const int kv = (wg >> 8) & 3;
  const int b = wg >> 10;
  const int t0 = tq * 4;
  const int tid = threadIdx.x;
  const int lane = tid & 63;
  const int g = tid >> 6;

  for (int i = tid; i < 2048; i += 256) {
    int gg = i >> 9, r = (i >> 7) & 3, d = i & 127;
    q_s[gg][r][d] = q[(((size_t)b * NQc + gg * NKVc + kv) * Tc + t0 + r) * 128 + d];
  }
  {
    const float* kbase = k_sum + (size_t)(b * 252 + kv) * 128;
    for (int i = tid; i < NBc * 32; i += 256) {
      int n = i >> 5, s = i & 31;
      f32x4 v4 = *(const f32x4*)(kbase + (size_t)n * 512 + s * 4);
      *(f32x4*)&ks[n * 128 + ((s ^ (n & 7)) << 2)] = v4;
    }
  }
  __syncthreads();

  float acc[4] = {0.f, 0.f, 0.f, 0.f};
  {
    const int lrow = (lane < 63) ? lane : 62;
    const int lx = lrow & 7;
#pragma unroll
    for (int s = 0; s < 32; ++s) {
      f32x4 k4 = *(const f32x4*)&ks[lrow * 128 + ((s ^ lx) << 2)];
#pragma unroll
      for (int r = 0; r < 4; ++r) {
        f32x4 q4 = *(const f32x4*)&q_s[g][r][s * 4];
        acc[r] = fmaf(q4[0], k4[0], acc[r]);
        acc[r] = fmaf(q4[1], k4[1], acc[r]);
        acc[r] = fmaf(q4[2], k4[2], acc[r]);
        acc[r] = fmaf(q4[3], k4[3], acc[r]);
      }
    }
  }
#pragma unroll
  for (int r = 0; r < 4; ++r) {
    const int t = t0 + r;
    const int nvalid = min(t / STRIDEc + 1, NBc);
    const bool valid = (lane < nvalid);
    float sval = valid ? acc[r] * SCALEc : -INFINITY;
    float m = sval;
#pragma unroll
    for (int off = 32; off; off >>= 1) m = fmaxf(m, __shfl_xor(m, off));
    float e = valid ? __expf(sval - m) : 0.f;
    float l = e;
#pragma unroll
    for (int off = 32; off; off >>= 1) l += __shfl_xor(l, off);
    p_s[g][r][lane] = e / fmaxf(l, 1e-9f);
  }
  __syncthreads();

  // top-k: wave g handles row r=g (lowest-index tie-break == lax.top_k)
  {
    float v = p_s[0][g][lane] + p_s[1][g][lane] + p_s[2][g][lane] + p_s[3][g][lane];
    if (lane >= NBc) v = -1.f;
    unsigned long long mask = 0ull;
    for (int it = 0; it < TOPNc; ++it) {
      float mx = v;
#pragma unroll
      for (int off = 32; off; off >>= 1) mx = fmaxf(mx, __shfl_xor(mx, off));
      unsigned long long ball = __ballot(v == mx);
      int sl = __ffsll(ball) - 1;
      mask |= 1ull << sl;
      if (lane == sl) v = -1.f;
    }
    if (lane == 0) sel[(((size_t)b * NKVc + kv) << 10) + t0 + g] = mask;
  }
  // stage v_sum over ks (all QK ks-reads completed before last barrier)
  {
    const float* vbase = v_sum + (size_t)(b * 252 + kv) * 128;
    for (int i = tid; i < NBc * 32; i += 256) {
      int n = i >> 5, s = i & 31;
      f32x4 v4 = *(const f32x4*)(vbase + (size_t)n * 512 + s * 4);
      *(f32x4*)&ks[n * 128 + ((s ^ (n & 7)) << 2)] = v4;
    }
  }
  __syncthreads();

  const int h = g * NKVc + kv;
  float ox[4] = {0.f, 0.f, 0.f, 0.f}, oy[4] = {0.f, 0.f, 0.f, 0.f};
  const int slotd = lane >> 1, wi = (lane & 1) * 2;
  const int nvmax = min((t0 + 3) / STRIDEc + 1, NBc);
  for (int n = 0; n < nvmax; ++n) {
    const float* vp = &ks[n * 128 + (((slotd ^ (n & 7)) << 2) | wi)];
    const float vx = vp[0], vy = vp[1];
#pragma unroll
    for (int r = 0; r < 4; ++r) {
      float pn = p_s[g][r][n];  // 0 for n >= nvalid_r
      ox[r] = fmaf(pn, vx, ox[r]);
      oy[r] = fmaf(pn, vy, oy[r]);
    }
  }
#pragma unroll
  for (int r = 0; r < 4; ++r) {
    const int t = t0 + r;
    const float g0 = kvproj[(size_t)(b * Tc + t) * 3200 + 3072 + h * 3];
    size_t obase = ((size_t)(b * NQc + h) * Tc + t) * 128 + lane * 2;
    *(float2*)&out[obase] = make_float2(g0 * ox[r], g0 * oy[r]);
  }
}

// ---------- MFMA flash-tile selected (MODE 0) / windowed (MODE 1) attention ----------
template <int MODE>
__global__ __launch_bounds__(256) void sparse_attn_mfma(
    const float* __restrict__ q, const float* __restrict__ kvproj, int colbase,
    const unsigned long long* __restrict__ sel, float* __restrict__ out) {
  __shared__ bf16_t Ks[64 * 128];
  __shared__ bf16_t Vt[128 * 64];
  __shared__ bf16_t Ps[4][16 * 64];

  const int wg = blockIdx.x;
  const int tt = wg & 63;
  const int kv = (wg >> 6) & 3;
  const int b = wg >> 8;
  const int t0 = tt * 16;
  const int tid = threadIdx.x, lane = tid & 63, g = tid >> 6;
  const int h = g * NKVc + kv;
  const int lr = lane >> 4;
  const int lc = lane & 15;

  s16x8 aq[4];
  {
    const float* qrow = q + (((size_t)(b * NQc + h) * Tc) + t0 + lc) * 128;
#pragma unroll
    for (int ks = 0; ks < 4; ++ks) {
      f32x4 lo = *(const f32x4*)(qrow + ks * 32 + lr * 8);
      f32x4 hi = *(const f32x4*)(qrow + ks * 32 + lr * 8 + 4);
      s16x8 v;
#pragma unroll
      for (int e = 0; e < 4; ++e) {
        v[e] = (short)f2bf(lo[e]);
        v[e + 4] = (short)f2bf(hi[e]);
      }
      aq[ks] = v;
    }
  }

  unsigned long long hm[4];
  unsigned long long um = 0ull;
  int c0;
  const int c1 = (t0 + 15) >> 6;
  if (MODE == 0) {
    const unsigned long long* sb = sel + ((size_t)(b * NKVc + kv) << 10);
#pragma unroll
    for (int r = 0; r < 4; ++r) {
      unsigned long long bm = sb[t0 + lr * 4 + r];
      hm[r] = bm | (bm << 1);
      um |= hm[r];
    }
    um |= __shfl_xor(um, 16);
    um |= __shfl_xor(um, 32);
    c0 = (__ffsll(um) - 1) >> 2;
  } else {
    int lo = t0 - (WINc - 1);
    c0 = (lo > 0 ? lo : 0) >> 6;
  }

  float run_m[4], run_l[4];
  f32x4 acc_o[8];
#pragma unroll
  for (int r = 0; r < 4; ++r) {
    run_m[r] = -INFINITY;
    run_l[r] = 0.f;
  }
#pragma unroll
  for (int j = 0; j < 8; ++j) acc_o[j] = 0.f;

  const float* kg = kvproj + colbase + kv * 128;
  const float* vg = kg + 512;
  const size_t rbase = (size_t)b * Tc;

  for (int c = c0; c <= c1; ++c) {
    if (MODE == 0 && ((um >> (4 * c)) & 0xFull) == 0ull) continue;
    const int s0 = c * 64;

    __syncthreads();
    for (int idx = tid; idx < 2048; idx += 256) {
      int s = idx >> 5, c4 = idx & 31;
      f32x4 v4 = *(const f32x4*)(kg + (rbase + s0 + s) * 3200 + c4 * 4);
      ushort4 wv;
      wv.x = f2bf(v4[0]);
      wv.y = f2bf(v4[1]);
      wv.z = f2bf(v4[2]);
      wv.w = f2bf(v4[3]);
      *(ushort4*)((char*)Ks + ((s * 256 + c4 * 8) ^ ((s & 7) << 4))) = wv;
    }
    for (int idx = tid; idx < 1024; idx += 256) {
      int sg = idx >> 7, d = idx & 127;
      unsigned short wv[8];
#pragma unroll
      for (int e = 0; e < 8; ++e)
        wv[e] = f2bf(vg[(rbase + s0 + sg * 8 + e) * 3200 + d]);
      *(s16x8*)((char*)Vt + ((d * 128 + sg * 16) ^ ((d & 7) << 4))) = *(s16x8*)wv;
    }
    __syncthreads();

    f32x4 accs[4];
#pragma unroll
    for (int j = 0; j < 4; ++j) accs[j] = 0.f;
#pragma unroll
    for (int ks = 0; ks < 4; ++ks) {
      s16x8 bk[4];
#pragma unroll
      for (int j = 0; j < 4; ++j) {
        int sB = j * 16 + lc;
        bk[j] = *(const s16x8*)((const char*)Ks +
                                ((sB * 256 + (ks * 4 + lr) * 16) ^ ((sB & 7) << 4)));
      }
#pragma unroll
      for (int j = 0; j < 4; ++j)
        accs[j] = __builtin_amdgcn_mfma_f32_16x16x32_bf16(aq[ks], bk[j], accs[j], 0, 0, 0);
    }

#pragma unroll
    for (int r = 0; r < 4; ++r) {
      const int t = t0 + lr * 4 + r;
      float ev[4];
      float mx = -INFINITY;
#pragma unroll
      for (int j = 0; j < 4; ++j) {
        int s = s0 + j * 16 + lc;
        bool att;
        if (MODE == 0) att = (s <= t) && ((hm[r] >> (s >> 4)) & 1ull);
        else att = (s <= t) && (t - s < WINc);
        float sv = att ? accs[j][r] * SCALEc : -INFINITY;
        ev[j] = sv;
        mx = fmaxf(mx, sv);
      }
      mx = fmaxf(mx, __shfl_xor(mx, 1));
      mx = fmaxf(mx, __shfl_xor(mx, 2));
      mx = fmaxf(mx, __shfl_xor(mx, 4));
      mx = fmaxf(mx, __shfl_xor(mx, 8));
      const float nm = fmaxf(run_m[r], mx);
      const float resc = (run_m[r] == -INFINITY) ? 0.f : __expf(run_m[r] - nm);
      float cl = 0.f;
#pragma unroll
      for (int j = 0; j < 4; ++j) {
        float e = (ev[j] == -INFINITY) ? 0.f : __expf(ev[j] - nm);
        ev[j] = e;
        cl += e;
      }
      cl += __shfl_xor(cl, 1);
      cl += __shfl_xor(cl, 2);
      cl += __shfl_xor(cl, 4);
      cl += __shfl_xor(cl, 8);
      run_l[r] = run_l[r] * resc + cl;
      run_m[r] = nm;
#pragma unroll
      for (int jo = 0; jo < 8; ++jo) acc_o[jo][r] *= resc;
      const int row = lr * 4 + r;
#pragma unroll
      for (int j = 0; j < 4; ++j) {
        int col = j * 16 + lc;
        *(bf16_t*)((char*)Ps[g] + ((row * 128 + col * 2) ^ ((row & 7) << 4))) =
            f2bf(ev[j]);
      }
    }

    asm volatile("s_waitcnt lgkmcnt(0)" ::: "memory");
    __builtin_amdgcn_sched_barrier(0);
    s16x8 ap[2];
#pragma unroll
    for (int k2 = 0; k2 < 2; ++k2)
      ap[k2] = *(const s16x8*)((const char*)Ps[g] +
                               ((lc * 128 + k2 * 64 + lr * 16) ^ ((lc & 7) << 4)));
#pragma unroll
    for (int k2 = 0; k2 < 2; ++k2) {
#pragma unroll
      for (int jo = 0; jo < 8; ++jo) {
        int d = jo * 16 + lc;
        s16x8 bv = *(const s16x8*)((const char*)Vt +
                                   ((d * 128 + k2 * 64 + lr * 16) ^ ((d & 7) << 4)));
        acc_o[jo] = __builtin_amdgcn_mfma_f32_16x16x32_bf16(ap[k2], bv, acc_o[jo], 0, 0, 0);
      }
    }
  }

#pragma unroll
  for (int r = 0; r < 4; ++r) {
    const int t = t0 + lr * 4 + r;
    const float gg =
        kvproj[(rbase + t) * 3200 + 3072 + h * 3 + (MODE == 0 ? 1 : 2)];
    const float sc = gg / fmaxf(run_l[r], 1e-9f);
    const size_t ob = ((size_t)(b * NQc + h) * Tc + t) * 128;
#pragma unroll
    for (int jo = 0; jo < 8; ++jo) {
      size_t oi = ob + jo * 16 + lc;
      out[oi] += acc_o[jo][r] * sc;
    }
  }
}

extern "C" void kernel_launch(void* const* d_in, const int* in_sizes, int n_in,
                              void* d_out, int out_size, void* d_ws, size_t ws_size,
                              hipStream_t stream) {
  const float* x = (const float*)d_in[0];
  const float* q = (const float*)d_in[1];
  const float* gate_w = (const float*)d_in[2];
  const float* gate_b = (const float*)d_in[3];
  const float* wk_cmp = (const float*)d_in[4];
  const float* wv_cmp = (const float*)d_in[5];
  const float* wk_slc = (const float*)d_in[6];
  const float* wv_slc = (const float*)d_in[7];
  const float* wk_win = (const float*)d_in[8];
  const float* wv_win = (const float*)d_in[9];
  const float* block_pos = (const float*)d_in[10];
  const float* ck1_w = (const float*)d_in[11];
  const float* ck1_b = (const float*)d_in[12];
  const float* ck2_w = (const float*)d_in[13];
  const float* ck2_b = (const float*)d_in[14];
  const float* cv1_w = (const float*)d_in[15];
  const float* cv1_b = (const float*)d_in[16];
  const float* cv2_w = (const float*)d_in[17];
  const float* cv2_b = (const float*)d_in[18];
  float* out = (float*)d_out;

  char* wsp = (char*)d_ws;
  // [0, 26214400)        kvproj f32 (2048 x 3200)
  // [26214400, 34603008) pA: xbf -> k_cmp partials z0,z1 -> hk_part/hv_part
  // [34603008, 45625856) pB: Wcat+bias_cat -> k_cmp partials z2,z3 -> hk/hv/sums/biases
  // [45625856, ...)      selB
  float* kvproj = (float*)wsp;
  char* pA = wsp + 26214400;
  char* pB = wsp + 34603008;

  bf16_t* xbf = (bf16_t*)pA;
  bf16_t* Wcat = (bf16_t*)pB;
  float* bias_cat = (float*)(pB + 11010048);
  float* part = (float*)pA;                    // 4 x 2048*512*4 contiguous (pA+pB adjacent)
  float* hk_part = (float*)pA;                 // 16*64512*4 = 4,128,768
  float* hv_part = (float*)(pA + 4128768);
  float* hk = (float*)pB;                      // 258,048
  float* hv = (float*)(pB + 258048);
  float* k_sum = (float*)(pB + 516096);
  float* v_sum = (float*)(pB + 774144);
  float* bias_k = (float*)(pB + 1032192);
  float* bias_v = (float*)(pB + 1032704);
  unsigned long long* selB = (unsigned long long*)(wsp + 45625856);

  dim3 blk256(256);

  conv_x<<<16384, blk256, 0, stream>>>(x, xbf);
  build_wcat<<<21504, blk256, 0, stream>>>(wv_cmp, wk_slc, wv_slc, wk_win,
                                           wv_win, gate_w, gate_b, Wcat, bias_cat);

  // cols 512..3199 first (consumes xbf/Wcat), then k_cmp partials overwrite them
  gemm_mfma<<<dim3(21, 16), blk256, 0, stream>>>(xbf, 2048, Wcat, 2048, kvproj,
                                                 3200, bias_cat, 2048, 512);
  // k_cmp cols 0..511: exact f32, split-K x4 + deterministic reduce
  gemm_xwt<<<dim3(8, 32, 4), blk256, 0, stream>>>(x, 2048, wk_cmp, 2048, nullptr,
                                                  part, 512, 2048, 512, 512);
  reduce_k<<<4096, blk256, 0, stream>>>(part, kvproj);

  rope_kernel<<<dim3(Bc * Tc * NKVc, 3), 64, 0, stream>>>(kvproj);

  bias_adj_kernel<<<dim3(128, 2), blk256, 0, stream>>>(block_pos, ck1_w, ck1_b,
                                                       cv1_w, cv1_b, bias_k, bias_v);
  gemm_cmp1<<<dim3(2, 8, 32), blk256, 0, stream>>>(kvproj, ck1_w, cv1_w,
                                                   hk_part, hv_part);
  reduce_gelu<<<504, blk256, 0, stream>>>(hk_part, hv_part, bias_k, bias_v, hk, hv);
  gemm_l2<<<dim3(2, 8, 2), blk256, 0, stream>>>(hk, ck2_w, ck2_b, hv, cv2_w,
                                                cv2_b, k_sum, v_sum);

  cmp_attn<<<2048, blk256, 0, stream>>>(q, k_sum, v_sum, kvproj, out, selB);
  sparse_attn_mfma<0><<<512, blk256, 0, stream>>>(q, kvproj, 1024, selB, out);
  sparse_attn_mfma<1><<<512, blk256, 0, stream>>>(q, kvproj, 2048, selB, out);
}

// Round 6
// 436.065 us; speedup vs baseline: 9.1714x; 1.0556x over previous
//
#include <hip/hip_runtime.h>
#include <hip/hip_bf16.h>
#include <math.h>

#define Bc 2
#define Tc 1024
#define DMc 2048
#define NQc 16
#define NKVc 4
#define DHc 128
#define BLKc 32
#define STRIDEc 16
#define TOPNc 16
#define WINc 512
#define NREPc 4
#define NBc 63
#define SCALEc 0.08838834764831843f
#define KVP_LD 1280   // kvproj f32: 0..511 k_cmp | 512..1023 v_cmp | 1024..1071 gates | pad
#define KVB_LD 2048   // kvbf bf16: 0..511 k_slc | 512..1023 v_slc | 1024..1535 k_win | 1536..2047 v_win

typedef unsigned short bf16_t;
typedef short s16x8 __attribute__((ext_vector_type(8)));
typedef float f32x4 __attribute__((ext_vector_type(4)));

__device__ __forceinline__ unsigned short f2bf(float f) {
  unsigned int u = __float_as_uint(f);
  u += 0x7fffu + ((u >> 16) & 1u);
  return (unsigned short)(u >> 16);
}
__device__ __forceinline__ float bf2f(unsigned short h) {
  return __uint_as_float((unsigned int)h << 16);
}
__device__ __forceinline__ float geluf(float x) {
  return 0.5f * x * (1.0f + erff(x * 0.7071067811865476f));
}
__device__ __forceinline__ void load_lds16(const void* g, void* l) {
  __builtin_amdgcn_global_load_lds(
      (const __attribute__((address_space(1))) void*)g,
      (__attribute__((address_space(3))) void*)l, 16, 0, 0);
}

// ---------- x -> bf16 ----------
__global__ void conv_x(const float* __restrict__ x, bf16_t* __restrict__ xbf) {
  size_t i = (size_t)blockIdx.x * 256 + threadIdx.x;  // exact: 2048*2048/256
  xbf[i] = f2bf(x[i]);
}

// ---------- concat weights rows 512..3199 into bf16 Wcat ----------
__global__ void build_wcat(
    const float* __restrict__ wv_cmp, const float* __restrict__ wk_slc,
    const float* __restrict__ wv_slc, const float* __restrict__ wk_win,
    const float* __restrict__ wv_win, const float* __restrict__ gate_w,
    const float* __restrict__ gate_b, bf16_t* __restrict__ Wcat,
    float* __restrict__ bias_cat) {
  size_t i = (size_t)blockIdx.x * 256 + threadIdx.x;  // exact: 2688*2048/256
  int rr = (int)(i >> 11), c = (int)(i & 2047);
  int r = rr + 512;
  float v = 0.f;
  if (r < 3072) {
    int blk = r >> 9;  // 1..5
    size_t o = (size_t)(r & 511) * 2048 + c;
    if (blk == 1) v = wv_cmp[o];
    else if (blk == 2) v = wk_slc[o];
    else if (blk == 3) v = wv_slc[o];
    else if (blk == 4) v = wk_win[o];
    else v = wv_win[o];
  } else if (r < 3120) {
    v = gate_w[(size_t)(r - 3072) * 2048 + c];
  }
  Wcat[i] = f2bf(v);
  if (c == 0) bias_cat[r] = (r >= 3072 && r < 3120) ? gate_b[r - 3072] : 0.f;
}

// ---------- bf16 MFMA GEMM: cols 512..3199 ----------
// epilogue routes: [512,1024)->kvproj f32; [1024,3072)->kvbf bf16; [3072,3200)->gates f32 sigmoid
__global__ __launch_bounds__(256) void gemm_mfma(
    const bf16_t* __restrict__ A, int lda,
    const bf16_t* __restrict__ Bw, int ldb,
    float* __restrict__ kvproj, bf16_t* __restrict__ kvbf,
    const float* __restrict__ bias, int K) {
  __shared__ bf16_t As[128 * 32];
  __shared__ bf16_t Bs[128 * 32];
  const int bm = blockIdx.y * 128, bnw = blockIdx.x * 128, bn = 512 + bnw;
  const int tid = threadIdx.x, lane = tid & 63, w = tid >> 6;
  const int wr = (w >> 1) * 64, wc = (w & 1) * 64;

  f32x4 acc[4][4];
#pragma unroll
  for (int i = 0; i < 4; ++i)
#pragma unroll
    for (int j = 0; j < 4; ++j) acc[i][j] = 0.f;

  const int srow = lane >> 2;
  const int sslot = lane & 3;

  for (int k0 = 0; k0 < K; k0 += 32) {
    __syncthreads();
#pragma unroll
    for (int j = 0; j < 2; ++j) {
      int rb = w * 32 + j * 16;
      int row = rb + srow;
      int slot = sslot ^ ((row >> 1) & 3);
      load_lds16(A + (size_t)(bm + row) * lda + k0 + slot * 8, &As[rb * 32]);
      load_lds16(Bw + (size_t)(bnw + row) * ldb + k0 + slot * 8, &Bs[rb * 32]);
    }
    __syncthreads();

    s16x8 af[4], bfr[4];
#pragma unroll
    for (int i = 0; i < 4; ++i) {
      int ar = wr + i * 16 + (lane & 15);
      int as = ((lane >> 4) ^ ((ar >> 1) & 3)) * 8;
      af[i] = *(const s16x8*)&As[ar * 32 + as];
      int br = wc + i * 16 + (lane & 15);
      int bs = ((lane >> 4) ^ ((br >> 1) & 3)) * 8;
      bfr[i] = *(const s16x8*)&Bs[br * 32 + bs];
    }
#pragma unroll
    for (int i = 0; i < 4; ++i)
#pragma unroll
      for (int j = 0; j < 4; ++j)
        acc[i][j] = __builtin_amdgcn_mfma_f32_16x16x32_bf16(af[i], bfr[j], acc[i][j], 0, 0, 0);
  }

#pragma unroll
  for (int i = 0; i < 4; ++i) {
    int row = bm + wr + i * 16 + ((lane >> 4) << 2);
#pragma unroll
    for (int j = 0; j < 4; ++j) {
      int col = bn + wc + j * 16 + (lane & 15);
      float bv = bias[col];
#pragma unroll
      for (int r = 0; r < 4; ++r) {
        float v = acc[i][j][r] + bv;
        if (col < 1024) {
          kvproj[(size_t)(row + r) * KVP_LD + col] = v;
        } else if (col < 3072) {
          kvbf[(size_t)(row + r) * KVB_LD + (col - 1024)] = f2bf(v);
        } else {
          kvproj[(size_t)(row + r) * KVP_LD + (col - 2048)] =
              1.f / (1.f + __expf(-v));
        }
      }
    }
  }
}

// ---------- f32 VALU GEMM (split-K partials via blockIdx.z) ----------
__global__ __launch_bounds__(256) void gemm_xwt(
    const float* __restrict__ A, int lda, const float* __restrict__ W, int ldw,
    float* __restrict__ C, int ldc, int M, int N, int K) {
  __shared__ float As[16][68];
  __shared__ float Ws[16][68];
  const int z = blockIdx.z;
  A += (size_t)z * K;
  W += (size_t)z * K;
  C += (size_t)z * (size_t)M * ldc;
  const int bm = blockIdx.y * 64, bn = blockIdx.x * 64;
  const int tid = threadIdx.x;
  const int tx = tid & 15, ty = tid >> 4;
  float acc[4][4] = {{0.f}};
  for (int k0 = 0; k0 < K; k0 += 16) {
#pragma unroll
    for (int i0 = 0; i0 < 4; ++i0) {
      int i = tid + i0 * 256;
      int m = i >> 4, kk = i & 15;
      As[kk][m] = A[(size_t)(bm + m) * lda + (k0 + kk)];
      Ws[kk][m] = W[(size_t)(bn + m) * ldw + (k0 + kk)];
    }
    __syncthreads();
#pragma unroll
    for (int kk = 0; kk < 16; ++kk) {
      float4 a4 = *reinterpret_cast<const float4*>(&As[kk][ty * 4]);
      float4 w4 = *reinterpret_cast<const float4*>(&Ws[kk][tx * 4]);
      float av[4] = {a4.x, a4.y, a4.z, a4.w};
      float wv[4] = {w4.x, w4.y, w4.z, w4.w};
#pragma unroll
      for (int i = 0; i < 4; ++i)
#pragma unroll
        for (int j = 0; j < 4; ++j) acc[i][j] = fmaf(av[i], wv[j], acc[i][j]);
    }
    __syncthreads();
  }
#pragma unroll
  for (int i = 0; i < 4; ++i)
#pragma unroll
    for (int j = 0; j < 4; ++j)
      C[(size_t)(bm + ty * 4 + i) * ldc + bn + tx * 4 + j] = acc[i][j];
}

// ---------- reduce 4 k_cmp partials + RoPE -> kvproj cols 0..511 ----------
__global__ void rope_k_fused(const float* __restrict__ part,
                             float* __restrict__ kvproj) {
  int blk = blockIdx.x;  // (b*T+t)*KV+kv
  int kv = blk & 3;
  int t = (blk >> 2) & (Tc - 1);
  int b = blk >> 12;
  int d = threadIdx.x;  // 0..63
  size_t base = (size_t)(b * Tc + t) * 512 + kv * 128;
  float x1 = part[base + d] + part[1048576 + base + d] +
             part[2097152 + base + d] + part[3145728 + base + d];
  float x2 = part[base + d + 64] + part[1048576 + base + d + 64] +
             part[2097152 + base + d + 64] + part[3145728 + base + d + 64];
  float inv = powf(10000.f, -(float)d * (1.f / 64.f));
  float ang = (float)t * inv;
  float s, c;
  sincosf(ang, &s, &c);
  float* p = kvproj + (size_t)(b * Tc + t) * KVP_LD + kv * 128;
  p[d] = x1 * c - x2 * s;
  p[d + 64] = x1 * s + x2 * c;
}

// ---------- RoPE in place on kvbf K slices (bf16) ----------
__global__ void rope_bf(bf16_t* __restrict__ kvbf) {
  int blk = blockIdx.x;
  int coloff = blockIdx.y << 10;  // 0 (slc K) or 1024 (win K)
  int kv = blk & 3;
  int t = (blk >> 2) & (Tc - 1);
  int b = blk >> 12;
  bf16_t* p = kvbf + (size_t)(b * Tc + t) * KVB_LD + coloff + kv * 128;
  int d = threadIdx.x;
  float inv = powf(10000.f, -(float)d * (1.f / 64.f));
  float ang = (float)t * inv;
  float s, c;
  sincosf(ang, &s, &c);
  float x1 = bf2f(p[d]), x2 = bf2f(p[d + 64]);
  p[d] = f2bf(x1 * c - x2 * s);
  p[d + 64] = f2bf(x1 * s + x2 * c);
}

// ---------- compress layer1: gathered-A GEMM, split-K x16, k&v merged ----------
__global__ __launch_bounds__(256) void gemm_cmp1(
    const float* __restrict__ kvproj,
    const float* __restrict__ ck1_w, const float* __restrict__ cv1_w,
    float* __restrict__ hk_part, float* __restrict__ hv_part) {
  __shared__ float As[16][68];
  __shared__ float Ws[16][68];
  const int zz = blockIdx.z;
  const bool isv = zz >= 16;
  const int z = zz & 15;
  const int coloff = isv ? 512 : 0;
  const float* W = isv ? cv1_w : ck1_w;
  float* Cpart = isv ? hv_part : hk_part;
  const int bm = blockIdx.y * 64, bn = blockIdx.x * 64;
  const int tid = threadIdx.x;
  const int tx = tid & 15, ty = tid >> 4;
  float acc[4][4] = {{0.f}};
  for (int k0 = z * 256; k0 < z * 256 + 256; k0 += 16) {
#pragma unroll
    for (int i0 = 0; i0 < 4; ++i0) {
      int i = tid + i0 * 256;
      int m = i >> 4, kk = i & 15;
      int gm = bm + m;
      float av = 0.f;
      if (gm < 504) {
        int b = gm / 252, rem = gm % 252;
        int n = rem >> 2, kv = rem & 3;
        int f = k0 + kk;
        int j = f >> 7, d = f & 127;
        av = kvproj[(size_t)(b * Tc + n * 16 + j) * KVP_LD + coloff + kv * 128 + d];
      }
      As[kk][m] = av;
      Ws[kk][m] = W[(size_t)(bn + m) * 4096 + (k0 + kk)];
    }
    __syncthreads();
#pragma unroll
    for (int kk = 0; kk < 16; ++kk) {
      float4 a4 = *reinterpret_cast<const float4*>(&As[kk][ty * 4]);
      float4 w4 = *reinterpret_cast<const float4*>(&Ws[kk][tx * 4]);
      float av[4] = {a4.x, a4.y, a4.z, a4.w};
      float wv[4] = {w4.x, w4.y, w4.z, w4.w};
#pragma unroll
      for (int i = 0; i < 4; ++i)
#pragma unroll
        for (int j = 0; j < 4; ++j) acc[i][j] = fmaf(av[i], wv[j], acc[i][j]);
    }
    __syncthreads();
  }
#pragma unroll
  for (int i = 0; i < 4; ++i) {
    int m = bm + ty * 4 + i;
    if (m >= 504) continue;
#pragma unroll
    for (int j = 0; j < 4; ++j)
      Cpart[(size_t)z * 64512 + (size_t)m * 128 + bn + tx * 4 + j] = acc[i][j];
  }
}

// ---------- bias_adj[o] = b1[o] + block_pos_flat . w1[o,:] ----------
__global__ void bias_adj_kernel(const float* __restrict__ bp,
                                const float* __restrict__ w1k,
                                const float* __restrict__ b1k,
                                const float* __restrict__ w1v,
                                const float* __restrict__ b1v,
                                float* __restrict__ outk,
                                float* __restrict__ outv) {
  __shared__ float red[4];
  const int o = blockIdx.x;
  const float* w1 = blockIdx.y ? w1v : w1k;
  float s = 0.f;
  for (int i = threadIdx.x; i < 4096; i += 256)
    s += bp[i] * w1[(size_t)o * 4096 + i];
#pragma unroll
  for (int off = 32; off; off >>= 1) s += __shfl_xor(s, off);
  if ((threadIdx.x & 63) == 0) red[threadIdx.x >> 6] = s;
  __syncthreads();
  if (threadIdx.x == 0) {
    float t = red[0] + red[1] + red[2] + red[3];
    if (blockIdx.y) outv[o] = t + b1v[o];
    else outk[o] = t + b1k[o];
  }
}

// ---------- reduce 16 partials + bias + gelu, k&v merged ----------
__global__ void reduce_gelu(const float* __restrict__ hk_part,
                            const float* __restrict__ hv_part,
                            const float* __restrict__ bias_k,
                            const float* __restrict__ bias_v,
                            float* __restrict__ hk, float* __restrict__ hv) {
  int gi = blockIdx.x * 256 + threadIdx.x;  // exact: 2*64512/256
  const bool isv = gi >= 64512;
  int i = isv ? gi - 64512 : gi;
  const float* parts = isv ? hv_part : hk_part;
  float s = (isv ? bias_v : bias_k)[i & 127];
#pragma unroll
  for (int z = 0; z < 16; ++z) s += parts[z * 64512 + i];
  (isv ? hv : hk)[i] = geluf(s);
}

// ---------- compress layer2, k&v merged ----------
__global__ __launch_bounds__(256) void gemm_l2(
    const float* __restrict__ hk, const float* __restrict__ w2k,
    const float* __restrict__ b2k, const float* __restrict__ hv,
    const float* __restrict__ w2v, const float* __restrict__ b2v,
    float* __restrict__ k_sum, float* __restrict__ v_sum) {
  __shared__ float As[16][68];
  __shared__ float Ws[16][68];
  const bool isv = blockIdx.z != 0;
  const float* A = isv ? hv : hk;
  const float* W = isv ? w2v : w2k;
  const float* bias = isv ? b2v : b2k;
  float* C = isv ? v_sum : k_sum;
  const int bm = blockIdx.y * 64, bn = blockIdx.x * 64;
  const int tid = threadIdx.x;
  const int tx = tid & 15, ty = tid >> 4;
  float acc[4][4] = {{0.f}};
  for (int k0 = 0; k0 < 128; k0 += 16) {
#pragma unroll
    for (int i0 = 0; i0 < 4; ++i0) {
      int i = tid + i0 * 256;
      int m = i >> 4, kk = i & 15;
      int gm = bm + m;
      As[kk][m] = (gm < 504) ? A[(size_t)gm * 128 + (k0 + kk)] : 0.f;
      Ws[kk][m] = W[(size_t)(bn + m) * 128 + (k0 + kk)];
    }
    __syncthreads();
#pragma unroll
    for (int kk = 0; kk < 16; ++kk) {
      float4 a4 = *reinterpret_cast<const float4*>(&As[kk][ty * 4]);
      float4 w4 = *reinterpret_cast<const float4*>(&Ws[kk][tx * 4]);
      float av[4] = {a4.x, a4.y, a4.z, a4.w};
      float wv[4] = {w4.x, w4.y, w4.z, w4.w};
#pragma unroll
      for (int i = 0; i < 4; ++i)
#pragma unroll
        for (int j = 0; j < 4; ++j) acc[i][j] = fmaf(av[i], wv[j], acc[i][j]);
    }
    __syncthreads();
  }
#pragma unroll
  for (int i = 0; i < 4; ++i) {
    int m = bm + ty * 4 + i;
    if (m >= 504) continue;
#pragma unroll
    for (int j = 0; j < 4; ++j)
      C[(size_t)m * 128 + bn + tx * 4 + j] = acc[i][j] + bias[bn + tx * 4 + j];
  }
}

// ---------- compressed attention + top-k: 4 query tokens per wg ----------
__global__ __launch_bounds__(256) void cmp_attn(
    const float* __restrict__ q, const float* __restrict__ k_sum,
    const float* __restrict__ v_sum, const float* __restrict__ kvproj,
    float* __restrict__ out, unsigned long long* __restrict__ sel) {
  __shared__ __align__(16) float q_s[4][4][128];
  __shared__ __align__(16) float ks[NBc * 128];
  __shared__ float p_s[4][4][64];

  const int wg = blockIdx.x;  // (b*4+kv)*256 + tq
  const int tq = wg & 255;
  const int kv = (wg >> 8) & 3;
  const int b = wg >> 10;
  const int t0 = tq * 4;
  const int tid = threadIdx.x;
  const int lane = tid & 63;
  const int g = tid >> 6;

  for (int i = tid; i < 2048; i += 256) {
    int gg = i >> 9, r = (i >> 7) & 3, d = i & 127;
    q_s[gg][r][d] = q[(((size_t)b * NQc + gg * NKVc + kv) * Tc + t0 + r) * 128 + d];
  }
  {
    const float* kbase = k_sum + (size_t)(b * 252 + kv) * 128;
    for (int i = tid; i < NBc * 32; i += 256) {
      int n = i >> 5, s = i & 31;
      f32x4 v4 = *(const f32x4*)(kbase + (size_t)n * 512 + s * 4);
      *(f32x4*)&ks[n * 128 + ((s ^ (n & 7)) << 2)] = v4;
    }
  }
  __syncthreads();

  float acc[4] = {0.f, 0.f, 0.f, 0.f};
  {
    const int lrow = (lane < 63) ? lane : 62;
    const int lx = lrow & 7;
#pragma unroll
    for (int s = 0; s < 32; ++s) {
      f32x4 k4 = *(const f32x4*)&ks[lrow * 128 + ((s ^ lx) << 2)];
#pragma unroll
      for (int r = 0; r < 4; ++r) {
        f32x4 q4 = *(const f32x4*)&q_s[g][r][s * 4];
        acc[r] = fmaf(q4[0], k4[0], acc[r]);
        acc[r] = fmaf(q4[1], k4[1], acc[r]);
        acc[r] = fmaf(q4[2], k4[2], acc[r]);
        acc[r] = fmaf(q4[3], k4[3], acc[r]);
      }
    }
  }
#pragma unroll
  for (int r = 0; r < 4; ++r) {
    const int t = t0 + r;
    const int nvalid = min(t / STRIDEc + 1, NBc);
    const bool valid = (lane < nvalid);
    float sval = valid ? acc[r] * SCALEc : -INFINITY;
    float m = sval;
#pragma unroll
    for (int off = 32; off; off >>= 1) m = fmaxf(m, __shfl_xor(m, off));
    float e = valid ? __expf(sval - m) : 0.f;
    float l = e;
#pragma unroll
    for (int off = 32; off; off >>= 1) l += __shfl_xor(l, off);
    p_s[g][r][lane] = e / fmaxf(l, 1e-9f);
  }
  __syncthreads();

  {  // top-k: wave g handles row r=g
    float v = p_s[0][g][lane] + p_s[1][g][lane] + p_s[2][g][lane] + p_s[3][g][lane];
    if (lane >= NBc) v = -1.f;
    unsigned long long mask = 0ull;
    for (int it = 0; it < TOPNc; ++it) {
      float mx = v;
#pragma unroll
      for (int off = 32; off; off >>= 1) mx = fmaxf(mx, __shfl_xor(mx, off));
      unsigned long long ball = __ballot(v == mx);
      int sl = __ffsll(ball) - 1;
      mask |= 1ull << sl;
      if (lane == sl) v = -1.f;
    }
    if (lane == 0) sel[(((size_t)b * NKVc + kv) << 10) + t0 + g] = mask;
  }
  {
    const float* vbase = v_sum + (size_t)(b * 252 + kv) * 128;
    for (int i = tid; i < NBc * 32; i += 256) {
      int n = i >> 5, s = i & 31;
      f32x4 v4 = *(const f32x4*)(vbase + (size_t)n * 512 + s * 4);
      *(f32x4*)&ks[n * 128 + ((s ^ (n & 7)) << 2)] = v4;
    }
  }
  __syncthreads();

  const int h = g * NKVc + kv;
  float ox[4] = {0.f, 0.f, 0.f, 0.f}, oy[4] = {0.f, 0.f, 0.f, 0.f};
  const int slotd = lane >> 1, wi = (lane & 1) * 2;
  const int nvmax = min((t0 + 3) / STRIDEc + 1, NBc);
  for (int n = 0; n < nvmax; ++n) {
    const float* vp = &ks[n * 128 + (((slotd ^ (n & 7)) << 2) | wi)];
    const float vx = vp[0], vy = vp[1];
#pragma unroll
    for (int r = 0; r < 4; ++r) {
      float pn = p_s[g][r][n];
      ox[r] = fmaf(pn, vx, ox[r]);
      oy[r] = fmaf(pn, vy, oy[r]);
    }
  }
#pragma unroll
  for (int r = 0; r < 4; ++r) {
    const int t = t0 + r;
    const float g0 = kvproj[(size_t)(b * Tc + t) * KVP_LD + 1024 + h * 3];
    size_t obase = ((size_t)(b * NQc + h) * Tc + t) * 128 + lane * 2;
    *(float2*)&out[obase] = make_float2(g0 * ox[r], g0 * oy[r]);
  }
}

// ---------- merged MFMA flash-tile attention: mode 0 = slc (-> out +=), 1 = win (-> out2 =) ----------
__global__ __launch_bounds__(256) void sparse_attn_mfma(
    const float* __restrict__ q, const bf16_t* __restrict__ kvbf,
    const float* __restrict__ kvproj, const unsigned long long* __restrict__ sel,
    float* __restrict__ out, float* __restrict__ out2) {
  __shared__ bf16_t Ks[64 * 128];    // [s][d], swz ^((s&7)<<4)
  __shared__ bf16_t Vt[128 * 64];    // [d][s], swz ^(((d>>1)&7)<<4)
  __shared__ bf16_t Ps[4][16 * 64];  // per-wave P, swz ^((row&7)<<4)

  const int w = blockIdx.x;
  const int mode = w & 1;
  const int u = w >> 1;
  const int tt = 63 - (u & 63);  // heavy (high-t) tiles dispatch first
  const int kv = (u >> 6) & 3;
  const int b = u >> 8;
  const int t0 = tt * 16;
  const int tid = threadIdx.x, lane = tid & 63, g = tid >> 6;
  const int h = g * NKVc + kv;
  const int lr = lane >> 4;
  const int lc = lane & 15;

  s16x8 aq[4];
  {
    const float* qrow = q + (((size_t)(b * NQc + h) * Tc) + t0 + lc) * 128;
#pragma unroll
    for (int ks = 0; ks < 4; ++ks) {
      f32x4 lo = *(const f32x4*)(qrow + ks * 32 + lr * 8);
      f32x4 hi = *(const f32x4*)(qrow + ks * 32 + lr * 8 + 4);
      s16x8 v;
#pragma unroll
      for (int e = 0; e < 4; ++e) {
        v[e] = (short)f2bf(lo[e]);
        v[e + 4] = (short)f2bf(hi[e]);
      }
      aq[ks] = v;
    }
  }

  unsigned long long hm[4] = {~0ull, ~0ull, ~0ull, ~0ull};
  unsigned long long um = 0ull;
  int c0;
  const int c1 = (t0 + 15) >> 6;
  if (mode == 0) {
    const unsigned long long* sb = sel + ((size_t)(b * NKVc + kv) << 10);
#pragma unroll
    for (int r = 0; r < 4; ++r) {
      unsigned long long bm = sb[t0 + lr * 4 + r];
      hm[r] = bm | (bm << 1);
      um |= hm[r];
    }
    um |= __shfl_xor(um, 16);
    um |= __shfl_xor(um, 32);
    c0 = (__ffsll(um) - 1) >> 2;
  } else {
    int lo = t0 - (WINc - 1);
    c0 = (lo > 0 ? lo : 0) >> 6;
  }

  float run_m[4], run_l[4];
  f32x4 acc_o[8];
#pragma unroll
  for (int r = 0; r < 4; ++r) {
    run_m[r] = -INFINITY;
    run_l[r] = 0.f;
  }
#pragma unroll
  for (int j = 0; j < 8; ++j) acc_o[j] = 0.f;

  const int colK = (mode << 10) + kv * 128;
  const bf16_t* kb = kvbf + colK;
  const bf16_t* vb = kvbf + colK + 512;
  const size_t rbase = (size_t)b * Tc;

  for (int c = c0; c <= c1; ++c) {
    if (mode == 0 && ((um >> (4 * c)) & 0xFull) == 0ull) continue;
    const int s0 = c * 64;

    __syncthreads();
    // K: 16B bf16 copies, swizzled
    for (int idx = tid; idx < 1024; idx += 256) {
      int s = idx >> 4, c8 = idx & 15;
      s16x8 v = *(const s16x8*)(kb + (rbase + s0 + s) * KVB_LD + c8 * 8);
      *(s16x8*)((char*)Ks + ((s * 256 + c8 * 16) ^ ((s & 7) << 4))) = v;
    }
    // V transposed: u32-pair gather (two d-rows per load)
    for (int idx = tid; idx < 512; idx += 256) {
      int sg = idx >> 6, d2 = (idx & 63) * 2;
      const bf16_t* src = vb + (rbase + s0 + sg * 8) * KVB_LD + d2;
      unsigned short w0[8], w1[8];
#pragma unroll
      for (int e = 0; e < 8; ++e) {
        unsigned int uv = *(const unsigned int*)(src + (size_t)e * KVB_LD);
        w0[e] = (unsigned short)uv;
        w1[e] = (unsigned short)(uv >> 16);
      }
      int xo = ((d2 >> 1) & 7) << 4;
      *(s16x8*)((char*)Vt + ((d2 * 128 + sg * 16) ^ xo)) = *(s16x8*)w0;
      *(s16x8*)((char*)Vt + (((d2 + 1) * 128 + sg * 16) ^ xo)) = *(s16x8*)w1;
    }
    __syncthreads();

    f32x4 accs[4];
#pragma unroll
    for (int j = 0; j < 4; ++j) accs[j] = 0.f;
#pragma unroll
    for (int ks = 0; ks < 4; ++ks) {
      s16x8 bk[4];
#pragma unroll
      for (int j = 0; j < 4; ++j) {
        int sB = j * 16 + lc;
        bk[j] = *(const s16x8*)((const char*)Ks +
                                ((sB * 256 + (ks * 4 + lr) * 16) ^ ((sB & 7) << 4)));
      }
#pragma unroll
      for (int j = 0; j < 4; ++j)
        accs[j] = __builtin_amdgcn_mfma_f32_16x16x32_bf16(aq[ks], bk[j], accs[j], 0, 0, 0);
    }

#pragma unroll
    for (int r = 0; r < 4; ++r) {
      const int t = t0 + lr * 4 + r;
      float ev[4];
      float mx = -INFINITY;
#pragma unroll
      for (int j = 0; j < 4; ++j) {
        int s = s0 + j * 16 + lc;
        bool att;
        if (mode == 0) att = (s <= t) && ((hm[r] >> (s >> 4)) & 1ull);
        else att = (s <= t) && (t - s < WINc);
        float sv = att ? accs[j][r] * SCALEc : -INFINITY;
        ev[j] = sv;
        mx = fmaxf(mx, sv);
      }
      mx = fmaxf(mx, __shfl_xor(mx, 1));
      mx = fmaxf(mx, __shfl_xor(mx, 2));
      mx = fmaxf(mx, __shfl_xor(mx, 4));
      mx = fmaxf(mx, __shfl_xor(mx, 8));
      const float nm = fmaxf(run_m[r], mx);
      const float resc = (run_m[r] == -INFINITY) ? 0.f : __expf(run_m[r] - nm);
      float cl = 0.f;
#pragma unroll
      for (int j = 0; j < 4; ++j) {
        float e = (ev[j] == -INFINITY) ? 0.f : __expf(ev[j] - nm);
        ev[j] = e;
        cl += e;
      }
      cl += __shfl_xor(cl, 1);
      cl += __shfl_xor(cl, 2);
      cl += __shfl_xor(cl, 4);
      cl += __shfl_xor(cl, 8);
      run_l[r] = run_l[r] * resc + cl;
      run_m[r] = nm;
#pragma unroll
      for (int jo = 0; jo < 8; ++jo) acc_o[jo][r] *= resc;
      const int row = lr * 4 + r;
#pragma unroll
      for (int j = 0; j < 4; ++j) {
        int col = j * 16 + lc;
        *(bf16_t*)((char*)Ps[g] + ((row * 128 + col * 2) ^ ((row & 7) << 4))) =
            f2bf(ev[j]);
      }
    }

    asm volatile("s_waitcnt lgkmcnt(0)" ::: "memory");
    __builtin_amdgcn_sched_barrier(0);
    s16x8 ap[2];
#pragma unroll
    for (int k2 = 0; k2 < 2; ++k2)
      ap[k2] = *(const s16x8*)((const char*)Ps[g] +
                               ((lc * 128 + k2 * 64 + lr * 16) ^ ((lc & 7) << 4)));
#pragma unroll
    for (int k2 = 0; k2 < 2; ++k2) {
#pragma unroll
      for (int jo = 0; jo < 8; ++jo) {
        int d = jo * 16 + lc;
        s16x8 bv = *(const s16x8*)((const char*)Vt +
                                   ((d * 128 + k2 * 64 + lr * 16) ^ (((d >> 1) & 7) << 4)));
        acc_o[jo] = __builtin_amdgcn_mfma_f32_16x16x32_bf16(ap[k2], bv, acc_o[jo], 0, 0, 0);
      }
    }
  }

#pragma unroll
  for (int r = 0; r < 4; ++r) {
    const int t = t0 + lr * 4 + r;
    const float gg = kvproj[(rbase + t) * KVP_LD + 1024 + h * 3 + 1 + mode];
    const float sc = gg / fmaxf(run_l[r], 1e-9f);
    const size_t ob = ((size_t)(b * NQc + h) * Tc + t) * 128;
#pragma unroll
    for (int jo = 0; jo < 8; ++jo) {
      size_t oi = ob + jo * 16 + lc;
      float v = acc_o[jo][r] * sc;
      if (mode == 0) out[oi] += v;
      else out2[oi] = v;
    }
  }
}

// ---------- out += out2 ----------
__global__ void add_out(float* __restrict__ out, const float* __restrict__ out2) {
  size_t i = (size_t)blockIdx.x * 256 + threadIdx.x;  // exact: 4194304/256
  out[i] += out2[i];
}

extern "C" void kernel_launch(void* const* d_in, const int* in_sizes, int n_in,
                              void* d_out, int out_size, void* d_ws, size_t ws_size,
                              hipStream_t stream) {
  const float* x = (const float*)d_in[0];
  const float* q = (const float*)d_in[1];
  const float* gate_w = (const float*)d_in[2];
  const float* gate_b = (const float*)d_in[3];
  const float* wk_cmp = (const float*)d_in[4];
  const float* wv_cmp = (const float*)d_in[5];
  const float* wk_slc = (const float*)d_in[6];
  const float* wv_slc = (const float*)d_in[7];
  const float* wk_win = (const float*)d_in[8];
  const float* wv_win = (const float*)d_in[9];
  const float* block_pos = (const float*)d_in[10];
  const float* ck1_w = (const float*)d_in[11];
  const float* ck1_b = (const float*)d_in[12];
  const float* ck2_w = (const float*)d_in[13];
  const float* ck2_b = (const float*)d_in[14];
  const float* cv1_w = (const float*)d_in[15];
  const float* cv1_b = (const float*)d_in[16];
  const float* cv2_w = (const float*)d_in[17];
  const float* cv2_b = (const float*)d_in[18];
  float* out = (float*)d_out;

  char* wsp = (char*)d_ws;
  // [0, 10485760)            kvproj f32 2048 x 1280
  // [10485760, 18874368)     kvbf bf16 2048 x 2048
  // [18874368, 27262976)     xbf -> part(z0,z1) -> hk_part/hv_part -> out2
  // [27262976, 38273024)     Wcat -> part(z2,z3) -> hk/hv/k_sum/v_sum/bias_k/v
  // [38273024, 38285824)     bias_cat
  // [38285824, 38351360)     selB
  float* kvproj = (float*)wsp;
  bf16_t* kvbf = (bf16_t*)(wsp + 10485760);
  bf16_t* xbf = (bf16_t*)(wsp + 18874368);
  bf16_t* Wcat = (bf16_t*)(wsp + 27262976);
  float* bias_cat = (float*)(wsp + 38273024);
  unsigned long long* selB = (unsigned long long*)(wsp + 38285824);

  float* part = (float*)(wsp + 18874368);      // 4 x 2048*512*4 = 16,777,216
  float* hk_part = (float*)(wsp + 18874368);   // 16*64512*4 = 4,128,768
  float* hv_part = (float*)(wsp + 23003136);
  float* out2 = (float*)(wsp + 18874368);      // 16,777,216 (after hk/hv_part dead)
  float* hk = (float*)(wsp + 35651584);
  float* hv = (float*)(wsp + 35909632);
  float* k_sum = (float*)(wsp + 36167680);
  float* v_sum = (float*)(wsp + 36425728);
  float* bias_k = (float*)(wsp + 36683776);
  float* bias_v = (float*)(wsp + 36684288);

  dim3 blk256(256);

  conv_x<<<16384, blk256, 0, stream>>>(x, xbf);
  build_wcat<<<21504, blk256, 0, stream>>>(wv_cmp, wk_slc, wv_slc, wk_win,
                                           wv_win, gate_w, gate_b, Wcat, bias_cat);

  gemm_mfma<<<dim3(21, 16), blk256, 0, stream>>>(xbf, 2048, Wcat, 2048, kvproj,
                                                 kvbf, bias_cat, 2048);
  // k_cmp: exact f32 split-K x4 (overwrites xbf/Wcat regions)
  gemm_xwt<<<dim3(8, 32, 4), blk256, 0, stream>>>(x, 2048, wk_cmp, 2048, part,
                                                  512, 2048, 512, 512);
  rope_k_fused<<<Bc * Tc * NKVc, 64, 0, stream>>>(part, kvproj);
  rope_bf<<<dim3(Bc * Tc * NKVc, 2), 64, 0, stream>>>(kvbf);

  bias_adj_kernel<<<dim3(128, 2), blk256, 0, stream>>>(block_pos, ck1_w, ck1_b,
                                                       cv1_w, cv1_b, bias_k, bias_v);
  gemm_cmp1<<<dim3(2, 8, 32), blk256, 0, stream>>>(kvproj, ck1_w, cv1_w,
                                                   hk_part, hv_part);
  reduce_gelu<<<504, blk256, 0, stream>>>(hk_part, hv_part, bias_k, bias_v, hk, hv);
  gemm_l2<<<dim3(2, 8, 2), blk256, 0, stream>>>(hk, ck2_w, ck2_b, hv, cv2_w,
                                                cv2_b, k_sum, v_sum);

  cmp_attn<<<2048, blk256, 0, stream>>>(q, k_sum, v_sum, kvproj, out, selB);
  sparse_attn_mfma<<<1024, blk256, 0, stream>>>(q, kvbf, kvproj, selB, out, out2);
  add_out<<<16384, blk256, 0, stream>>>(out, out2);
}

// Round 7
// 414.150 us; speedup vs baseline: 9.6567x; 1.0529x over previous
//
#include <hip/hip_runtime.h>
#include <hip/hip_bf16.h>
#include <math.h>

#define Bc 2
#define Tc 1024
#define DMc 2048
#define NQc 16
#define NKVc 4
#define DHc 128
#define BLKc 32
#define STRIDEc 16
#define TOPNc 16
#define WINc 512
#define NREPc 4
#define NBc 63
#define SCALEc 0.08838834764831843f
#define KVP_LD 1280   // kvproj f32: 0..511 k_cmp | 512..1023 v_cmp | 1024..1071 gates | pad
#define KVB_LD 2048   // kvbf bf16: 0..511 k_slc | [512..1024 unused] | 1024..1535 k_win | unused

typedef unsigned short bf16_t;
typedef short s16x8 __attribute__((ext_vector_type(8)));
typedef float f32x4 __attribute__((ext_vector_type(4)));
typedef unsigned short u16x4 __attribute__((ext_vector_type(4)));

__device__ __forceinline__ unsigned short f2bf(float f) {
  unsigned int u = __float_as_uint(f);
  u += 0x7fffu + ((u >> 16) & 1u);
  return (unsigned short)(u >> 16);
}
__device__ __forceinline__ float bf2f(unsigned short h) {
  return __uint_as_float((unsigned int)h << 16);
}
__device__ __forceinline__ float geluf(float x) {
  return 0.5f * x * (1.0f + erff(x * 0.7071067811865476f));
}
__device__ __forceinline__ void load_lds16(const void* g, void* l) {
  __builtin_amdgcn_global_load_lds(
      (const __attribute__((address_space(1))) void*)g,
      (__attribute__((address_space(3))) void*)l, 16, 0, 0);
}

// ---------- x -> bf16 ----------
__global__ void conv_x(const float* __restrict__ x, bf16_t* __restrict__ xbf) {
  size_t i = (size_t)blockIdx.x * 256 + threadIdx.x;  // exact: 2048*2048/256
  xbf[i] = f2bf(x[i]);
}

// ---------- concat weights rows 512..3199 into bf16 Wcat ----------
__global__ void build_wcat(
    const float* __restrict__ wv_cmp, const float* __restrict__ wk_slc,
    const float* __restrict__ wv_slc, const float* __restrict__ wk_win,
    const float* __restrict__ wv_win, const float* __restrict__ gate_w,
    const float* __restrict__ gate_b, bf16_t* __restrict__ Wcat,
    float* __restrict__ bias_cat) {
  size_t i = (size_t)blockIdx.x * 256 + threadIdx.x;  // exact: 2688*2048/256
  int rr = (int)(i >> 11), c = (int)(i & 2047);
  int r = rr + 512;
  float v = 0.f;
  if (r < 3072) {
    int blk = r >> 9;  // 1..5
    size_t o = (size_t)(r & 511) * 2048 + c;
    if (blk == 1) v = wv_cmp[o];
    else if (blk == 2) v = wk_slc[o];
    else if (blk == 3) v = wv_slc[o];
    else if (blk == 4) v = wk_win[o];
    else v = wv_win[o];
  } else if (r < 3120) {
    v = gate_w[(size_t)(r - 3072) * 2048 + c];
  }
  Wcat[i] = f2bf(v);
  if (c == 0) bias_cat[r] = (r >= 3072 && r < 3120) ? gate_b[r - 3072] : 0.f;
}

// ---------- bf16 MFMA GEMM: cols 512..3199 ----------
// epilogue routes: [512,1024)->kvproj f32 (v_cmp); k_slc/k_win -> kvbf bf16;
// v_slc/v_win -> VT (transposed bf16 [slice][d][t]); [3072,3200)->gates sigmoid
__global__ __launch_bounds__(256) void gemm_mfma(
    const bf16_t* __restrict__ A, int lda,
    const bf16_t* __restrict__ Bw, int ldb,
    float* __restrict__ kvproj, bf16_t* __restrict__ kvbf,
    bf16_t* __restrict__ VT, const float* __restrict__ bias, int K) {
  __shared__ bf16_t As[128 * 32];
  __shared__ bf16_t Bs[128 * 32];
  const int bm = blockIdx.y * 128, bnw = blockIdx.x * 128, bn = 512 + bnw;
  const int tid = threadIdx.x, lane = tid & 63, w = tid >> 6;
  const int wr = (w >> 1) * 64, wc = (w & 1) * 64;

  f32x4 acc[4][4];
#pragma unroll
  for (int i = 0; i < 4; ++i)
#pragma unroll
    for (int j = 0; j < 4; ++j) acc[i][j] = 0.f;

  const int srow = lane >> 2;
  const int sslot = lane & 3;

  for (int k0 = 0; k0 < K; k0 += 32) {
    __syncthreads();
#pragma unroll
    for (int j = 0; j < 2; ++j) {
      int rb = w * 32 + j * 16;
      int row = rb + srow;
      int slot = sslot ^ ((row >> 1) & 3);
      load_lds16(A + (size_t)(bm + row) * lda + k0 + slot * 8, &As[rb * 32]);
      load_lds16(Bw + (size_t)(bnw + row) * ldb + k0 + slot * 8, &Bs[rb * 32]);
    }
    __syncthreads();

    s16x8 af[4], bfr[4];
#pragma unroll
    for (int i = 0; i < 4; ++i) {
      int ar = wr + i * 16 + (lane & 15);
      int as = ((lane >> 4) ^ ((ar >> 1) & 3)) * 8;
      af[i] = *(const s16x8*)&As[ar * 32 + as];
      int br = wc + i * 16 + (lane & 15);
      int bs = ((lane >> 4) ^ ((br >> 1) & 3)) * 8;
      bfr[i] = *(const s16x8*)&Bs[br * 32 + bs];
    }
#pragma unroll
    for (int i = 0; i < 4; ++i)
#pragma unroll
      for (int j = 0; j < 4; ++j)
        acc[i][j] = __builtin_amdgcn_mfma_f32_16x16x32_bf16(af[i], bfr[j], acc[i][j], 0, 0, 0);
  }

#pragma unroll
  for (int i = 0; i < 4; ++i) {
    int row = bm + wr + i * 16 + ((lane >> 4) << 2);
#pragma unroll
    for (int j = 0; j < 4; ++j) {
      int col = bn + wc + j * 16 + (lane & 15);
      float bv = bias[col];
      float vals[4];
#pragma unroll
      for (int r = 0; r < 4; ++r) vals[r] = acc[i][j][r] + bv;
      if (col < 1024) {  // v_cmp -> f32 kvproj
#pragma unroll
        for (int r = 0; r < 4; ++r)
          kvproj[(size_t)(row + r) * KVP_LD + col] = vals[r];
      } else if (col < 3072) {
        int cc = col - 1024;
        int region = cc >> 9;  // 0 k_slc, 1 v_slc, 2 k_win, 3 v_win
        if ((region & 1) == 0) {
#pragma unroll
          for (int r = 0; r < 4; ++r)
            kvbf[(size_t)(row + r) * KVB_LD + cc] = f2bf(vals[r]);
        } else {
          int mode = region >> 1;
          int kv = (cc >> 7) & 3, d = cc & 127;
          int b = row >> 10;
          u16x4 w4;
#pragma unroll
          for (int r = 0; r < 4; ++r) w4[r] = f2bf(vals[r]);
          *(u16x4*)(VT + (size_t)((b * 4 + kv) * 2 + mode) * 131072 +
                    d * 1024 + (row & 1023)) = w4;
        }
      } else {
#pragma unroll
        for (int r = 0; r < 4; ++r)
          kvproj[(size_t)(row + r) * KVP_LD + (col - 2048)] =
              1.f / (1.f + __expf(-vals[r]));
      }
    }
  }
}

// ---------- f32 VALU GEMM (split-K partials via blockIdx.z) ----------
__global__ __launch_bounds__(256) void gemm_xwt(
    const float* __restrict__ A, int lda, const float* __restrict__ W, int ldw,
    float* __restrict__ C, int ldc, int M, int N, int K) {
  __shared__ float As[16][68];
  __shared__ float Ws[16][68];
  const int z = blockIdx.z;
  A += (size_t)z * K;
  W += (size_t)z * K;
  C += (size_t)z * (size_t)M * ldc;
  const int bm = blockIdx.y * 64, bn = blockIdx.x * 64;
  const int tid = threadIdx.x;
  const int tx = tid & 15, ty = tid >> 4;
  float acc[4][4] = {{0.f}};
  for (int k0 = 0; k0 < K; k0 += 16) {
#pragma unroll
    for (int i0 = 0; i0 < 4; ++i0) {
      int i = tid + i0 * 256;
      int m = i >> 4, kk = i & 15;
      As[kk][m] = A[(size_t)(bm + m) * lda + (k0 + kk)];
      Ws[kk][m] = W[(size_t)(bn + m) * ldw + (k0 + kk)];
    }
    __syncthreads();
#pragma unroll
    for (int kk = 0; kk < 16; ++kk) {
      float4 a4 = *reinterpret_cast<const float4*>(&As[kk][ty * 4]);
      float4 w4 = *reinterpret_cast<const float4*>(&Ws[kk][tx * 4]);
      float av[4] = {a4.x, a4.y, a4.z, a4.w};
      float wv[4] = {w4.x, w4.y, w4.z, w4.w};
#pragma unroll
      for (int i = 0; i < 4; ++i)
#pragma unroll
        for (int j = 0; j < 4; ++j) acc[i][j] = fmaf(av[i], wv[j], acc[i][j]);
    }
    __syncthreads();
  }
#pragma unroll
  for (int i = 0; i < 4; ++i)
#pragma unroll
    for (int j = 0; j < 4; ++j)
      C[(size_t)(bm + ty * 4 + i) * ldc + bn + tx * 4 + j] = acc[i][j];
}

// ---------- reduce 4 k_cmp partials + RoPE -> kvproj cols 0..511 ----------
__global__ void rope_k_fused(const float* __restrict__ part,
                             float* __restrict__ kvproj) {
  int blk = blockIdx.x;  // (b*T+t)*KV+kv
  int kv = blk & 3;
  int t = (blk >> 2) & (Tc - 1);
  int b = blk >> 12;
  int d = threadIdx.x;  // 0..63
  size_t base = (size_t)(b * Tc + t) * 512 + kv * 128;
  float x1 = part[base + d] + part[1048576 + base + d] +
             part[2097152 + base + d] + part[3145728 + base + d];
  float x2 = part[base + d + 64] + part[1048576 + base + d + 64] +
             part[2097152 + base + d + 64] + part[3145728 + base + d + 64];
  float inv = powf(10000.f, -(float)d * (1.f / 64.f));
  float ang = (float)t * inv;
  float s, c;
  sincosf(ang, &s, &c);
  float* p = kvproj + (size_t)(b * Tc + t) * KVP_LD + kv * 128;
  p[d] = x1 * c - x2 * s;
  p[d + 64] = x1 * s + x2 * c;
}

// ---------- RoPE in place on kvbf K slices (bf16) ----------
__global__ void rope_bf(bf16_t* __restrict__ kvbf) {
  int blk = blockIdx.x;
  int coloff = blockIdx.y << 10;  // 0 (slc K) or 1024 (win K)
  int kv = blk & 3;
  int t = (blk >> 2) & (Tc - 1);
  int b = blk >> 12;
  bf16_t* p = kvbf + (size_t)(b * Tc + t) * KVB_LD + coloff + kv * 128;
  int d = threadIdx.x;
  float inv = powf(10000.f, -(float)d * (1.f / 64.f));
  float ang = (float)t * inv;
  float s, c;
  sincosf(ang, &s, &c);
  float x1 = bf2f(p[d]), x2 = bf2f(p[d + 64]);
  p[d] = f2bf(x1 * c - x2 * s);
  p[d + 64] = f2bf(x1 * s + x2 * c);
}

// ---------- compress layer1: gathered-A GEMM, split-K x16, k&v merged ----------
__global__ __launch_bounds__(256) void gemm_cmp1(
    const float* __restrict__ kvproj,
    const float* __restrict__ ck1_w, const float* __restrict__ cv1_w,
    float* __restrict__ hk_part, float* __restrict__ hv_part) {
  __shared__ float As[16][68];
  __shared__ float Ws[16][68];
  const int zz = blockIdx.z;
  const bool isv = zz >= 16;
  const int z = zz & 15;
  const int coloff = isv ? 512 : 0;
  const float* W = isv ? cv1_w : ck1_w;
  float* Cpart = isv ? hv_part : hk_part;
  const int bm = blockIdx.y * 64, bn = blockIdx.x * 64;
  const int tid = threadIdx.x;
  const int tx = tid & 15, ty = tid >> 4;
  float acc[4][4] = {{0.f}};
  for (int k0 = z * 256; k0 < z * 256 + 256; k0 += 16) {
#pragma unroll
    for (int i0 = 0; i0 < 4; ++i0) {
      int i = tid + i0 * 256;
      int m = i >> 4, kk = i & 15;
      int gm = bm + m;
      float av = 0.f;
      if (gm < 504) {
        int b = gm / 252, rem = gm % 252;
        int n = rem >> 2, kv = rem & 3;
        int f = k0 + kk;
        int j = f >> 7, d = f & 127;
        av = kvproj[(size_t)(b * Tc + n * 16 + j) * KVP_LD + coloff + kv * 128 + d];
      }
      As[kk][m] = av;
      Ws[kk][m] = W[(size_t)(bn + m) * 4096 + (k0 + kk)];
    }
    __syncthreads();
#pragma unroll
    for (int kk = 0; kk < 16; ++kk) {
      float4 a4 = *reinterpret_cast<const float4*>(&As[kk][ty * 4]);
      float4 w4 = *reinterpret_cast<const float4*>(&Ws[kk][tx * 4]);
      float av[4] = {a4.x, a4.y, a4.z, a4.w};
      float wv[4] = {w4.x, w4.y, w4.z, w4.w};
#pragma unroll
      for (int i = 0; i < 4; ++i)
#pragma unroll
        for (int j = 0; j < 4; ++j) acc[i][j] = fmaf(av[i], wv[j], acc[i][j]);
    }
    __syncthreads();
  }
#pragma unroll
  for (int i = 0; i < 4; ++i) {
    int m = bm + ty * 4 + i;
    if (m >= 504) continue;
#pragma unroll
    for (int j = 0; j < 4; ++j)
      Cpart[(size_t)z * 64512 + (size_t)m * 128 + bn + tx * 4 + j] = acc[i][j];
  }
}

// ---------- bias_adj[o] = b1[o] + block_pos_flat . w1[o,:] ----------
__global__ void bias_adj_kernel(const float* __restrict__ bp,
                                const float* __restrict__ w1k,
                                const float* __restrict__ b1k,
                                const float* __restrict__ w1v,
                                const float* __restrict__ b1v,
                                float* __restrict__ outk,
                                float* __restrict__ outv) {
  __shared__ float red[4];
  const int o = blockIdx.x;
  const float* w1 = blockIdx.y ? w1v : w1k;
  float s = 0.f;
  for (int i = threadIdx.x; i < 4096; i += 256)
    s += bp[i] * w1[(size_t)o * 4096 + i];
#pragma unroll
  for (int off = 32; off; off >>= 1) s += __shfl_xor(s, off);
  if ((threadIdx.x & 63) == 0) red[threadIdx.x >> 6] = s;
  __syncthreads();
  if (threadIdx.x == 0) {
    float t = red[0] + red[1] + red[2] + red[3];
    if (blockIdx.y) outv[o] = t + b1v[o];
    else outk[o] = t + b1k[o];
  }
}

// ---------- reduce 16 partials + bias + gelu, k&v merged ----------
__global__ void reduce_gelu(const float* __restrict__ hk_part,
                            const float* __restrict__ hv_part,
                            const float* __restrict__ bias_k,
                            const float* __restrict__ bias_v,
                            float* __restrict__ hk, float* __restrict__ hv) {
  int gi = blockIdx.x * 256 + threadIdx.x;  // exact: 2*64512/256
  const bool isv = gi >= 64512;
  int i = isv ? gi - 64512 : gi;
  const float* parts = isv ? hv_part : hk_part;
  float s = (isv ? bias_v : bias_k)[i & 127];
#pragma unroll
  for (int z = 0; z < 16; ++z) s += parts[z * 64512 + i];
  (isv ? hv : hk)[i] = geluf(s);
}

// ---------- compress layer2, k&v merged ----------
__global__ __launch_bounds__(256) void gemm_l2(
    const float* __restrict__ hk, const float* __restrict__ w2k,
    const float* __restrict__ b2k, const float* __restrict__ hv,
    const float* __restrict__ w2v, const float* __restrict__ b2v,
    float* __restrict__ k_sum, float* __restrict__ v_sum) {
  __shared__ float As[16][68];
  __shared__ float Ws[16][68];
  const bool isv = blockIdx.z != 0;
  const float* A = isv ? hv : hk;
  const float* W = isv ? w2v : w2k;
  const float* bias = isv ? b2v : b2k;
  float* C = isv ? v_sum : k_sum;
  const int bm = blockIdx.y * 64, bn = blockIdx.x * 64;
  const int tid = threadIdx.x;
  const int tx = tid & 15, ty = tid >> 4;
  float acc[4][4] = {{0.f}};
  for (int k0 = 0; k0 < 128; k0 += 16) {
#pragma unroll
    for (int i0 = 0; i0 < 4; ++i0) {
      int i = tid + i0 * 256;
      int m = i >> 4, kk = i & 15;
      int gm = bm + m;
      As[kk][m] = (gm < 504) ? A[(size_t)gm * 128 + (k0 + kk)] : 0.f;
      Ws[kk][m] = W[(size_t)(bn + m) * 128 + (k0 + kk)];
    }
    __syncthreads();
#pragma unroll
    for (int kk = 0; kk < 16; ++kk) {
      float4 a4 = *reinterpret_cast<const float4*>(&As[kk][ty * 4]);
      float4 w4 = *reinterpret_cast<const float4*>(&Ws[kk][tx * 4]);
      float av[4] = {a4.x, a4.y, a4.z, a4.w};
      float wv[4] = {w4.x, w4.y, w4.z, w4.w};
#pragma unroll
      for (int i = 0; i < 4; ++i)
#pragma unroll
        for (int j = 0; j < 4; ++j) acc[i][j] = fmaf(av[i], wv[j], acc[i][j]);
    }
    __syncthreads();
  }
#pragma unroll
  for (int i = 0; i < 4; ++i) {
    int m = bm + ty * 4 + i;
    if (m >= 504) continue;
#pragma unroll
    for (int j = 0; j < 4; ++j)
      C[(size_t)m * 128 + bn + tx * 4 + j] = acc[i][j] + bias[bn + tx * 4 + j];
  }
}

// ---------- compressed attention + top-k: 4 query tokens per wg ----------
__global__ __launch_bounds__(256) void cmp_attn(
    const float* __restrict__ q, const float* __restrict__ k_sum,
    const float* __restrict__ v_sum, const float* __restrict__ kvproj,
    float* __restrict__ out, unsigned long long* __restrict__ sel) {
  __shared__ __align__(16) float q_s[4][4][128];
  __shared__ __align__(16) float ks[NBc * 128];
  __shared__ float p_s[4][4][64];

  const int wg = blockIdx.x;  // (b*4+kv)*256 + tq
  const int tq = wg & 255;
  const int kv = (wg >> 8) & 3;
  const int b = wg >> 10;
  const int t0 = tq * 4;
  const int tid = threadIdx.x;
  const int lane = tid & 63;
  const int g = tid >> 6;

  for (int i = tid; i < 2048; i += 256) {
    int gg = i >> 9, r = (i >> 7) & 3, d = i & 127;
    q_s[gg][r][d] = q[(((size_t)b * NQc + gg * NKVc + kv) * Tc + t0 + r) * 128 + d];
  }
  {
    const float* kbase = k_sum + (size_t)(b * 252 + kv) * 128;
    for (int i = tid; i < NBc * 32; i += 256) {
      int n = i >> 5, s = i & 31;
      f32x4 v4 = *(const f32x4*)(kbase + (size_t)n * 512 + s * 4);
      *(f32x4*)&ks[n * 128 + ((s ^ (n & 7)) << 2)] = v4;
    }
  }
  __syncthreads();

  float acc[4] = {0.f, 0.f, 0.f, 0.f};
  {
    const int lrow = (lane < 63) ? lane : 62;
    const int lx = lrow & 7;
#pragma unroll
    for (int s = 0; s < 32; ++s) {
      f32x4 k4 = *(const f32x4*)&ks[lrow * 128 + ((s ^ lx) << 2)];
#pragma unroll
      for (int r = 0; r < 4; ++r) {
        f32x4 q4 = *(const f32x4*)&q_s[g][r][s * 4];
        acc[r] = fmaf(q4[0], k4[0], acc[r]);
        acc[r] = fmaf(q4[1], k4[1], acc[r]);
        acc[r] = fmaf(q4[2], k4[2], acc[r]);
        acc[r] = fmaf(q4[3], k4[3], acc[r]);
      }
    }
  }
#pragma unroll
  for (int r = 0; r < 4; ++r) {
    const int t = t0 + r;
    const int nvalid = min(t / STRIDEc + 1, NBc);
    const bool valid = (lane < nvalid);
    float sval = valid ? acc[r] * SCALEc : -INFINITY;
    float m = sval;
#pragma unroll
    for (int off = 32; off; off >>= 1) m = fmaxf(m, __shfl_xor(m, off));
    float e = valid ? __expf(sval - m) : 0.f;
    float l = e;
#pragma unroll
    for (int off = 32; off; off >>= 1) l += __shfl_xor(l, off);
    p_s[g][r][lane] = e / fmaxf(l, 1e-9f);
  }
  __syncthreads();

  {  // top-k: wave g handles row r=g
    float v = p_s[0][g][lane] + p_s[1][g][lane] + p_s[2][g][lane] + p_s[3][g][lane];
    if (lane >= NBc) v = -1.f;
    unsigned long long mask = 0ull;
    for (int it = 0; it < TOPNc; ++it) {
      float mx = v;
#pragma unroll
      for (int off = 32; off; off >>= 1) mx = fmaxf(mx, __shfl_xor(mx, off));
      unsigned long long ball = __ballot(v == mx);
      int sl = __ffsll(ball) - 1;
      mask |= 1ull << sl;
      if (lane == sl) v = -1.f;
    }
    if (lane == 0) sel[(((size_t)b * NKVc + kv) << 10) + t0 + g] = mask;
  }
  {
    const float* vbase = v_sum + (size_t)(b * 252 + kv) * 128;
    for (int i = tid; i < NBc * 32; i += 256) {
      int n = i >> 5, s = i & 31;
      f32x4 v4 = *(const f32x4*)(vbase + (size_t)n * 512 + s * 4);
      *(f32x4*)&ks[n * 128 + ((s ^ (n & 7)) << 2)] = v4;
    }
  }
  __syncthreads();

  const int h = g * NKVc + kv;
  float ox[4] = {0.f, 0.f, 0.f, 0.f}, oy[4] = {0.f, 0.f, 0.f, 0.f};
  const int slotd = lane >> 1, wi = (lane & 1) * 2;
  const int nvmax = min((t0 + 3) / STRIDEc + 1, NBc);
  for (int n = 0; n < nvmax; ++n) {
    const float* vp = &ks[n * 128 + (((slotd ^ (n & 7)) << 2) | wi)];
    const float vx = vp[0], vy = vp[1];
#pragma unroll
    for (int r = 0; r < 4; ++r) {
      float pn = p_s[g][r][n];
      ox[r] = fmaf(pn, vx, ox[r]);
      oy[r] = fmaf(pn, vy, oy[r]);
    }
  }
#pragma unroll
  for (int r = 0; r < 4; ++r) {
    const int t = t0 + r;
    const float g0 = kvproj[(size_t)(b * Tc + t) * KVP_LD + 1024 + h * 3];
    size_t obase = ((size_t)(b * NQc + h) * Tc + t) * 128 + lane * 2;
    *(float2*)&out[obase] = make_float2(g0 * ox[r], g0 * oy[r]);
  }
}

// ---------- merged MFMA flash-tile attention, QBLK=32, 8 waves, double-buffered ----------
// mode 0 = slc (out +=), mode 1 = win (out2 =)
__global__ __launch_bounds__(512) void sparse_attn_mfma(
    const float* __restrict__ q, const bf16_t* __restrict__ kvbf,
    const bf16_t* __restrict__ VT, const float* __restrict__ kvproj,
    const unsigned long long* __restrict__ sel,
    float* __restrict__ out, float* __restrict__ out2) {
  __shared__ bf16_t KsB[2][64 * 128];   // [s][d], swz ^((s&7)<<4)  (via source pre-swz)
  __shared__ bf16_t VtB[2][128 * 64];   // [d][s], swz ^(((d>>1)&7)<<4)
  __shared__ bf16_t Ps[8][16 * 64];     // per-wave P, swz ^((row&7)<<4)

  const int wgi = blockIdx.x;
  const int mode = wgi & 1;
  const int u = wgi >> 1;
  const int tt = 31 - (u & 31);  // heavy (high-t) tiles first
  const int kv = (u >> 5) & 3;
  const int b = u >> 7;
  const int t0 = tt * 32;
  const int tid = threadIdx.x, lane = tid & 63;
  const int wv = tid >> 6;   // 0..7
  const int g = wv & 3;      // head
  const int half = wv >> 2;  // row-half
  const int t0h = t0 + half * 16;
  const int h = g * NKVc + kv;
  const int lr = lane >> 4;
  const int lc = lane & 15;

  // Q fragments for rows t0h + lc
  s16x8 aq[4];
  {
    const float* qrow = q + (((size_t)(b * NQc + h) * Tc) + t0h + lc) * 128;
#pragma unroll
    for (int ks = 0; ks < 4; ++ks) {
      f32x4 lo = *(const f32x4*)(qrow + ks * 32 + lr * 8);
      f32x4 hi = *(const f32x4*)(qrow + ks * 32 + lr * 8 + 4);
      s16x8 v;
#pragma unroll
      for (int e = 0; e < 4; ++e) {
        v[e] = (short)f2bf(lo[e]);
        v[e + 4] = (short)f2bf(hi[e]);
      }
      aq[ks] = v;
    }
  }

  unsigned long long hm[4] = {~0ull, ~0ull, ~0ull, ~0ull};
  unsigned long long um = ~0ull;
  int c0;
  const int c1 = (t0 + 31) >> 6;
  const unsigned long long* sb = sel + ((size_t)(b * NKVc + kv) << 10);
  if (mode == 0) {
#pragma unroll
    for (int r = 0; r < 4; ++r) {
      unsigned long long bm = sb[t0h + lr * 4 + r];
      hm[r] = bm | (bm << 1);
    }
    // wg-uniform union over all 32 rows (sel is head-independent) -> identical
    // in every wave => uniform barrier counts (no divergent skip hazard)
    unsigned long long uu = 0ull;
    if (lane < 32) {
      unsigned long long bm = sb[t0 + lane];
      uu = bm | (bm << 1);
    }
#pragma unroll
    for (int off = 32; off; off >>= 1) uu |= __shfl_xor(uu, off);
    um = uu;
    c0 = (__ffsll(um) - 1) >> 2;
  } else {
    int lo = t0 - (WINc - 1);
    c0 = (lo > 0 ? lo : 0) >> 6;
  }

  float run_m[4], run_l[4];
  f32x4 acc_o[8];
#pragma unroll
  for (int r = 0; r < 4; ++r) {
    run_m[r] = -INFINITY;
    run_l[r] = 0.f;
  }
#pragma unroll
  for (int j = 0; j < 8; ++j) acc_o[j] = 0.f;

  const bf16_t* kb = kvbf + (mode << 10) + kv * 128;
  const bf16_t* vt = VT + (size_t)((b * 4 + kv) * 2 + mode) * 131072;
  const size_t rbase = (size_t)b * Tc;

  auto STAGE = [&](int bufi, int c) {
    const int s0 = c * 64;
#pragma unroll
    for (int p = 0; p < 2; ++p) {  // K: 64 rows x 16 slots of 16B
      int o = p * 512 + tid;
      int s = o >> 4, sl = o & 15;
      int slot = sl ^ (s & 7);  // pre-swizzled source, linear dest (G21)
      load_lds16(kb + (rbase + s0 + s) * KVB_LD + slot * 8,
                 (char*)&KsB[bufi][0] + (p * 512 + wv * 64) * 16);
    }
#pragma unroll
    for (int p = 0; p < 2; ++p) {  // V^T: 128 rows x 8 slots of 16B
      int o = p * 512 + tid;
      int d = o >> 3, sl = o & 7;
      int slot = sl ^ ((d >> 1) & 7);
      load_lds16(vt + (size_t)d * 1024 + s0 + slot * 8,
                 (char*)&VtB[bufi][0] + (p * 512 + wv * 64) * 16);
    }
  };

  int c = c0;
  STAGE(0, c);
  int buf = 0;
  while (true) {
    int cn = c + 1;
    if (mode == 0)
      while (cn <= c1 && ((um >> (4 * cn)) & 0xFull) == 0ull) ++cn;
    __syncthreads();  // drains vmcnt(0): buf's stage complete; prev buf free
    if (cn <= c1) STAGE(buf ^ 1, cn);

    const int s0 = c * 64;
    const char* KsP = (const char*)&KsB[buf][0];
    const char* VtP = (const char*)&VtB[buf][0];

    // QK^T
    f32x4 accs[4];
#pragma unroll
    for (int j = 0; j < 4; ++j) accs[j] = 0.f;
    __builtin_amdgcn_s_setprio(1);
#pragma unroll
    for (int ks = 0; ks < 4; ++ks) {
      s16x8 bk[4];
#pragma unroll
      for (int j = 0; j < 4; ++j) {
        int sB = j * 16 + lc;
        bk[j] = *(const s16x8*)(KsP +
                                ((sB * 256 + (ks * 4 + lr) * 16) ^ ((sB & 7) << 4)));
      }
#pragma unroll
      for (int j = 0; j < 4; ++j)
        accs[j] = __builtin_amdgcn_mfma_f32_16x16x32_bf16(aq[ks], bk[j], accs[j], 0, 0, 0);
    }
    __builtin_amdgcn_s_setprio(0);

    // online softmax, write P to per-wave LDS
#pragma unroll
    for (int r = 0; r < 4; ++r) {
      const int t = t0h + lr * 4 + r;
      float ev[4];
      float mx = -INFINITY;
#pragma unroll
      for (int j = 0; j < 4; ++j) {
        int s = s0 + j * 16 + lc;
        bool att;
        if (mode == 0) att = (s <= t) && ((hm[r] >> (s >> 4)) & 1ull);
        else att = (s <= t) && (t - s < WINc);
        float sv = att ? accs[j][r] * SCALEc : -INFINITY;
        ev[j] = sv;
        mx = fmaxf(mx, sv);
      }
      mx = fmaxf(mx, __shfl_xor(mx, 1));
      mx = fmaxf(mx, __shfl_xor(mx, 2));
      mx = fmaxf(mx, __shfl_xor(mx, 4));
      mx = fmaxf(mx, __shfl_xor(mx, 8));
      const float nm = fmaxf(run_m[r], mx);
      const float resc = (run_m[r] == -INFINITY) ? 0.f : __expf(run_m[r] - nm);
      float cl = 0.f;
#pragma unroll
      for (int j = 0; j < 4; ++j) {
        float e = (ev[j] == -INFINITY) ? 0.f : __expf(ev[j] - nm);
        ev[j] = e;
        cl += e;
      }
      cl += __shfl_xor(cl, 1);
      cl += __shfl_xor(cl, 2);
      cl += __shfl_xor(cl, 4);
      cl += __shfl_xor(cl, 8);
      run_l[r] = run_l[r] * resc + cl;
      run_m[r] = nm;
#pragma unroll
      for (int jo = 0; jo < 8; ++jo) acc_o[jo][r] *= resc;
      const int row = lr * 4 + r;
#pragma unroll
      for (int j = 0; j < 4; ++j) {
        int col = j * 16 + lc;
        *(bf16_t*)((char*)Ps[wv] + ((row * 128 + col * 2) ^ ((row & 7) << 4))) =
            f2bf(ev[j]);
      }
    }

    // PV (same-wave P round-trip)
    asm volatile("s_waitcnt lgkmcnt(0)" ::: "memory");
    __builtin_amdgcn_sched_barrier(0);
    s16x8 ap[2];
#pragma unroll
    for (int k2 = 0; k2 < 2; ++k2)
      ap[k2] = *(const s16x8*)((const char*)Ps[wv] +
                               ((lc * 128 + k2 * 64 + lr * 16) ^ ((lc & 7) << 4)));
    __builtin_amdgcn_s_setprio(1);
#pragma unroll
    for (int k2 = 0; k2 < 2; ++k2) {
#pragma unroll
      for (int jo = 0; jo < 8; ++jo) {
        int d = jo * 16 + lc;
        s16x8 bv = *(const s16x8*)(VtP +
                                   ((d * 128 + k2 * 64 + lr * 16) ^ (((d >> 1) & 7) << 4)));
        acc_o[jo] = __builtin_amdgcn_mfma_f32_16x16x32_bf16(ap[k2], bv, acc_o[jo], 0, 0, 0);
      }
    }
    __builtin_amdgcn_s_setprio(0);

    if (cn > c1) break;
    buf ^= 1;
    c = cn;
  }

  // epilogue
#pragma unroll
  for (int r = 0; r < 4; ++r) {
    const int t = t0h + lr * 4 + r;
    const float gg = kvproj[(rbase + t) * KVP_LD + 1024 + h * 3 + 1 + mode];
    const float sc = gg / fmaxf(run_l[r], 1e-9f);
    const size_t ob = ((size_t)(b * NQc + h) * Tc + t) * 128;
#pragma unroll
    for (int jo = 0; jo < 8; ++jo) {
      size_t oi = ob + jo * 16 + lc;
      float v = acc_o[jo][r] * sc;
      if (mode == 0) out[oi] += v;
      else out2[oi] = v;
    }
  }
}

// ---------- out += out2 ----------
__global__ void add_out(float* __restrict__ out, const float* __restrict__ out2) {
  size_t i = (size_t)blockIdx.x * 256 + threadIdx.x;  // exact: 4194304/256
  out[i] += out2[i];
}

extern "C" void kernel_launch(void* const* d_in, const int* in_sizes, int n_in,
                              void* d_out, int out_size, void* d_ws, size_t ws_size,
                              hipStream_t stream) {
  const float* x = (const float*)d_in[0];
  const float* q = (const float*)d_in[1];
  const float* gate_w = (const float*)d_in[2];
  const float* gate_b = (const float*)d_in[3];
  const float* wk_cmp = (const float*)d_in[4];
  const float* wv_cmp = (const float*)d_in[5];
  const float* wk_slc = (const float*)d_in[6];
  const float* wv_slc = (const float*)d_in[7];
  const float* wk_win = (const float*)d_in[8];
  const float* wv_win = (const float*)d_in[9];
  const float* block_pos = (const float*)d_in[10];
  const float* ck1_w = (const float*)d_in[11];
  const float* ck1_b = (const float*)d_in[12];
  const float* ck2_w = (const float*)d_in[13];
  const float* ck2_b = (const float*)d_in[14];
  const float* cv1_w = (const float*)d_in[15];
  const float* cv1_b = (const float*)d_in[16];
  const float* cv2_w = (const float*)d_in[17];
  const float* cv2_b = (const float*)d_in[18];
  float* out = (float*)d_out;

  char* wsp = (char*)d_ws;
  // [0, 10485760)            kvproj f32 2048 x 1280
  // [10485760, 18874368)     kvbf bf16 2048 x 2048 (K slices only)
  // [18874368, 35651584)     xbf -> part(z0..z3) -> hk_part/hv_part -> out2
  // [27262976, ...)          Wcat (within above before part z2/z3... see order)
  // [35651584, 36684800)     hk/hv/k_sum/v_sum/bias_k/v
  // [38273024, 38285824)     bias_cat
  // [38285824, 38351360)     selB
  // [38351360, 42545664)     VT bf16 (16 slices x 128 x 1024)
  float* kvproj = (float*)wsp;
  bf16_t* kvbf = (bf16_t*)(wsp + 10485760);
  bf16_t* xbf = (bf16_t*)(wsp + 18874368);
  bf16_t* Wcat = (bf16_t*)(wsp + 27262976);
  float* bias_cat = (float*)(wsp + 38273024);
  unsigned long long* selB = (unsigned long long*)(wsp + 38285824);
  bf16_t* VT = (bf16_t*)(wsp + 38351360);

  float* part = (float*)(wsp + 18874368);      // 4 x 2048*512*4 = 16,777,216
  float* hk_part = (float*)(wsp + 18874368);   // 16*64512*4 = 4,128,768
  float* hv_part = (float*)(wsp + 23003136);
  float* out2 = (float*)(wsp + 18874368);      // 16 MB (after parts dead)
  float* hk = (float*)(wsp + 35651584);
  float* hv = (float*)(wsp + 35909632);
  float* k_sum = (float*)(wsp + 36167680);
  float* v_sum = (float*)(wsp + 36425728);
  float* bias_k = (float*)(wsp + 36683776);
  float* bias_v = (float*)(wsp + 36684288);

  dim3 blk256(256);

  conv_x<<<16384, blk256, 0, stream>>>(x, xbf);
  build_wcat<<<21504, blk256, 0, stream>>>(wv_cmp, wk_slc, wv_slc, wk_win,
                                           wv_win, gate_w, gate_b, Wcat, bias_cat);

  gemm_mfma<<<dim3(21, 16), blk256, 0, stream>>>(xbf, 2048, Wcat, 2048, kvproj,
                                                 kvbf, VT, bias_cat, 2048);
  // k_cmp: exact f32 split-K x4 (overwrites xbf/Wcat regions)
  gemm_xwt<<<dim3(8, 32, 4), blk256, 0, stream>>>(x, 2048, wk_cmp, 2048, part,
                                                  512, 2048, 512, 512);
  rope_k_fused<<<Bc * Tc * NKVc, 64, 0, stream>>>(part, kvproj);
  rope_bf<<<dim3(Bc * Tc * NKVc, 2), 64, 0, stream>>>(kvbf);

  bias_adj_kernel<<<dim3(128, 2), blk256, 0, stream>>>(block_pos, ck1_w, ck1_b,
                                                       cv1_w, cv1_b, bias_k, bias_v);
  gemm_cmp1<<<dim3(2, 8, 32), blk256, 0, stream>>>(kvproj, ck1_w, cv1_w,
                                                   hk_part, hv_part);
  reduce_gelu<<<504, blk256, 0, stream>>>(hk_part, hv_part, bias_k, bias_v, hk, hv);
  gemm_l2<<<dim3(2, 8, 2), blk256, 0, stream>>>(hk, ck2_w, ck2_b, hv, cv2_w,
                                                cv2_b, k_sum, v_sum);

  cmp_attn<<<2048, blk256, 0, stream>>>(q, k_sum, v_sum, kvproj, out, selB);
  sparse_attn_mfma<<<512, dim3(512), 0, stream>>>(q, kvbf, VT, kvproj, selB, out, out2);
  add_out<<<16384, blk256, 0, stream>>>(out, out2);
}

// Round 8
// 379.776 us; speedup vs baseline: 10.5308x; 1.0905x over previous
//
#include <hip/hip_runtime.h>
#include <hip/hip_bf16.h>
#include <math.h>

#define Bc 2
#define Tc 1024
#define DMc 2048
#define NQc 16
#define NKVc 4
#define DHc 128
#define BLKc 32
#define STRIDEc 16
#define TOPNc 16
#define WINc 512
#define NREPc 4
#define NBc 63
#define SCALEc 0.08838834764831843f
#define KVP_LD 1280   // kvproj f32: 0..511 k_cmp | 512..1023 v_cmp | 1024..1071 gates | pad
#define KVB_LD 2048   // kvbf bf16: 0..511 k_slc | 1024..1535 k_win (v slices go to VT)

typedef unsigned short bf16_t;
typedef short s16x8 __attribute__((ext_vector_type(8)));
typedef float f32x4 __attribute__((ext_vector_type(4)));
typedef unsigned short u16x4 __attribute__((ext_vector_type(4)));
typedef unsigned int u32x4 __attribute__((ext_vector_type(4)));

__device__ __forceinline__ unsigned short f2bf(float f) {
  unsigned int u = __float_as_uint(f);
  u += 0x7fffu + ((u >> 16) & 1u);
  return (unsigned short)(u >> 16);
}
__device__ __forceinline__ float bf2f(unsigned short h) {
  return __uint_as_float((unsigned int)h << 16);
}
__device__ __forceinline__ float geluf(float x) {
  return 0.5f * x * (1.0f + erff(x * 0.7071067811865476f));
}
__device__ __forceinline__ void load_lds16(const void* g, void* l) {
  __builtin_amdgcn_global_load_lds(
      (const __attribute__((address_space(1))) void*)g,
      (__attribute__((address_space(3))) void*)l, 16, 0, 0);
}

// ---------- x -> bf16 ----------
__global__ void conv_x(const float* __restrict__ x, bf16_t* __restrict__ xbf) {
  size_t i = (size_t)blockIdx.x * 256 + threadIdx.x;  // exact: 2048*2048/256
  xbf[i] = f2bf(x[i]);
}

// ---------- concat weights rows 512..3199 into bf16 Wcat ----------
__global__ void build_wcat(
    const float* __restrict__ wv_cmp, const float* __restrict__ wk_slc,
    const float* __restrict__ wv_slc, const float* __restrict__ wk_win,
    const float* __restrict__ wv_win, const float* __restrict__ gate_w,
    const float* __restrict__ gate_b, bf16_t* __restrict__ Wcat,
    float* __restrict__ bias_cat) {
  size_t i = (size_t)blockIdx.x * 256 + threadIdx.x;  // exact: 2688*2048/256
  int rr = (int)(i >> 11), c = (int)(i & 2047);
  int r = rr + 512;
  float v = 0.f;
  if (r < 3072) {
    int blk = r >> 9;  // 1..5
    size_t o = (size_t)(r & 511) * 2048 + c;
    if (blk == 1) v = wv_cmp[o];
    else if (blk == 2) v = wk_slc[o];
    else if (blk == 3) v = wv_slc[o];
    else if (blk == 4) v = wk_win[o];
    else v = wv_win[o];
  } else if (r < 3120) {
    v = gate_w[(size_t)(r - 3072) * 2048 + c];
  }
  Wcat[i] = f2bf(v);
  if (c == 0) bias_cat[r] = (r >= 3072 && r < 3120) ? gate_b[r - 3072] : 0.f;
}

// ---------- bf16 MFMA GEMM: cols 512..3199 ----------
__global__ __launch_bounds__(256) void gemm_mfma(
    const bf16_t* __restrict__ A, int lda,
    const bf16_t* __restrict__ Bw, int ldb,
    float* __restrict__ kvproj, bf16_t* __restrict__ kvbf,
    bf16_t* __restrict__ VT, const float* __restrict__ bias, int K) {
  __shared__ bf16_t As[128 * 32];
  __shared__ bf16_t Bs[128 * 32];
  const int bm = blockIdx.y * 128, bnw = blockIdx.x * 128, bn = 512 + bnw;
  const int tid = threadIdx.x, lane = tid & 63, w = tid >> 6;
  const int wr = (w >> 1) * 64, wc = (w & 1) * 64;

  f32x4 acc[4][4];
#pragma unroll
  for (int i = 0; i < 4; ++i)
#pragma unroll
    for (int j = 0; j < 4; ++j) acc[i][j] = 0.f;

  const int srow = lane >> 2;
  const int sslot = lane & 3;

  for (int k0 = 0; k0 < K; k0 += 32) {
    __syncthreads();
#pragma unroll
    for (int j = 0; j < 2; ++j) {
      int rb = w * 32 + j * 16;
      int row = rb + srow;
      int slot = sslot ^ ((row >> 1) & 3);
      load_lds16(A + (size_t)(bm + row) * lda + k0 + slot * 8, &As[rb * 32]);
      load_lds16(Bw + (size_t)(bnw + row) * ldb + k0 + slot * 8, &Bs[rb * 32]);
    }
    __syncthreads();

    s16x8 af[4], bfr[4];
#pragma unroll
    for (int i = 0; i < 4; ++i) {
      int ar = wr + i * 16 + (lane & 15);
      int as = ((lane >> 4) ^ ((ar >> 1) & 3)) * 8;
      af[i] = *(const s16x8*)&As[ar * 32 + as];
      int br = wc + i * 16 + (lane & 15);
      int bs = ((lane >> 4) ^ ((br >> 1) & 3)) * 8;
      bfr[i] = *(const s16x8*)&Bs[br * 32 + bs];
    }
#pragma unroll
    for (int i = 0; i < 4; ++i)
#pragma unroll
      for (int j = 0; j < 4; ++j)
        acc[i][j] = __builtin_amdgcn_mfma_f32_16x16x32_bf16(af[i], bfr[j], acc[i][j], 0, 0, 0);
  }

#pragma unroll
  for (int i = 0; i < 4; ++i) {
    int row = bm + wr + i * 16 + ((lane >> 4) << 2);
#pragma unroll
    for (int j = 0; j < 4; ++j) {
      int col = bn + wc + j * 16 + (lane & 15);
      float bv = bias[col];
      float vals[4];
#pragma unroll
      for (int r = 0; r < 4; ++r) vals[r] = acc[i][j][r] + bv;
      if (col < 1024) {  // v_cmp -> f32 kvproj
#pragma unroll
        for (int r = 0; r < 4; ++r)
          kvproj[(size_t)(row + r) * KVP_LD + col] = vals[r];
      } else if (col < 3072) {
        int cc = col - 1024;
        int region = cc >> 9;  // 0 k_slc, 1 v_slc, 2 k_win, 3 v_win
        if ((region & 1) == 0) {
#pragma unroll
          for (int r = 0; r < 4; ++r)
            kvbf[(size_t)(row + r) * KVB_LD + cc] = f2bf(vals[r]);
        } else {
          int mode = region >> 1;
          int kv = (cc >> 7) & 3, d = cc & 127;
          int b = row >> 10;
          u16x4 w4;
#pragma unroll
          for (int r = 0; r < 4; ++r) w4[r] = f2bf(vals[r]);
          *(u16x4*)(VT + (size_t)((b * 4 + kv) * 2 + mode) * 131072 +
                    d * 1024 + (row & 1023)) = w4;
        }
      } else {
#pragma unroll
        for (int r = 0; r < 4; ++r)
          kvproj[(size_t)(row + r) * KVP_LD + (col - 2048)] =
              1.f / (1.f + __expf(-vals[r]));
      }
    }
  }
}

// ---------- f32 VALU GEMM (split-K partials via blockIdx.z) ----------
__global__ __launch_bounds__(256) void gemm_xwt(
    const float* __restrict__ A, int lda, const float* __restrict__ W, int ldw,
    float* __restrict__ C, int ldc, int M, int N, int K) {
  __shared__ float As[16][68];
  __shared__ float Ws[16][68];
  const int z = blockIdx.z;
  A += (size_t)z * K;
  W += (size_t)z * K;
  C += (size_t)z * (size_t)M * ldc;
  const int bm = blockIdx.y * 64, bn = blockIdx.x * 64;
  const int tid = threadIdx.x;
  const int tx = tid & 15, ty = tid >> 4;
  float acc[4][4] = {{0.f}};
  for (int k0 = 0; k0 < K; k0 += 16) {
#pragma unroll
    for (int i0 = 0; i0 < 4; ++i0) {
      int i = tid + i0 * 256;
      int m = i >> 4, kk = i & 15;
      As[kk][m] = A[(size_t)(bm + m) * lda + (k0 + kk)];
      Ws[kk][m] = W[(size_t)(bn + m) * ldw + (k0 + kk)];
    }
    __syncthreads();
#pragma unroll
    for (int kk = 0; kk < 16; ++kk) {
      float4 a4 = *reinterpret_cast<const float4*>(&As[kk][ty * 4]);
      float4 w4 = *reinterpret_cast<const float4*>(&Ws[kk][tx * 4]);
      float av[4] = {a4.x, a4.y, a4.z, a4.w};
      float wv[4] = {w4.x, w4.y, w4.z, w4.w};
#pragma unroll
      for (int i = 0; i < 4; ++i)
#pragma unroll
        for (int j = 0; j < 4; ++j) acc[i][j] = fmaf(av[i], wv[j], acc[i][j]);
    }
    __syncthreads();
  }
#pragma unroll
  for (int i = 0; i < 4; ++i)
#pragma unroll
    for (int j = 0; j < 4; ++j)
      C[(size_t)(bm + ty * 4 + i) * ldc + bn + tx * 4 + j] = acc[i][j];
}

// ---------- reduce 4 k_cmp partials + RoPE -> kvproj cols 0..511 ----------
__global__ void rope_k_fused(const float* __restrict__ part,
                             float* __restrict__ kvproj) {
  int blk = blockIdx.x;  // (b*T+t)*KV+kv
  int kv = blk & 3;
  int t = (blk >> 2) & (Tc - 1);
  int b = blk >> 12;
  int d = threadIdx.x;  // 0..63
  size_t base = (size_t)(b * Tc + t) * 512 + kv * 128;
  float x1 = part[base + d] + part[1048576 + base + d] +
             part[2097152 + base + d] + part[3145728 + base + d];
  float x2 = part[base + d + 64] + part[1048576 + base + d + 64] +
             part[2097152 + base + d + 64] + part[3145728 + base + d + 64];
  float inv = powf(10000.f, -(float)d * (1.f / 64.f));
  float ang = (float)t * inv;
  float s, c;
  sincosf(ang, &s, &c);
  float* p = kvproj + (size_t)(b * Tc + t) * KVP_LD + kv * 128;
  p[d] = x1 * c - x2 * s;
  p[d + 64] = x1 * s + x2 * c;
}

// ---------- RoPE in place on kvbf K slices (bf16) ----------
__global__ void rope_bf(bf16_t* __restrict__ kvbf) {
  int blk = blockIdx.x;
  int coloff = blockIdx.y << 10;  // 0 (slc K) or 1024 (win K)
  int kv = blk & 3;
  int t = (blk >> 2) & (Tc - 1);
  int b = blk >> 12;
  bf16_t* p = kvbf + (size_t)(b * Tc + t) * KVB_LD + coloff + kv * 128;
  int d = threadIdx.x;
  float inv = powf(10000.f, -(float)d * (1.f / 64.f));
  float ang = (float)t * inv;
  float s, c;
  sincosf(ang, &s, &c);
  float x1 = bf2f(p[d]), x2 = bf2f(p[d + 64]);
  p[d] = f2bf(x1 * c - x2 * s);
  p[d + 64] = f2bf(x1 * s + x2 * c);
}

// ---------- compress layer1: gathered-A GEMM, split-K x16, k&v merged ----------
__global__ __launch_bounds__(256) void gemm_cmp1(
    const float* __restrict__ kvproj,
    const float* __restrict__ ck1_w, const float* __restrict__ cv1_w,
    float* __restrict__ hk_part, float* __restrict__ hv_part) {
  __shared__ float As[16][68];
  __shared__ float Ws[16][68];
  const int zz = blockIdx.z;
  const bool isv = zz >= 16;
  const int z = zz & 15;
  const int coloff = isv ? 512 : 0;
  const float* W = isv ? cv1_w : ck1_w;
  float* Cpart = isv ? hv_part : hk_part;
  const int bm = blockIdx.y * 64, bn = blockIdx.x * 64;
  const int tid = threadIdx.x;
  const int tx = tid & 15, ty = tid >> 4;
  float acc[4][4] = {{0.f}};
  for (int k0 = z * 256; k0 < z * 256 + 256; k0 += 16) {
#pragma unroll
    for (int i0 = 0; i0 < 4; ++i0) {
      int i = tid + i0 * 256;
      int m = i >> 4, kk = i & 15;
      int gm = bm + m;
      float av = 0.f;
      if (gm < 504) {
        int b = gm / 252, rem = gm % 252;
        int n = rem >> 2, kv = rem & 3;
        int f = k0 + kk;
        int j = f >> 7, d = f & 127;
        av = kvproj[(size_t)(b * Tc + n * 16 + j) * KVP_LD + coloff + kv * 128 + d];
      }
      As[kk][m] = av;
      Ws[kk][m] = W[(size_t)(bn + m) * 4096 + (k0 + kk)];
    }
    __syncthreads();
#pragma unroll
    for (int kk = 0; kk < 16; ++kk) {
      float4 a4 = *reinterpret_cast<const float4*>(&As[kk][ty * 4]);
      float4 w4 = *reinterpret_cast<const float4*>(&Ws[kk][tx * 4]);
      float av[4] = {a4.x, a4.y, a4.z, a4.w};
      float wv[4] = {w4.x, w4.y, w4.z, w4.w};
#pragma unroll
      for (int i = 0; i < 4; ++i)
#pragma unroll
        for (int j = 0; j < 4; ++j) acc[i][j] = fmaf(av[i], wv[j], acc[i][j]);
    }
    __syncthreads();
  }
#pragma unroll
  for (int i = 0; i < 4; ++i) {
    int m = bm + ty * 4 + i;
    if (m >= 504) continue;
#pragma unroll
    for (int j = 0; j < 4; ++j)
      Cpart[(size_t)z * 64512 + (size_t)m * 128 + bn + tx * 4 + j] = acc[i][j];
  }
}

// ---------- bias_adj[o] = b1[o] + block_pos_flat . w1[o,:] ----------
__global__ void bias_adj_kernel(const float* __restrict__ bp,
                                const float* __restrict__ w1k,
                                const float* __restrict__ b1k,
                                const float* __restrict__ w1v,
                                const float* __restrict__ b1v,
                                float* __restrict__ outk,
                                float* __restrict__ outv) {
  __shared__ float red[4];
  const int o = blockIdx.x;
  const float* w1 = blockIdx.y ? w1v : w1k;
  float s = 0.f;
  for (int i = threadIdx.x; i < 4096; i += 256)
    s += bp[i] * w1[(size_t)o * 4096 + i];
#pragma unroll
  for (int off = 32; off; off >>= 1) s += __shfl_xor(s, off);
  if ((threadIdx.x & 63) == 0) red[threadIdx.x >> 6] = s;
  __syncthreads();
  if (threadIdx.x == 0) {
    float t = red[0] + red[1] + red[2] + red[3];
    if (blockIdx.y) outv[o] = t + b1v[o];
    else outk[o] = t + b1k[o];
  }
}

// ---------- reduce 16 partials + bias + gelu, k&v merged ----------
__global__ void reduce_gelu(const float* __restrict__ hk_part,
                            const float* __restrict__ hv_part,
                            const float* __restrict__ bias_k,
                            const float* __restrict__ bias_v,
                            float* __restrict__ hk, float* __restrict__ hv) {
  int gi = blockIdx.x * 256 + threadIdx.x;  // exact: 2*64512/256
  const bool isv = gi >= 64512;
  int i = isv ? gi - 64512 : gi;
  const float* parts = isv ? hv_part : hk_part;
  float s = (isv ? bias_v : bias_k)[i & 127];
#pragma unroll
  for (int z = 0; z < 16; ++z) s += parts[z * 64512 + i];
  (isv ? hv : hk)[i] = geluf(s);
}

// ---------- compress layer2, k&v merged ----------
__global__ __launch_bounds__(256) void gemm_l2(
    const float* __restrict__ hk, const float* __restrict__ w2k,
    const float* __restrict__ b2k, const float* __restrict__ hv,
    const float* __restrict__ w2v, const float* __restrict__ b2v,
    float* __restrict__ k_sum, float* __restrict__ v_sum) {
  __shared__ float As[16][68];
  __shared__ float Ws[16][68];
  const bool isv = blockIdx.z != 0;
  const float* A = isv ? hv : hk;
  const float* W = isv ? w2v : w2k;
  const float* bias = isv ? b2v : b2k;
  float* C = isv ? v_sum : k_sum;
  const int bm = blockIdx.y * 64, bn = blockIdx.x * 64;
  const int tid = threadIdx.x;
  const int tx = tid & 15, ty = tid >> 4;
  float acc[4][4] = {{0.f}};
  for (int k0 = 0; k0 < 128; k0 += 16) {
#pragma unroll
    for (int i0 = 0; i0 < 4; ++i0) {
      int i = tid + i0 * 256;
      int m = i >> 4, kk = i & 15;
      int gm = bm + m;
      As[kk][m] = (gm < 504) ? A[(size_t)gm * 128 + (k0 + kk)] : 0.f;
      Ws[kk][m] = W[(size_t)(bn + m) * 128 + (k0 + kk)];
    }
    __syncthreads();
#pragma unroll
    for (int kk = 0; kk < 16; ++kk) {
      float4 a4 = *reinterpret_cast<const float4*>(&As[kk][ty * 4]);
      float4 w4 = *reinterpret_cast<const float4*>(&Ws[kk][tx * 4]);
      float av[4] = {a4.x, a4.y, a4.z, a4.w};
      float wv[4] = {w4.x, w4.y, w4.z, w4.w};
#pragma unroll
      for (int i = 0; i < 4; ++i)
#pragma unroll
        for (int j = 0; j < 4; ++j) acc[i][j] = fmaf(av[i], wv[j], acc[i][j]);
    }
    __syncthreads();
  }
#pragma unroll
  for (int i = 0; i < 4; ++i) {
    int m = bm + ty * 4 + i;
    if (m >= 504) continue;
#pragma unroll
    for (int j = 0; j < 4; ++j)
      C[(size_t)m * 128 + bn + tx * 4 + j] = acc[i][j] + bias[bn + tx * 4 + j];
  }
}

// ---------- compressed attention + top-k: 4 query tokens per wg ----------
__global__ __launch_bounds__(256) void cmp_attn(
    const float* __restrict__ q, const float* __restrict__ k_sum,
    const float* __restrict__ v_sum, const float* __restrict__ kvproj,
    float* __restrict__ out, unsigned long long* __restrict__ sel) {
  __shared__ __align__(16) float q_s[4][4][128];
  __shared__ __align__(16) float ks[NBc * 128];
  __shared__ float p_s[4][4][64];

  const int wg = blockIdx.x;  // (b*4+kv)*256 + tq
  const int tq = wg & 255;
  const int kv = (wg >> 8) & 3;
  const int b = wg >> 10;
  const int t0 = tq * 4;
  const int tid = threadIdx.x;
  const int lane = tid & 63;
  const int g = tid >> 6;

  for (int i = tid; i < 2048; i += 256) {
    int gg = i >> 9, r = (i >> 7) & 3, d = i & 127;
    q_s[gg][r][d] = q[(((size_t)b * NQc + gg * NKVc + kv) * Tc + t0 + r) * 128 + d];
  }
  {
    const float* kbase = k_sum + (size_t)(b * 252 + kv) * 128;
    for (int i = tid; i < NBc * 32; i += 256) {
      int n = i >> 5, s = i & 31;
      f32x4 v4 = *(const f32x4*)(kbase + (size_t)n * 512 + s * 4);
      *(f32x4*)&ks[n * 128 + ((s ^ (n & 7)) << 2)] = v4;
    }
  }
  __syncthreads();

  float acc[4] = {0.f, 0.f, 0.f, 0.f};
  {
    const int lrow = (lane < 63) ? lane : 62;
    const int lx = lrow & 7;
#pragma unroll
    for (int s = 0; s < 32; ++s) {
      f32x4 k4 = *(const f32x4*)&ks[lrow * 128 + ((s ^ lx) << 2)];
#pragma unroll
      for (int r = 0; r < 4; ++r) {
        f32x4 q4 = *(const f32x4*)&q_s[g][r][s * 4];
        acc[r] = fmaf(q4[0], k4[0], acc[r]);
        acc[r] = fmaf(q4[1], k4[1], acc[r]);
        acc[r] = fmaf(q4[2], k4[2], acc[r]);
        acc[r] = fmaf(q4[3], k4[3], acc[r]);
      }
    }
  }
#pragma unroll
  for (int r = 0; r < 4; ++r) {
    const int t = t0 + r;
    const int nvalid = min(t / STRIDEc + 1, NBc);
    const bool valid = (lane < nvalid);
    float sval = valid ? acc[r] * SCALEc : -INFINITY;
    float m = sval;
#pragma unroll
    for (int off = 32; off; off >>= 1) m = fmaxf(m, __shfl_xor(m, off));
    float e = valid ? __expf(sval - m) : 0.f;
    float l = e;
#pragma unroll
    for (int off = 32; off; off >>= 1) l += __shfl_xor(l, off);
    p_s[g][r][lane] = e / fmaxf(l, 1e-9f);
  }
  __syncthreads();

  {  // top-k: wave g handles row r=g
    float v = p_s[0][g][lane] + p_s[1][g][lane] + p_s[2][g][lane] + p_s[3][g][lane];
    if (lane >= NBc) v = -1.f;
    unsigned long long mask = 0ull;
    for (int it = 0; it < TOPNc; ++it) {
      float mx = v;
#pragma unroll
      for (int off = 32; off; off >>= 1) mx = fmaxf(mx, __shfl_xor(mx, off));
      unsigned long long ball = __ballot(v == mx);
      int sl = __ffsll(ball) - 1;
      mask |= 1ull << sl;
      if (lane == sl) v = -1.f;
    }
    if (lane == 0) sel[(((size_t)b * NKVc + kv) << 10) + t0 + g] = mask;
  }
  {
    const float* vbase = v_sum + (size_t)(b * 252 + kv) * 128;
    for (int i = tid; i < NBc * 32; i += 256) {
      int n = i >> 5, s = i & 31;
      f32x4 v4 = *(const f32x4*)(vbase + (size_t)n * 512 + s * 4);
      *(f32x4*)&ks[n * 128 + ((s ^ (n & 7)) << 2)] = v4;
    }
  }
  __syncthreads();

  const int h = g * NKVc + kv;
  float ox[4] = {0.f, 0.f, 0.f, 0.f}, oy[4] = {0.f, 0.f, 0.f, 0.f};
  const int slotd = lane >> 1, wi = (lane & 1) * 2;
  const int nvmax = min((t0 + 3) / STRIDEc + 1, NBc);
  for (int n = 0; n < nvmax; ++n) {
    const float* vp = &ks[n * 128 + (((slotd ^ (n & 7)) << 2) | wi)];
    const float vx = vp[0], vy = vp[1];
#pragma unroll
    for (int r = 0; r < 4; ++r) {
      float pn = p_s[g][r][n];
      ox[r] = fmaf(pn, vx, ox[r]);
      oy[r] = fmaf(pn, vy, oy[r]);
    }
  }
#pragma unroll
  for (int r = 0; r < 4; ++r) {
    const int t = t0 + r;
    const float g0 = kvproj[(size_t)(b * Tc + t) * KVP_LD + 1024 + h * 3];
    size_t obase = ((size_t)(b * NQc + h) * Tc + t) * 128 + lane * 2;
    *(float2*)&out[obase] = make_float2(g0 * ox[r], g0 * oy[r]);
  }
}

// ---------- merged MFMA flash-tile attention (swapped-QK, in-register P) ----------
// mode 0 = slc (out +=), mode 1 = win (out2 =); QBLK=32, 8 waves, dbuf K/V, 64KB LDS
__global__ __launch_bounds__(512, 4) void sparse_attn_mfma(
    const float* __restrict__ q, const bf16_t* __restrict__ kvbf,
    const bf16_t* __restrict__ VT, const float* __restrict__ kvproj,
    const unsigned long long* __restrict__ sel,
    float* __restrict__ out, float* __restrict__ out2) {
  __shared__ bf16_t KsB[2][64 * 128];   // [s][d], swz ^((s&7)<<4) via pre-swz source
  __shared__ bf16_t VtB[2][128 * 64];   // [d][s], swz ^(((d>>1)&7)<<4)

  const int wgi = blockIdx.x;
  const int mode = wgi & 1;
  const int u = wgi >> 1;
  const int tt = 31 - (u & 31);  // heavy (high-t) tiles first
  const int kv = (u >> 5) & 3;
  const int b = u >> 7;
  const int t0 = tt * 32;
  const int tid = threadIdx.x, lane = tid & 63;
  const int wv = tid >> 6;   // 0..7
  const int g = wv & 3;      // head
  const int half = wv >> 2;  // row-half
  const int t0h = t0 + half * 16;
  const int h = g * NKVc + kv;
  const int lr = lane >> 4;
  const int lc = lane & 15;
  const int tL = t0h + lc;   // this lane's softmax column (query row)

  // Q fragments (B-operand): rows t0h+lc
  s16x8 aq[4];
  {
    const float* qrow = q + (((size_t)(b * NQc + h) * Tc) + tL) * 128;
#pragma unroll
    for (int ks = 0; ks < 4; ++ks) {
      f32x4 lo = *(const f32x4*)(qrow + ks * 32 + lr * 8);
      f32x4 hi = *(const f32x4*)(qrow + ks * 32 + lr * 8 + 4);
      s16x8 v;
#pragma unroll
      for (int e = 0; e < 4; ++e) {
        v[e] = (short)f2bf(lo[e]);
        v[e + 4] = (short)f2bf(hi[e]);
      }
      aq[ks] = v;
    }
  }

  unsigned long long hm = ~0ull;
  unsigned long long um = ~0ull;
  int c0;
  const int c1 = (t0 + 31) >> 6;
  const unsigned long long* sb = sel + ((size_t)(b * NKVc + kv) << 10);
  if (mode == 0) {
    unsigned long long bm = sb[tL];
    hm = bm | (bm << 1);  // token s attended iff bit (s>>4)
    // wg-uniform union over all 32 rows => uniform barrier counts in every wave
    unsigned long long uu = 0ull;
    if (lane < 32) {
      unsigned long long b2 = sb[t0 + lane];
      uu = b2 | (b2 << 1);
    }
#pragma unroll
    for (int off = 32; off; off >>= 1) uu |= __shfl_xor(uu, off);
    um = uu;
    c0 = (__ffsll(um) - 1) >> 2;
  } else {
    int lo = t0 - (WINc - 1);
    c0 = (lo > 0 ? lo : 0) >> 6;
  }

  float run_m = -INFINITY, run_l = 0.f;  // per-lane, for t = tL
  f32x4 acc_o[8];                        // O[t=t0h+lr*4+r][d=jo*16+lc]
#pragma unroll
  for (int j = 0; j < 8; ++j) acc_o[j] = 0.f;

  const bf16_t* kb = kvbf + (mode << 10) + kv * 128;
  const bf16_t* vt = VT + (size_t)((b * 4 + kv) * 2 + mode) * 131072;
  const size_t rbase = (size_t)b * Tc;

  auto STAGE = [&](int bufi, int c) {
    const int s0 = c * 64;
#pragma unroll
    for (int p = 0; p < 2; ++p) {  // K: 64 rows x 16 slots of 16B
      int o = p * 512 + tid;
      int s = o >> 4, sl = o & 15;
      int slot = sl ^ (s & 7);
      load_lds16(kb + (rbase + s0 + s) * KVB_LD + slot * 8,
                 (char*)&KsB[bufi][0] + (p * 512 + wv * 64) * 16);
    }
#pragma unroll
    for (int p = 0; p < 2; ++p) {  // V^T: 128 rows x 8 slots of 16B
      int o = p * 512 + tid;
      int d = o >> 3, sl = o & 7;
      int slot = sl ^ ((d >> 1) & 7);
      load_lds16(vt + (size_t)d * 1024 + s0 + slot * 8,
                 (char*)&VtB[bufi][0] + (p * 512 + wv * 64) * 16);
    }
  };

  int c = c0;
  STAGE(0, c);
  int buf = 0;
  while (true) {
    int cn = c + 1;
    if (mode == 0)
      while (cn <= c1 && ((um >> (4 * cn)) & 0xFull) == 0ull) ++cn;
    __syncthreads();  // drains vmcnt(0): buf staged; prev buf free
    if (cn <= c1) STAGE(buf ^ 1, cn);

    const int s0 = c * 64;
    const char* KsP = (const char*)&KsB[buf][0];
    const char* VtP = (const char*)&VtB[buf][0];

    // S^T = mfma(K, Q): lane holds S[s0+j*16+lr*4+r][tL]
    f32x4 accs[4];
#pragma unroll
    for (int j = 0; j < 4; ++j) accs[j] = 0.f;
    __builtin_amdgcn_s_setprio(1);
#pragma unroll
    for (int ks = 0; ks < 4; ++ks) {
      s16x8 bk[4];
#pragma unroll
      for (int j = 0; j < 4; ++j) {
        int sB = j * 16 + lc;
        bk[j] = *(const s16x8*)(KsP +
                                ((sB * 256 + (ks * 4 + lr) * 16) ^ ((sB & 7) << 4)));
      }
#pragma unroll
      for (int j = 0; j < 4; ++j)
        accs[j] = __builtin_amdgcn_mfma_f32_16x16x32_bf16(bk[j], aq[ks], accs[j], 0, 0, 0);
    }
    __builtin_amdgcn_s_setprio(0);

    // per-lane online softmax over the 16 register s-values (+xor16/32 lane reduce)
    float ev[4][4];
    float mx = -INFINITY;
#pragma unroll
    for (int j = 0; j < 4; ++j)
#pragma unroll
      for (int r = 0; r < 4; ++r) {
        int s = s0 + j * 16 + lr * 4 + r;
        bool att;
        if (mode == 0) att = (s <= tL) && ((hm >> (s >> 4)) & 1ull);
        else att = (s <= tL) && (tL - s < WINc);
        float sv = att ? accs[j][r] * SCALEc : -INFINITY;
        ev[j][r] = sv;
        mx = fmaxf(mx, sv);
      }
    mx = fmaxf(mx, __shfl_xor(mx, 16));
    mx = fmaxf(mx, __shfl_xor(mx, 32));
    const float nm = fmaxf(run_m, mx);
    const float resc = (run_m == -INFINITY) ? 0.f : __expf(run_m - nm);
    float cl = 0.f;
#pragma unroll
    for (int j = 0; j < 4; ++j)
#pragma unroll
      for (int r = 0; r < 4; ++r) {
        float e = (ev[j][r] == -INFINITY) ? 0.f : __expf(ev[j][r] - nm);
        ev[j][r] = e;
        cl += e;
      }
    cl += __shfl_xor(cl, 16);
    cl += __shfl_xor(cl, 32);
    run_l = run_l * resc + cl;
    run_m = nm;

    // pack P pairs (s-consecutive) to bf16x2 words
    unsigned int pw[4][2];
#pragma unroll
    for (int j = 0; j < 4; ++j) {
      pw[j][0] = ((unsigned int)f2bf(ev[j][1]) << 16) | f2bf(ev[j][0]);
      pw[j][1] = ((unsigned int)f2bf(ev[j][3]) << 16) | f2bf(ev[j][2]);
    }

    // rescale acc_o rows (resc lives at lane lc=t-row; broadcast within lr group)
    float rs[4];
#pragma unroll
    for (int r = 0; r < 4; ++r) rs[r] = __shfl(resc, lr * 16 + lr * 4 + r);
#pragma unroll
    for (int jo = 0; jo < 8; ++jo)
#pragma unroll
      for (int r = 0; r < 4; ++r) acc_o[jo][r] *= rs[r];

    // build PV A-fragments in-register: ap[k2] elem e = P[s0+k2*32+lr*8+e][tL]
    s16x8 ap[2];
#pragma unroll
    for (int k2 = 0; k2 < 2; ++k2) {
      u32x4 words;
#pragma unroll
      for (int w = 0; w < 4; ++w) {
        int src = ((lr & 1) * 2 + (w >> 1)) * 16 + lc;
        unsigned int a0 = __shfl((int)pw[2 * k2][w & 1], src);
        unsigned int a1 = __shfl((int)pw[2 * k2 + 1][w & 1], src);
        words[w] = (lr >> 1) ? a1 : a0;
      }
      ap[k2] = __builtin_bit_cast(s16x8, words);
    }

    __builtin_amdgcn_s_setprio(1);
#pragma unroll
    for (int k2 = 0; k2 < 2; ++k2) {
#pragma unroll
      for (int jo = 0; jo < 8; ++jo) {
        int d = jo * 16 + lc;
        s16x8 bv = *(const s16x8*)(VtP +
                                   ((d * 128 + k2 * 64 + lr * 16) ^ (((d >> 1) & 7) << 4)));
        acc_o[jo] = __builtin_amdgcn_mfma_f32_16x16x32_bf16(ap[k2], bv, acc_o[jo], 0, 0, 0);
      }
    }
    __builtin_amdgcn_s_setprio(0);

    if (cn > c1) break;
    buf ^= 1;
    c = cn;
  }

  // epilogue: redistribute run_l to acc_o row layout, scale, write
  float rl[4];
#pragma unroll
  for (int r = 0; r < 4; ++r) rl[r] = __shfl(run_l, lr * 16 + lr * 4 + r);
#pragma unroll
  for (int r = 0; r < 4; ++r) {
    const int t = t0h + lr * 4 + r;
    const float gg = kvproj[(rbase + t) * KVP_LD + 1024 + h * 3 + 1 + mode];
    const float sc = gg / fmaxf(rl[r], 1e-9f);
    const size_t ob = ((size_t)(b * NQc + h) * Tc + t) * 128;
#pragma unroll
    for (int jo = 0; jo < 8; ++jo) {
      size_t oi = ob + jo * 16 + lc;
      float v = acc_o[jo][r] * sc;
      if (mode == 0) out[oi] += v;
      else out2[oi] = v;
    }
  }
}

// ---------- out += out2 ----------
__global__ void add_out(float* __restrict__ out, const float* __restrict__ out2) {
  size_t i = (size_t)blockIdx.x * 256 + threadIdx.x;  // exact: 4194304/256
  out[i] += out2[i];
}

extern "C" void kernel_launch(void* const* d_in, const int* in_sizes, int n_in,
                              void* d_out, int out_size, void* d_ws, size_t ws_size,
                              hipStream_t stream) {
  const float* x = (const float*)d_in[0];
  const float* q = (const float*)d_in[1];
  const float* gate_w = (const float*)d_in[2];
  const float* gate_b = (const float*)d_in[3];
  const float* wk_cmp = (const float*)d_in[4];
  const float* wv_cmp = (const float*)d_in[5];
  const float* wk_slc = (const float*)d_in[6];
  const float* wv_slc = (const float*)d_in[7];
  const float* wk_win = (const float*)d_in[8];
  const float* wv_win = (const float*)d_in[9];
  const float* block_pos = (const float*)d_in[10];
  const float* ck1_w = (const float*)d_in[11];
  const float* ck1_b = (const float*)d_in[12];
  const float* ck2_w = (const float*)d_in[13];
  const float* ck2_b = (const float*)d_in[14];
  const float* cv1_w = (const float*)d_in[15];
  const float* cv1_b = (const float*)d_in[16];
  const float* cv2_w = (const float*)d_in[17];
  const float* cv2_b = (const float*)d_in[18];
  float* out = (float*)d_out;

  char* wsp = (char*)d_ws;
  float* kvproj = (float*)wsp;
  bf16_t* kvbf = (bf16_t*)(wsp + 10485760);
  bf16_t* xbf = (bf16_t*)(wsp + 18874368);
  bf16_t* Wcat = (bf16_t*)(wsp + 27262976);
  float* bias_cat = (float*)(wsp + 38273024);
  unsigned long long* selB = (unsigned long long*)(wsp + 38285824);
  bf16_t* VT = (bf16_t*)(wsp + 38351360);

  float* part = (float*)(wsp + 18874368);      // 4 x 2048*512*4 = 16,777,216
  float* hk_part = (float*)(wsp + 18874368);   // 16*64512*4
  float* hv_part = (float*)(wsp + 23003136);
  float* out2 = (float*)(wsp + 18874368);      // 16 MB (after parts dead)
  float* hk = (float*)(wsp + 35651584);
  float* hv = (float*)(wsp + 35909632);
  float* k_sum = (float*)(wsp + 36167680);
  float* v_sum = (float*)(wsp + 36425728);
  float* bias_k = (float*)(wsp + 36683776);
  float* bias_v = (float*)(wsp + 36684288);

  dim3 blk256(256);

  conv_x<<<16384, blk256, 0, stream>>>(x, xbf);
  build_wcat<<<21504, blk256, 0, stream>>>(wv_cmp, wk_slc, wv_slc, wk_win,
                                           wv_win, gate_w, gate_b, Wcat, bias_cat);

  gemm_mfma<<<dim3(21, 16), blk256, 0, stream>>>(xbf, 2048, Wcat, 2048, kvproj,
                                                 kvbf, VT, bias_cat, 2048);
  gemm_xwt<<<dim3(8, 32, 4), blk256, 0, stream>>>(x, 2048, wk_cmp, 2048, part,
                                                  512, 2048, 512, 512);
  rope_k_fused<<<Bc * Tc * NKVc, 64, 0, stream>>>(part, kvproj);
  rope_bf<<<dim3(Bc * Tc * NKVc, 2), 64, 0, stream>>>(kvbf);

  bias_adj_kernel<<<dim3(128, 2), blk256, 0, stream>>>(block_pos, ck1_w, ck1_b,
                                                       cv1_w, cv1_b, bias_k, bias_v);
  gemm_cmp1<<<dim3(2, 8, 32), blk256, 0, stream>>>(kvproj, ck1_w, cv1_w,
                                                   hk_part, hv_part);
  reduce_gelu<<<504, blk256, 0, stream>>>(hk_part, hv_part, bias_k, bias_v, hk, hv);
  gemm_l2<<<dim3(2, 8, 2), blk256, 0, stream>>>(hk, ck2_w, ck2_b, hv, cv2_w,
                                                cv2_b, k_sum, v_sum);

  cmp_attn<<<2048, blk256, 0, stream>>>(q, k_sum, v_sum, kvproj, out, selB);
  sparse_attn_mfma<<<512, dim3(512), 0, stream>>>(q, kvbf, VT, kvproj, selB, out, out2);
  add_out<<<16384, blk256, 0, stream>>>(out, out2);
}

// Round 9
// 358.341 us; speedup vs baseline: 11.1607x; 1.0598x over previous
//
#include <hip/hip_runtime.h>
#include <hip/hip_bf16.h>
#include <math.h>

#define Bc 2
#define Tc 1024
#define DMc 2048
#define NQc 16
#define NKVc 4
#define DHc 128
#define BLKc 32
#define STRIDEc 16
#define TOPNc 16
#define WINc 512
#define NREPc 4
#define NBc 63
#define SCALEc 0.08838834764831843f
#define KVP_LD 1280   // kvproj f32: 0..511 k_cmp | 512..1023 v_cmp | 1024..1071 gates | pad
#define KVB_LD 2048   // kvbf bf16: 0..511 k_slc | 1024..1535 k_win (v slices go to VT)

typedef unsigned short bf16_t;
typedef short s16x8 __attribute__((ext_vector_type(8)));
typedef float f32x4 __attribute__((ext_vector_type(4)));
typedef unsigned short u16x4 __attribute__((ext_vector_type(4)));
typedef unsigned int u32x4 __attribute__((ext_vector_type(4)));

__device__ __forceinline__ unsigned short f2bf(float f) {
  unsigned int u = __float_as_uint(f);
  u += 0x7fffu + ((u >> 16) & 1u);
  return (unsigned short)(u >> 16);
}
__device__ __forceinline__ float bf2f(unsigned short h) {
  return __uint_as_float((unsigned int)h << 16);
}
__device__ __forceinline__ float geluf(float x) {
  return 0.5f * x * (1.0f + erff(x * 0.7071067811865476f));
}
__device__ __forceinline__ void load_lds16(const void* g, void* l) {
  __builtin_amdgcn_global_load_lds(
      (const __attribute__((address_space(1))) void*)g,
      (__attribute__((address_space(3))) void*)l, 16, 0, 0);
}

// ---------- x -> bf16 ----------
__global__ void conv_x(const float* __restrict__ x, bf16_t* __restrict__ xbf) {
  size_t i = (size_t)blockIdx.x * 256 + threadIdx.x;  // exact: 2048*2048/256
  xbf[i] = f2bf(x[i]);
}

// ---------- concat weights rows 512..3199 into bf16 Wcat ----------
__global__ void build_wcat(
    const float* __restrict__ wv_cmp, const float* __restrict__ wk_slc,
    const float* __restrict__ wv_slc, const float* __restrict__ wk_win,
    const float* __restrict__ wv_win, const float* __restrict__ gate_w,
    const float* __restrict__ gate_b, bf16_t* __restrict__ Wcat,
    float* __restrict__ bias_cat) {
  size_t i = (size_t)blockIdx.x * 256 + threadIdx.x;  // exact: 2688*2048/256
  int rr = (int)(i >> 11), c = (int)(i & 2047);
  int r = rr + 512;
  float v = 0.f;
  if (r < 3072) {
    int blk = r >> 9;  // 1..5
    size_t o = (size_t)(r & 511) * 2048 + c;
    if (blk == 1) v = wv_cmp[o];
    else if (blk == 2) v = wk_slc[o];
    else if (blk == 3) v = wv_slc[o];
    else if (blk == 4) v = wk_win[o];
    else v = wv_win[o];
  } else if (r < 3120) {
    v = gate_w[(size_t)(r - 3072) * 2048 + c];
  }
  Wcat[i] = f2bf(v);
  if (c == 0) bias_cat[r] = (r >= 3072 && r < 3120) ? gate_b[r - 3072] : 0.f;
}

// ---------- bf16 MFMA GEMM: cols 512..3199 ----------
__global__ __launch_bounds__(256) void gemm_mfma(
    const bf16_t* __restrict__ A, int lda,
    const bf16_t* __restrict__ Bw, int ldb,
    float* __restrict__ kvproj, bf16_t* __restrict__ kvbf,
    bf16_t* __restrict__ VT, const float* __restrict__ bias, int K) {
  __shared__ bf16_t As[128 * 32];
  __shared__ bf16_t Bs[128 * 32];
  const int bm = blockIdx.y * 128, bnw = blockIdx.x * 128, bn = 512 + bnw;
  const int tid = threadIdx.x, lane = tid & 63, w = tid >> 6;
  const int wr = (w >> 1) * 64, wc = (w & 1) * 64;

  f32x4 acc[4][4];
#pragma unroll
  for (int i = 0; i < 4; ++i)
#pragma unroll
    for (int j = 0; j < 4; ++j) acc[i][j] = 0.f;

  const int srow = lane >> 2;
  const int sslot = lane & 3;

  for (int k0 = 0; k0 < K; k0 += 32) {
    __syncthreads();
#pragma unroll
    for (int j = 0; j < 2; ++j) {
      int rb = w * 32 + j * 16;
      int row = rb + srow;
      int slot = sslot ^ ((row >> 1) & 3);
      load_lds16(A + (size_t)(bm + row) * lda + k0 + slot * 8, &As[rb * 32]);
      load_lds16(Bw + (size_t)(bnw + row) * ldb + k0 + slot * 8, &Bs[rb * 32]);
    }
    __syncthreads();

    s16x8 af[4], bfr[4];
#pragma unroll
    for (int i = 0; i < 4; ++i) {
      int ar = wr + i * 16 + (lane & 15);
      int as = ((lane >> 4) ^ ((ar >> 1) & 3)) * 8;
      af[i] = *(const s16x8*)&As[ar * 32 + as];
      int br = wc + i * 16 + (lane & 15);
      int bs = ((lane >> 4) ^ ((br >> 1) & 3)) * 8;
      bfr[i] = *(const s16x8*)&Bs[br * 32 + bs];
    }
#pragma unroll
    for (int i = 0; i < 4; ++i)
#pragma unroll
      for (int j = 0; j < 4; ++j)
        acc[i][j] = __builtin_amdgcn_mfma_f32_16x16x32_bf16(af[i], bfr[j], acc[i][j], 0, 0, 0);
  }

#pragma unroll
  for (int i = 0; i < 4; ++i) {
    int row = bm + wr + i * 16 + ((lane >> 4) << 2);
#pragma unroll
    for (int j = 0; j < 4; ++j) {
      int col = bn + wc + j * 16 + (lane & 15);
      float bv = bias[col];
      float vals[4];
#pragma unroll
      for (int r = 0; r < 4; ++r) vals[r] = acc[i][j][r] + bv;
      if (col < 1024) {  // v_cmp -> f32 kvproj
#pragma unroll
        for (int r = 0; r < 4; ++r)
          kvproj[(size_t)(row + r) * KVP_LD + col] = vals[r];
      } else if (col < 3072) {
        int cc = col - 1024;
        int region = cc >> 9;  // 0 k_slc, 1 v_slc, 2 k_win, 3 v_win
        if ((region & 1) == 0) {
#pragma unroll
          for (int r = 0; r < 4; ++r)
            kvbf[(size_t)(row + r) * KVB_LD + cc] = f2bf(vals[r]);
        } else {
          int mode = region >> 1;
          int kv = (cc >> 7) & 3, d = cc & 127;
          int b = row >> 10;
          u16x4 w4;
#pragma unroll
          for (int r = 0; r < 4; ++r) w4[r] = f2bf(vals[r]);
          *(u16x4*)(VT + (size_t)((b * 4 + kv) * 2 + mode) * 131072 +
                    d * 1024 + (row & 1023)) = w4;
        }
      } else {
#pragma unroll
        for (int r = 0; r < 4; ++r)
          kvproj[(size_t)(row + r) * KVP_LD + (col - 2048)] =
              1.f / (1.f + __expf(-vals[r]));
      }
    }
  }
}

// ---------- f32 VALU GEMM (split-K partials via blockIdx.z) ----------
__global__ __launch_bounds__(256) void gemm_xwt(
    const float* __restrict__ A, int lda, const float* __restrict__ W, int ldw,
    float* __restrict__ C, int ldc, int M, int N, int K) {
  __shared__ float As[16][68];
  __shared__ float Ws[16][68];
  const int z = blockIdx.z;
  A += (size_t)z * K;
  W += (size_t)z * K;
  C += (size_t)z * (size_t)M * ldc;
  const int bm = blockIdx.y * 64, bn = blockIdx.x * 64;
  const int tid = threadIdx.x;
  const int tx = tid & 15, ty = tid >> 4;
  float acc[4][4] = {{0.f}};
  for (int k0 = 0; k0 < K; k0 += 16) {
#pragma unroll
    for (int i0 = 0; i0 < 4; ++i0) {
      int i = tid + i0 * 256;
      int m = i >> 4, kk = i & 15;
      As[kk][m] = A[(size_t)(bm + m) * lda + (k0 + kk)];
      Ws[kk][m] = W[(size_t)(bn + m) * ldw + (k0 + kk)];
    }
    __syncthreads();
#pragma unroll
    for (int kk = 0; kk < 16; ++kk) {
      float4 a4 = *reinterpret_cast<const float4*>(&As[kk][ty * 4]);
      float4 w4 = *reinterpret_cast<const float4*>(&Ws[kk][tx * 4]);
      float av[4] = {a4.x, a4.y, a4.z, a4.w};
      float wv[4] = {w4.x, w4.y, w4.z, w4.w};
#pragma unroll
      for (int i = 0; i < 4; ++i)
#pragma unroll
        for (int j = 0; j < 4; ++j) acc[i][j] = fmaf(av[i], wv[j], acc[i][j]);
    }
    __syncthreads();
  }
#pragma unroll
  for (int i = 0; i < 4; ++i)
#pragma unroll
    for (int j = 0; j < 4; ++j)
      C[(size_t)(bm + ty * 4 + i) * ldc + bn + tx * 4 + j] = acc[i][j];
}

// ---------- reduce 4 k_cmp partials + RoPE -> kvproj cols 0..511 ----------
__global__ void rope_k_fused(const float* __restrict__ part,
                             float* __restrict__ kvproj) {
  int blk = blockIdx.x;  // (b*T+t)*KV+kv
  int kv = blk & 3;
  int t = (blk >> 2) & (Tc - 1);
  int b = blk >> 12;
  int d = threadIdx.x;  // 0..63
  size_t base = (size_t)(b * Tc + t) * 512 + kv * 128;
  float x1 = part[base + d] + part[1048576 + base + d] +
             part[2097152 + base + d] + part[3145728 + base + d];
  float x2 = part[base + d + 64] + part[1048576 + base + d + 64] +
             part[2097152 + base + d + 64] + part[3145728 + base + d + 64];
  float inv = powf(10000.f, -(float)d * (1.f / 64.f));
  float ang = (float)t * inv;
  float s, c;
  sincosf(ang, &s, &c);
  float* p = kvproj + (size_t)(b * Tc + t) * KVP_LD + kv * 128;
  p[d] = x1 * c - x2 * s;
  p[d + 64] = x1 * s + x2 * c;
}

// ---------- RoPE in place on kvbf K slices (bf16) ----------
__global__ void rope_bf(bf16_t* __restrict__ kvbf) {
  int blk = blockIdx.x;
  int coloff = blockIdx.y << 10;  // 0 (slc K) or 1024 (win K)
  int kv = blk & 3;
  int t = (blk >> 2) & (Tc - 1);
  int b = blk >> 12;
  bf16_t* p = kvbf + (size_t)(b * Tc + t) * KVB_LD + coloff + kv * 128;
  int d = threadIdx.x;
  float inv = powf(10000.f, -(float)d * (1.f / 64.f));
  float ang = (float)t * inv;
  float s, c;
  sincosf(ang, &s, &c);
  float x1 = bf2f(p[d]), x2 = bf2f(p[d + 64]);
  p[d] = f2bf(x1 * c - x2 * s);
  p[d + 64] = f2bf(x1 * s + x2 * c);
}

// ---------- compress layer1: gathered-A GEMM, split-K x16, k&v merged ----------
__global__ __launch_bounds__(256) void gemm_cmp1(
    const float* __restrict__ kvproj,
    const float* __restrict__ ck1_w, const float* __restrict__ cv1_w,
    float* __restrict__ hk_part, float* __restrict__ hv_part) {
  __shared__ float As[16][68];
  __shared__ float Ws[16][68];
  const int zz = blockIdx.z;
  const bool isv = zz >= 16;
  const int z = zz & 15;
  const int coloff = isv ? 512 : 0;
  const float* W = isv ? cv1_w : ck1_w;
  float* Cpart = isv ? hv_part : hk_part;
  const int bm = blockIdx.y * 64, bn = blockIdx.x * 64;
  const int tid = threadIdx.x;
  const int tx = tid & 15, ty = tid >> 4;
  float acc[4][4] = {{0.f}};
  for (int k0 = z * 256; k0 < z * 256 + 256; k0 += 16) {
#pragma unroll
    for (int i0 = 0; i0 < 4; ++i0) {
      int i = tid + i0 * 256;
      int m = i >> 4, kk = i & 15;
      int gm = bm + m;
      float av = 0.f;
      if (gm < 504) {
        int b = gm / 252, rem = gm % 252;
        int n = rem >> 2, kv = rem & 3;
        int f = k0 + kk;
        int j = f >> 7, d = f & 127;
        av = kvproj[(size_t)(b * Tc + n * 16 + j) * KVP_LD + coloff + kv * 128 + d];
      }
      As[kk][m] = av;
      Ws[kk][m] = W[(size_t)(bn + m) * 4096 + (k0 + kk)];
    }
    __syncthreads();
#pragma unroll
    for (int kk = 0; kk < 16; ++kk) {
      float4 a4 = *reinterpret_cast<const float4*>(&As[kk][ty * 4]);
      float4 w4 = *reinterpret_cast<const float4*>(&Ws[kk][tx * 4]);
      float av[4] = {a4.x, a4.y, a4.z, a4.w};
      float wv[4] = {w4.x, w4.y, w4.z, w4.w};
#pragma unroll
      for (int i = 0; i < 4; ++i)
#pragma unroll
        for (int j = 0; j < 4; ++j) acc[i][j] = fmaf(av[i], wv[j], acc[i][j]);
    }
    __syncthreads();
  }
#pragma unroll
  for (int i = 0; i < 4; ++i) {
    int m = bm + ty * 4 + i;
    if (m >= 504) continue;
#pragma unroll
    for (int j = 0; j < 4; ++j)
      Cpart[(size_t)z * 64512 + (size_t)m * 128 + bn + tx * 4 + j] = acc[i][j];
  }
}

// ---------- bias_adj[o] = b1[o] + block_pos_flat . w1[o,:] ----------
__global__ void bias_adj_kernel(const float* __restrict__ bp,
                                const float* __restrict__ w1k,
                                const float* __restrict__ b1k,
                                const float* __restrict__ w1v,
                                const float* __restrict__ b1v,
                                float* __restrict__ outk,
                                float* __restrict__ outv) {
  __shared__ float red[4];
  const int o = blockIdx.x;
  const float* w1 = blockIdx.y ? w1v : w1k;
  float s = 0.f;
  for (int i = threadIdx.x; i < 4096; i += 256)
    s += bp[i] * w1[(size_t)o * 4096 + i];
#pragma unroll
  for (int off = 32; off; off >>= 1) s += __shfl_xor(s, off);
  if ((threadIdx.x & 63) == 0) red[threadIdx.x >> 6] = s;
  __syncthreads();
  if (threadIdx.x == 0) {
    float t = red[0] + red[1] + red[2] + red[3];
    if (blockIdx.y) outv[o] = t + b1v[o];
    else outk[o] = t + b1k[o];
  }
}

// ---------- reduce 16 partials + bias + gelu, k&v merged ----------
__global__ void reduce_gelu(const float* __restrict__ hk_part,
                            const float* __restrict__ hv_part,
                            const float* __restrict__ bias_k,
                            const float* __restrict__ bias_v,
                            float* __restrict__ hk, float* __restrict__ hv) {
  int gi = blockIdx.x * 256 + threadIdx.x;  // exact: 2*64512/256
  const bool isv = gi >= 64512;
  int i = isv ? gi - 64512 : gi;
  const float* parts = isv ? hv_part : hk_part;
  float s = (isv ? bias_v : bias_k)[i & 127];
#pragma unroll
  for (int z = 0; z < 16; ++z) s += parts[z * 64512 + i];
  (isv ? hv : hk)[i] = geluf(s);
}

// ---------- compress layer2, k&v merged ----------
__global__ __launch_bounds__(256) void gemm_l2(
    const float* __restrict__ hk, const float* __restrict__ w2k,
    const float* __restrict__ b2k, const float* __restrict__ hv,
    const float* __restrict__ w2v, const float* __restrict__ b2v,
    float* __restrict__ k_sum, float* __restrict__ v_sum) {
  __shared__ float As[16][68];
  __shared__ float Ws[16][68];
  const bool isv = blockIdx.z != 0;
  const float* A = isv ? hv : hk;
  const float* W = isv ? w2v : w2k;
  const float* bias = isv ? b2v : b2k;
  float* C = isv ? v_sum : k_sum;
  const int bm = blockIdx.y * 64, bn = blockIdx.x * 64;
  const int tid = threadIdx.x;
  const int tx = tid & 15, ty = tid >> 4;
  float acc[4][4] = {{0.f}};
  for (int k0 = 0; k0 < 128; k0 += 16) {
#pragma unroll
    for (int i0 = 0; i0 < 4; ++i0) {
      int i = tid + i0 * 256;
      int m = i >> 4, kk = i & 15;
      int gm = bm + m;
      As[kk][m] = (gm < 504) ? A[(size_t)gm * 128 + (k0 + kk)] : 0.f;
      Ws[kk][m] = W[(size_t)(bn + m) * 128 + (k0 + kk)];
    }
    __syncthreads();
#pragma unroll
    for (int kk = 0; kk < 16; ++kk) {
      float4 a4 = *reinterpret_cast<const float4*>(&As[kk][ty * 4]);
      float4 w4 = *reinterpret_cast<const float4*>(&Ws[kk][tx * 4]);
      float av[4] = {a4.x, a4.y, a4.z, a4.w};
      float wv[4] = {w4.x, w4.y, w4.z, w4.w};
#pragma unroll
      for (int i = 0; i < 4; ++i)
#pragma unroll
        for (int j = 0; j < 4; ++j) acc[i][j] = fmaf(av[i], wv[j], acc[i][j]);
    }
    __syncthreads();
  }
#pragma unroll
  for (int i = 0; i < 4; ++i) {
    int m = bm + ty * 4 + i;
    if (m >= 504) continue;
#pragma unroll
    for (int j = 0; j < 4; ++j)
      C[(size_t)m * 128 + bn + tx * 4 + j] = acc[i][j] + bias[bn + tx * 4 + j];
  }
}

// ---------- compressed attention + top-k: 4 query tokens per wg ----------
__global__ __launch_bounds__(256) void cmp_attn(
    const float* __restrict__ q, const float* __restrict__ k_sum,
    const float* __restrict__ v_sum, const float* __restrict__ kvproj,
    float* __restrict__ out, unsigned long long* __restrict__ sel) {
  __shared__ __align__(16) float q_s[4][4][128];
  __shared__ __align__(16) float ks[NBc * 128];
  __shared__ float p_s[4][4][64];

  const int wg = blockIdx.x;  // (b*4+kv)*256 + tq
  const int tq = wg & 255;
  const int kv = (wg >> 8) & 3;
  const int b = wg >> 10;
  const int t0 = tq * 4;
  const int tid = threadIdx.x;
  const int lane = tid & 63;
  const int g = tid >> 6;

  for (int i = tid; i < 2048; i += 256) {
    int gg = i >> 9, r = (i >> 7) & 3, d = i & 127;
    q_s[gg][r][d] = q[(((size_t)b * NQc + gg * NKVc + kv) * Tc + t0 + r) * 128 + d];
  }
  {
    const float* kbase = k_sum + (size_t)(b * 252 + kv) * 128;
    for (int i = tid; i < NBc * 32; i += 256) {
      int n = i >> 5, s = i & 31;
      f32x4 v4 = *(const f32x4*)(kbase + (size_t)n * 512 + s * 4);
      *(f32x4*)&ks[n * 128 + ((s ^ (n & 7)) << 2)] = v4;
    }
  }
  __syncthreads();

  float acc[4] = {0.f, 0.f, 0.f, 0.f};
  {
    const int lrow = (lane < 63) ? lane : 62;
    const int lx = lrow & 7;
#pragma unroll
    for (int s = 0; s < 32; ++s) {
      f32x4 k4 = *(const f32x4*)&ks[lrow * 128 + ((s ^ lx) << 2)];
#pragma unroll
      for (int r = 0; r < 4; ++r) {
        f32x4 q4 = *(const f32x4*)&q_s[g][r][s * 4];
        acc[r] = fmaf(q4[0], k4[0], acc[r]);
        acc[r] = fmaf(q4[1], k4[1], acc[r]);
        acc[r] = fmaf(q4[2], k4[2], acc[r]);
        acc[r] = fmaf(q4[3], k4[3], acc[r]);
      }
    }
  }
#pragma unroll
  for (int r = 0; r < 4; ++r) {
    const int t = t0 + r;
    const int nvalid = min(t / STRIDEc + 1, NBc);
    const bool valid = (lane < nvalid);
    float sval = valid ? acc[r] * SCALEc : -INFINITY;
    float m = sval;
#pragma unroll
    for (int off = 32; off; off >>= 1) m = fmaxf(m, __shfl_xor(m, off));
    float e = valid ? __expf(sval - m) : 0.f;
    float l = e;
#pragma unroll
    for (int off = 32; off; off >>= 1) l += __shfl_xor(l, off);
    p_s[g][r][lane] = e / fmaxf(l, 1e-9f);
  }
  __syncthreads();

  {  // top-k: wave g handles row r=g
    float v = p_s[0][g][lane] + p_s[1][g][lane] + p_s[2][g][lane] + p_s[3][g][lane];
    if (lane >= NBc) v = -1.f;
    unsigned long long mask = 0ull;
    for (int it = 0; it < TOPNc; ++it) {
      float mx = v;
#pragma unroll
      for (int off = 32; off; off >>= 1) mx = fmaxf(mx, __shfl_xor(mx, off));
      unsigned long long ball = __ballot(v == mx);
      int sl = __ffsll(ball) - 1;
      mask |= 1ull << sl;
      if (lane == sl) v = -1.f;
    }
    if (lane == 0) sel[(((size_t)b * NKVc + kv) << 10) + t0 + g] = mask;
  }
  {
    const float* vbase = v_sum + (size_t)(b * 252 + kv) * 128;
    for (int i = tid; i < NBc * 32; i += 256) {
      int n = i >> 5, s = i & 31;
      f32x4 v4 = *(const f32x4*)(vbase + (size_t)n * 512 + s * 4);
      *(f32x4*)&ks[n * 128 + ((s ^ (n & 7)) << 2)] = v4;
    }
  }
  __syncthreads();

  const int h = g * NKVc + kv;
  float ox[4] = {0.f, 0.f, 0.f, 0.f}, oy[4] = {0.f, 0.f, 0.f, 0.f};
  const int slotd = lane >> 1, wi = (lane & 1) * 2;
  const int nvmax = min((t0 + 3) / STRIDEc + 1, NBc);
  for (int n = 0; n < nvmax; ++n) {
    const float* vp = &ks[n * 128 + (((slotd ^ (n & 7)) << 2) | wi)];
    const float vx = vp[0], vy = vp[1];
#pragma unroll
    for (int r = 0; r < 4; ++r) {
      float pn = p_s[g][r][n];
      ox[r] = fmaf(pn, vx, ox[r]);
      oy[r] = fmaf(pn, vy, oy[r]);
    }
  }
#pragma unroll
  for (int r = 0; r < 4; ++r) {
    const int t = t0 + r;
    const float g0 = kvproj[(size_t)(b * Tc + t) * KVP_LD + 1024 + h * 3];
    size_t obase = ((size_t)(b * NQc + h) * Tc + t) * 128 + lane * 2;
    *(float2*)&out[obase] = make_float2(g0 * ox[r], g0 * oy[r]);
  }
}

// ---------- merged MFMA flash-tile attention (swapped-QK, in-register P) ----------
// Balanced decode: co-resident pairs (wgi^1) and (wgi^256) both map tile tt <-> 31-tt,
// so every CU hosts complementary (ramp-up + ramp-down) work under either dispatch
// topology. mode 0 = slc (out +=), mode 1 = win (out2 =).
__global__ __launch_bounds__(512, 4) void sparse_attn_mfma(
    const float* __restrict__ q, const bf16_t* __restrict__ kvbf,
    const bf16_t* __restrict__ VT, const float* __restrict__ kvproj,
    const unsigned long long* __restrict__ sel,
    float* __restrict__ out, float* __restrict__ out2) {
  __shared__ bf16_t KsB[2][64 * 128];   // [s][d], swz ^((s&7)<<4) via pre-swz source
  __shared__ bf16_t VtB[2][128 * 64];   // [d][s], swz ^(((d>>1)&7)<<4)

  const int wgi = blockIdx.x;
  const int mode = wgi & 1;
  const int kv = (wgi >> 1) & 3;
  const int Y = (wgi >> 3) & 31;
  const int b = (wgi >> 8) & 1;
  const int tt = (mode ^ b) ? Y : 31 - Y;  // cost-complementary pairing
  const int t0 = tt * 32;
  const int tid = threadIdx.x, lane = tid & 63;
  const int wv = tid >> 6;   // 0..7
  const int g = wv & 3;      // head
  const int half = wv >> 2;  // row-half
  const int t0h = t0 + half * 16;
  const int h = g * NKVc + kv;
  const int lr = lane >> 4;
  const int lc = lane & 15;
  const int tL = t0h + lc;   // this lane's softmax column (query row)

  // Q fragments (B-operand): rows t0h+lc
  s16x8 aq[4];
  {
    const float* qrow = q + (((size_t)(b * NQc + h) * Tc) + tL) * 128;
#pragma unroll
    for (int ks = 0; ks < 4; ++ks) {
      f32x4 lo = *(const f32x4*)(qrow + ks * 32 + lr * 8);
      f32x4 hi = *(const f32x4*)(qrow + ks * 32 + lr * 8 + 4);
      s16x8 v;
#pragma unroll
      for (int e = 0; e < 4; ++e) {
        v[e] = (short)f2bf(lo[e]);
        v[e + 4] = (short)f2bf(hi[e]);
      }
      aq[ks] = v;
    }
  }

  unsigned long long hm = ~0ull;
  unsigned long long um = ~0ull;
  int c0;
  const int c1 = (t0 + 31) >> 6;
  const unsigned long long* sb = sel + ((size_t)(b * NKVc + kv) << 10);
  if (mode == 0) {
    unsigned long long bm = sb[tL];
    hm = bm | (bm << 1);  // token s attended iff bit (s>>4)
    // wg-uniform union over all 32 rows => uniform barrier counts in every wave
    unsigned long long uu = 0ull;
    if (lane < 32) {
      unsigned long long b2 = sb[t0 + lane];
      uu = b2 | (b2 << 1);
    }
#pragma unroll
    for (int off = 32; off; off >>= 1) uu |= __shfl_xor(uu, off);
    um = uu;
    c0 = (__ffsll(um) - 1) >> 2;
  } else {
    int lo = t0 - (WINc - 1);
    c0 = (lo > 0 ? lo : 0) >> 6;
  }

  float run_m = -INFINITY, run_l = 0.f;  // per-lane, for t = tL
  f32x4 acc_o[8];                        // O[t=t0h+lr*4+r][d=jo*16+lc]
#pragma unroll
  for (int j = 0; j < 8; ++j) acc_o[j] = 0.f;

  const bf16_t* kb = kvbf + (mode << 10) + kv * 128;
  const bf16_t* vt = VT + (size_t)((b * 4 + kv) * 2 + mode) * 131072;
  const size_t rbase = (size_t)b * Tc;

  auto STAGE = [&](int bufi, int c) {
    const int s0 = c * 64;
#pragma unroll
    for (int p = 0; p < 2; ++p) {  // K: 64 rows x 16 slots of 16B
      int o = p * 512 + tid;
      int s = o >> 4, sl = o & 15;
      int slot = sl ^ (s & 7);
      load_lds16(kb + (rbase + s0 + s) * KVB_LD + slot * 8,
                 (char*)&KsB[bufi][0] + (p * 512 + wv * 64) * 16);
    }
#pragma unroll
    for (int p = 0; p < 2; ++p) {  // V^T: 128 rows x 8 slots of 16B
      int o = p * 512 + tid;
      int d = o >> 3, sl = o & 7;
      int slot = sl ^ ((d >> 1) & 7);
      load_lds16(vt + (size_t)d * 1024 + s0 + slot * 8,
                 (char*)&VtB[bufi][0] + (p * 512 + wv * 64) * 16);
    }
  };

  int c = c0;
  STAGE(0, c);
  int buf = 0;
  while (true) {
    int cn = c + 1;
    if (mode == 0)
      while (cn <= c1 && ((um >> (4 * cn)) & 0xFull) == 0ull) ++cn;
    __syncthreads();  // drains vmcnt(0): buf staged; prev buf free
    if (cn <= c1) STAGE(buf ^ 1, cn);

    const int s0 = c * 64;
    const char* KsP = (const char*)&KsB[buf][0];
    const char* VtP = (const char*)&VtB[buf][0];

    // S^T = mfma(K, Q): lane holds S[s0+j*16+lr*4+r][tL]
    f32x4 accs[4];
#pragma unroll
    for (int j = 0; j < 4; ++j) accs[j] = 0.f;
    __builtin_amdgcn_s_setprio(1);
#pragma unroll
    for (int ks = 0; ks < 4; ++ks) {
      s16x8 bk[4];
#pragma unroll
      for (int j = 0; j < 4; ++j) {
        int sB = j * 16 + lc;
        bk[j] = *(const s16x8*)(KsP +
                                ((sB * 256 + (ks * 4 + lr) * 16) ^ ((sB & 7) << 4)));
      }
#pragma unroll
      for (int j = 0; j < 4; ++j)
        accs[j] = __builtin_amdgcn_mfma_f32_16x16x32_bf16(bk[j], aq[ks], accs[j], 0, 0, 0);
    }
    __builtin_amdgcn_s_setprio(0);

    // per-lane online softmax over the 16 register s-values (+xor16/32 lane reduce)
    float ev[4][4];
    float mx = -INFINITY;
#pragma unroll
    for (int j = 0; j < 4; ++j)
#pragma unroll
      for (int r = 0; r < 4; ++r) {
        int s = s0 + j * 16 + lr * 4 + r;
        bool att;
        if (mode == 0) att = (s <= tL) && ((hm >> (s >> 4)) & 1ull);
        else att = (s <= tL) && (tL - s < WINc);
        float sv = att ? accs[j][r] * SCALEc : -INFINITY;
        ev[j][r] = sv;
        mx = fmaxf(mx, sv);
      }
    mx = fmaxf(mx, __shfl_xor(mx, 16));
    mx = fmaxf(mx, __shfl_xor(mx, 32));
    // defer-rescale (T13): skip rescale when no column's max grew past THR=8.
    // (-inf corner safe: masked ev entries produce e=0 regardless of nm.)
    const bool defer = __all(mx <= run_m + 8.f);
    float nm = run_m;
    if (!defer) {
      nm = fmaxf(run_m, mx);
      const float resc = (run_m == -INFINITY) ? 0.f : __expf(run_m - nm);
      float rs[4];
#pragma unroll
      for (int r = 0; r < 4; ++r) rs[r] = __shfl(resc, lr * 16 + lr * 4 + r);
#pragma unroll
      for (int jo = 0; jo < 8; ++jo)
#pragma unroll
        for (int r = 0; r < 4; ++r) acc_o[jo][r] *= rs[r];
      run_l *= resc;
      run_m = nm;
    }
    float cl = 0.f;
#pragma unroll
    for (int j = 0; j < 4; ++j)
#pragma unroll
      for (int r = 0; r < 4; ++r) {
        float e = (ev[j][r] == -INFINITY) ? 0.f : __expf(ev[j][r] - nm);
        ev[j][r] = e;
        cl += e;
      }
    cl += __shfl_xor(cl, 16);
    cl += __shfl_xor(cl, 32);
    run_l += cl;

    // pack P pairs (s-consecutive) to bf16x2 words
    unsigned int pw[4][2];
#pragma unroll
    for (int j = 0; j < 4; ++j) {
      pw[j][0] = ((unsigned int)f2bf(ev[j][1]) << 16) | f2bf(ev[j][0]);
      pw[j][1] = ((unsigned int)f2bf(ev[j][3]) << 16) | f2bf(ev[j][2]);
    }

    // build PV A-fragments in-register: ap[k2] elem e = P[s0+k2*32+lr*8+e][tL]
    s16x8 ap[2];
#pragma unroll
    for (int k2 = 0; k2 < 2; ++k2) {
      u32x4 words;
#pragma unroll
      for (int w = 0; w < 4; ++w) {
        int src = ((lr & 1) * 2 + (w >> 1)) * 16 + lc;
        unsigned int a0 = __shfl((int)pw[2 * k2][w & 1], src);
        unsigned int a1 = __shfl((int)pw[2 * k2 + 1][w & 1], src);
        words[w] = (lr >> 1) ? a1 : a0;
      }
      ap[k2] = __builtin_bit_cast(s16x8, words);
    }

    __builtin_amdgcn_s_setprio(1);
#pragma unroll
    for (int k2 = 0; k2 < 2; ++k2) {
#pragma unroll
      for (int jo = 0; jo < 8; ++jo) {
        int d = jo * 16 + lc;
        s16x8 bv = *(const s16x8*)(VtP +
                                   ((d * 128 + k2 * 64 + lr * 16) ^ (((d >> 1) & 7) << 4)));
        acc_o[jo] = __builtin_amdgcn_mfma_f32_16x16x32_bf16(ap[k2], bv, acc_o[jo], 0, 0, 0);
      }
    }
    __builtin_amdgcn_s_setprio(0);

    if (cn > c1) break;
    buf ^= 1;
    c = cn;
  }

  // epilogue: redistribute run_l to acc_o row layout, scale, write
  float rl[4];
#pragma unroll
  for (int r = 0; r < 4; ++r) rl[r] = __shfl(run_l, lr * 16 + lr * 4 + r);
#pragma unroll
  for (int r = 0; r < 4; ++r) {
    const int t = t0h + lr * 4 + r;
    const float gg = kvproj[(rbase + t) * KVP_LD + 1024 + h * 3 + 1 + mode];
    const float sc = gg / fmaxf(rl[r], 1e-9f);
    const size_t ob = ((size_t)(b * NQc + h) * Tc + t) * 128;
#pragma unroll
    for (int jo = 0; jo < 8; ++jo) {
      size_t oi = ob + jo * 16 + lc;
      float v = acc_o[jo][r] * sc;
      if (mode == 0) out[oi] += v;
      else out2[oi] = v;
    }
  }
}

// ---------- out += out2 ----------
__global__ void add_out(float* __restrict__ out, const float* __restrict__ out2) {
  size_t i = (size_t)blockIdx.x * 256 + threadIdx.x;  // exact: 4194304/256
  out[i] += out2[i];
}

extern "C" void kernel_launch(void* const* d_in, const int* in_sizes, int n_in,
                              void* d_out, int out_size, void* d_ws, size_t ws_size,
                              hipStream_t stream) {
  const float* x = (const float*)d_in[0];
  const float* q = (const float*)d_in[1];
  const float* gate_w = (const float*)d_in[2];
  const float* gate_b = (const float*)d_in[3];
  const float* wk_cmp = (const float*)d_in[4];
  const float* wv_cmp = (const float*)d_in[5];
  const float* wk_slc = (const float*)d_in[6];
  const float* wv_slc = (const float*)d_in[7];
  const float* wk_win = (const float*)d_in[8];
  const float* wv_win = (const float*)d_in[9];
  const float* block_pos = (const float*)d_in[10];
  const float* ck1_w = (const float*)d_in[11];
  const float* ck1_b = (const float*)d_in[12];
  const float* ck2_w = (const float*)d_in[13];
  const float* ck2_b = (const float*)d_in[14];
  const float* cv1_w = (const float*)d_in[15];
  const float* cv1_b = (const float*)d_in[16];
  const float* cv2_w = (const float*)d_in[17];
  const float* cv2_b = (const float*)d_in[18];
  float* out = (float*)d_out;

  char* wsp = (char*)d_ws;
  float* kvproj = (float*)wsp;
  bf16_t* kvbf = (bf16_t*)(wsp + 10485760);
  bf16_t* xbf = (bf16_t*)(wsp + 18874368);
  bf16_t* Wcat = (bf16_t*)(wsp + 27262976);
  float* bias_cat = (float*)(wsp + 38273024);
  unsigned long long* selB = (unsigned long long*)(wsp + 38285824);
  bf16_t* VT = (bf16_t*)(wsp + 38351360);

  float* part = (float*)(wsp + 18874368);      // 4 x 2048*512*4 = 16,777,216
  float* hk_part = (float*)(wsp + 18874368);   // 16*64512*4
  float* hv_part = (float*)(wsp + 23003136);
  float* out2 = (float*)(wsp + 18874368);      // 16 MB (after parts dead)
  float* hk = (float*)(wsp + 35651584);
  float* hv = (float*)(wsp + 35909632);
  float* k_sum = (float*)(wsp + 36167680);
  float* v_sum = (float*)(wsp + 36425728);
  float* bias_k = (float*)(wsp + 36683776);
  float* bias_v = (float*)(wsp + 36684288);

  dim3 blk256(256);

  conv_x<<<16384, blk256, 0, stream>>>(x, xbf);
  build_wcat<<<21504, blk256, 0, stream>>>(wv_cmp, wk_slc, wv_slc, wk_win,
                                           wv_win, gate_w, gate_b, Wcat, bias_cat);

  gemm_mfma<<<dim3(21, 16), blk256, 0, stream>>>(xbf, 2048, Wcat, 2048, kvproj,
                                                 kvbf, VT, bias_cat, 2048);
  gemm_xwt<<<dim3(8, 32, 4), blk256, 0, stream>>>(x, 2048, wk_cmp, 2048, part,
                                                  512, 2048, 512, 512);
  rope_k_fused<<<Bc * Tc * NKVc, 64, 0, stream>>>(part, kvproj);
  rope_bf<<<dim3(Bc * Tc * NKVc, 2), 64, 0, stream>>>(kvbf);

  bias_adj_kernel<<<dim3(128, 2), blk256, 0, stream>>>(block_pos, ck1_w, ck1_b,
                                                       cv1_w, cv1_b, bias_k, bias_v);
  gemm_cmp1<<<dim3(2, 8, 32), blk256, 0, stream>>>(kvproj, ck1_w, cv1_w,
                                                   hk_part, hv_part);
  reduce_gelu<<<504, blk256, 0, stream>>>(hk_part, hv_part, bias_k, bias_v, hk, hv);
  gemm_l2<<<dim3(2, 8, 2), blk256, 0, stream>>>(hk, ck2_w, ck2_b, hv, cv2_w,
                                                cv2_b, k_sum, v_sum);

  cmp_attn<<<2048, blk256, 0, stream>>>(q, k_sum, v_sum, kvproj, out, selB);
  sparse_attn_mfma<<<512, dim3(512), 0, stream>>>(q, kvbf, VT, kvproj, selB, out, out2);
  add_out<<<16384, blk256, 0, stream>>>(out, out2);
}